// Round 10
// baseline (1246.298 us; speedup 1.0000x reference)
//
#include <hip/hip_runtime.h>

using uint = unsigned int;
using u16  = unsigned short;
using ll   = long long;

constexpr int cL = 4, cH = 12, cDH = 64, cD = 768, cM = 3072, cV = 32000, cS = 1024, cB = 2;
constexpr int cT  = cB * cS;   // 2048 tokens
constexpr int cBH = cB * cH;   // 24
constexpr int cQKV = 3 * cD;   // 2304

using bf16x8 = __bf16 __attribute__((ext_vector_type(8)));
using f32x4  = float  __attribute__((ext_vector_type(4)));

__device__ __forceinline__ float b2f(u16 u) {
    union { uint i; float f; } v; v.i = ((uint)u) << 16; return v.f;
}
__device__ __forceinline__ u16 f2b(float f) {
    union { float f; uint i; } v; v.f = f;
    uint u = v.i;
    return (u16)((u + 0x7fffu + ((u >> 16) & 1u)) >> 16);   // RNE
}
// read input element `idx` as float, per mode (1 = bf16, 0 = f32)
__device__ __forceinline__ float inp(const void* p, ll idx, int md) {
    return md ? b2f(((const u16*)p)[idx]) : ((const float*)p)[idx];
}
__device__ __forceinline__ float wave_sum(float v) {
    #pragma unroll
    for (int m = 32; m; m >>= 1) v += __shfl_xor(v, m);
    return v;
}
__device__ __forceinline__ float wave_max(float v) {
    #pragma unroll
    for (int m = 32; m; m >>= 1) v = fmaxf(v, __shfl_xor(v, m));
    return v;
}
__device__ __forceinline__ void gload16(const u16* g, u16* l) {
    __builtin_amdgcn_global_load_lds(
        (const __attribute__((address_space(1))) uint*)g,
        (__attribute__((address_space(3))) uint*)l,
        16, 0, 0);
}

// ---------------- dtype detector ------------------------------------------------------
__global__ void detect_k(const uint* __restrict__ e, int* __restrict__ flag)
{
    const int l = threadIdx.x;
    int hits = 0;
    #pragma unroll
    for (int i = 0; i < 4; ++i) {
        uint w  = e[l * 4 + i];
        uint ex = (w >> 7) & 0xffu;
        hits += (ex >= 100u && ex <= 126u) ? 1 : 0;
    }
    float s = wave_sum((float)hits);
    if (l == 0) *flag = (s >= 128.f) ? 1 : 0;   // 1 = bf16 inputs, 0 = f32 inputs
}

// ---------------- pack QKV biases -> f32 [L][2304] ------------------------------------
__global__ __launch_bounds__(256)
void packbias_k(const void* __restrict__ Qb, const void* __restrict__ Kb,
                const void* __restrict__ Vb, float* __restrict__ out,
                const int* __restrict__ modeflag)
{
    const int md = *modeflag;
    const int i = blockIdx.x * 256 + threadIdx.x;   // i < L*2304
    const int l = i / cQKV, c = i % cQKV;
    float v;
    if (c < cD)           v = inp(Qb, (ll)l * cD + c, md);
    else if (c < 2 * cD)  v = inp(Kb, (ll)l * cD + c - cD, md);
    else                  v = inp(Vb, (ll)l * cD + c - 2 * cD, md);
    out[i] = v;
}

// =============== gemm8p: m201-template 8-phase 256x256, BK=64, 8 waves ================
// C = A[M,K] * Bt[N,K]^T + bias. LDS 128KiB = 2 bufs x {A 256x64, B 256x64} bf16.
// Iteration = 2 K-tiles (a=2i buf0, b=2i+1 buf1), 8 phases; per phase: ds_read quadrant
// frags || stage 1 half-tile (2 gload_lds); barrier; lgkmcnt(0); setprio; 16 MFMA; barrier.
// vmcnt(6) ONLY at phases 4 & 8 (3 half-tiles in flight across barriers).
// Stage slots: P1:b.B0  P2:a+2.A0  P3:a+2.B1  P4:a+2.A1  P5:a+2.B0  P6-8:b+2.{A0,B1,A1}.
// WAR-safe: quadrant order (mh0,nh0)(mh0,nh1)(mh1,nh1)(mh1,nh0) => every region staged
// >=1 barrier-pair after its last ds_read. T2 swizzle g^=(row&7) both-sides.
template<int OUTK, bool GELU, int BIASK>
__global__ __launch_bounds__(512, 1)
void gemm8p(const u16* __restrict__ A, int lda,
            const u16* __restrict__ Bt, int ldb,
            void* __restrict__ Cv, int ldc, int K,
            const void* __restrict__ bias, ll bias_off,
            const int* __restrict__ modeflag)
{
    __shared__ __align__(16) u16 lds[2 * 32768];   // 128 KiB

    // T1: bijective XCD swizzle
    const int nwg = gridDim.x * gridDim.y;
    const int lin = blockIdx.y * gridDim.x + blockIdx.x;
    const int q8 = nwg >> 3, r8 = nwg & 7;
    const int xcd = lin & 7, idx = lin >> 3;
    const int n_  = (xcd < r8 ? xcd * (q8 + 1) : r8 * (q8 + 1) + (xcd - r8) * q8) + idx;
    const int rowTile = (n_ % gridDim.x) * 256;
    const int colTile = (n_ / gridDim.x) * 256;

    const int md = *modeflag;
    const int tid = threadIdx.x;
    const int lane = tid & 63, wid = tid >> 6;
    const int wr = wid >> 2, wc = wid & 3;          // per-wave rows {mh*128+wr*64+..}, cols {nh*128+wc*32+..}
    const int l15 = lane & 15, l16 = lane >> 4;
    const int nt = K >> 6;                          // BK=64; nt must be even
    const int niter = nt >> 1;

    // stage one half-tile (128 rows x 64 K); 2 gload_lds of 8KB (64 rows each)
    auto stA = [&](int t, int h) {
        #pragma unroll
        for (int j = 0; j < 2; ++j) {
            const int r = h * 128 + j * 64 + (tid >> 3);
            const int g = tid & 7;
            gload16(A + (size_t)(rowTile + r) * lda + t * 64 + ((g ^ (r & 7)) << 3),
                    &lds[(t & 1) * 32768 + (h * 128 + j * 64 + (wid << 3)) * 64]);
        }
    };
    auto stB = [&](int t, int h) {
        #pragma unroll
        for (int j = 0; j < 2; ++j) {
            const int r = h * 128 + j * 64 + (tid >> 3);
            const int g = tid & 7;
            gload16(Bt + (size_t)(colTile + r) * ldb + t * 64 + ((g ^ (r & 7)) << 3),
                    &lds[(t & 1) * 32768 + 16384 + (h * 128 + j * 64 + (wid << 3)) * 64]);
        }
    };

    f32x4 acc[8][4];
    #pragma unroll
    for (int m = 0; m < 8; ++m)
        #pragma unroll
        for (int n = 0; n < 4; ++n) acc[m][n] = f32x4{0.f, 0.f, 0.f, 0.f};

    bf16x8 af[4][2], bv[2][2];

#define RD_A(BUF, MH)                                                                  \
    { _Pragma("unroll") for (int m = 0; m < 4; ++m) {                                  \
        const int row = (MH) * 128 + wr * 64 + m * 16 + l15;                           \
        _Pragma("unroll") for (int ks = 0; ks < 2; ++ks) {                             \
            const int sg = (ks * 4 + l16) ^ (row & 7);                                 \
            af[m][ks] = *(const bf16x8*)&lds[(BUF) + row * 64 + sg * 8]; } } }
#define RD_B(BUF, NH)                                                                  \
    { _Pragma("unroll") for (int nn = 0; nn < 2; ++nn) {                               \
        const int row = (NH) * 128 + wc * 32 + nn * 16 + l15;                          \
        _Pragma("unroll") for (int ks = 0; ks < 2; ++ks) {                             \
            const int sg = (ks * 4 + l16) ^ (row & 7);                                 \
            bv[nn][ks] = *(const bf16x8*)&lds[(BUF) + 16384 + row * 64 + sg * 8]; } } }
#define MFMA_Q(MO, NO)                                                                 \
    __builtin_amdgcn_s_barrier();                                                      \
    asm volatile("s_waitcnt lgkmcnt(0)" ::: "memory");                                 \
    __builtin_amdgcn_sched_barrier(0);                                                 \
    __builtin_amdgcn_s_setprio(1);                                                     \
    { _Pragma("unroll") for (int m = 0; m < 4; ++m)                                    \
      _Pragma("unroll") for (int nn = 0; nn < 2; ++nn)                                 \
      _Pragma("unroll") for (int ks = 0; ks < 2; ++ks)                                 \
        acc[(MO) + m][(NO) + nn] =                                                     \
            __builtin_amdgcn_mfma_f32_16x16x32_bf16(af[m][ks], bv[nn][ks],             \
                                                    acc[(MO) + m][(NO) + nn], 0, 0, 0); } \
    __builtin_amdgcn_s_setprio(0);                                                     \
    __builtin_amdgcn_s_barrier();

    // prologue: t0 {A0,B1,A1,B0} vmcnt(4); t1 {A0,B1,A1} vmcnt(6)
    stA(0, 0); stB(0, 1); stA(0, 1); stB(0, 0);
    asm volatile("s_waitcnt vmcnt(4)" ::: "memory");
    stA(1, 0); stB(1, 1); stA(1, 1);
    asm volatile("s_waitcnt vmcnt(6)" ::: "memory");
    __builtin_amdgcn_s_barrier();

    for (int it = 0; it < niter; ++it) {
        const int a = 2 * it, b = a + 1;
        const bool more = (it + 1 < niter);
        // ---- P1: tile a Q(mh0,nh0); stage b.B0 ----
        RD_A(0, 0) RD_B(0, 0)
        stB(b, 0);
        MFMA_Q(0, 0)
        // ---- P2: Q(mh0,nh1); stage a+2.A0 ----
        RD_B(0, 1)
        if (more) stA(a + 2, 0);
        MFMA_Q(0, 2)
        // ---- P3: Q(mh1,nh1); stage a+2.B1 ----
        RD_A(0, 1)
        if (more) stB(a + 2, 1);
        MFMA_Q(4, 2)
        // ---- P4: Q(mh1,nh0); stage a+2.A1; vmcnt ----
        RD_B(0, 0)
        if (more) {
            stA(a + 2, 1);
            asm volatile("s_waitcnt vmcnt(6)" ::: "memory");
        } else {
            asm volatile("s_waitcnt vmcnt(0)" ::: "memory");
        }
        MFMA_Q(4, 0)
        // ---- P5: tile b Q(mh0,nh0); stage a+2.B0 ----
        RD_A(32768, 0) RD_B(32768, 0)
        if (more) stB(a + 2, 0);
        MFMA_Q(0, 0)
        // ---- P6: Q(mh0,nh1); stage b+2.A0 ----
        RD_B(32768, 1)
        if (more) stA(b + 2, 0);
        MFMA_Q(0, 2)
        // ---- P7: Q(mh1,nh1); stage b+2.B1 ----
        RD_A(32768, 1)
        if (more) stB(b + 2, 1);
        MFMA_Q(4, 2)
        // ---- P8: Q(mh1,nh0); stage b+2.A1; vmcnt(6) ----
        RD_B(32768, 0)
        if (more) {
            stA(b + 2, 1);
            asm volatile("s_waitcnt vmcnt(6)" ::: "memory");
        }
        MFMA_Q(4, 0)
    }
#undef RD_A
#undef RD_B
#undef MFMA_Q

    // ---- epilogue ----
    #pragma unroll
    for (int n = 0; n < 4; ++n) {
        const int col = colTile + (n >> 1) * 128 + wc * 32 + (n & 1) * 16 + l15;
        float bvv = 0.f;
        if constexpr (BIASK == 1) bvv = inp(bias, bias_off + col, md);
        if constexpr (BIASK == 2) bvv = ((const float*)bias)[bias_off + col];
        #pragma unroll
        for (int m = 0; m < 8; ++m) {
            const int rbase = rowTile + (m >> 2) * 128 + wr * 64 + (m & 3) * 16 + l16 * 4;
            #pragma unroll
            for (int r = 0; r < 4; ++r) {
                float xv = acc[m][n][r] + bvv;
                if constexpr (GELU) xv = 0.5f * xv * (1.f + erff(xv * 0.70710678118654752f));
                const size_t idx = (size_t)(rbase + r) * ldc + col;
                if constexpr (OUTK == 1)      ((u16*)Cv)[idx] = f2b(xv);
                else if constexpr (OUTK == 0) ((float*)Cv)[idx] = xv;
                else {
                    if (md) ((u16*)Cv)[idx] = f2b(xv);
                    else    ((float*)Cv)[idx] = xv;
                }
            }
        }
    }
}

// ---------------- GEMM (m97-style, 4 waves) — small/odd shapes ------------------------
template<int BM, int BN, int WGM, int WGN, int OUTK, bool GELU,
         bool COLMAJ, bool CSKIP, bool CK, int BIASK>
__global__ __launch_bounds__(256)
void gemm_bt(const u16* __restrict__ A, int lda, ll offAo, ll offAi,
             const u16* __restrict__ Bt, int ldb, ll offBo, ll offBi,
             void* __restrict__ Cv, int ldc, ll offCo, ll offCi,
             int HB, int K,
             const void* __restrict__ bias, ll bias_off, float scale,
             const float* __restrict__ r1, const float* __restrict__ r2,
             const int* __restrict__ modeflag)
{
    constexpr int MF = BM / WGM / 16;
    constexpr int NF = BN / WGN / 16;
    static_assert(BM % (WGM * 16) == 0 && BN % (WGN * 16) == 0, "tile/wave mismatch");
    static_assert(WGM * WGN == 4, "4 waves");
    __shared__ __align__(16) u16 sA[BM * 64];
    __shared__ __align__(16) u16 sB[BN * 64];

    int rowTile, colTile;
    if constexpr (CSKIP) {
        const int bi = blockIdx.x;
        int r = (int)((sqrtf(8.f * bi + 1.f) - 1.f) * 0.5f);
        while ((r + 1) * (r + 2) / 2 <= bi) ++r;
        while (r * (r + 1) / 2 > bi) --r;
        rowTile = r * BM;
        colTile = (bi - r * (r + 1) / 2) * BN;
    } else {
        rowTile = (COLMAJ ? blockIdx.x : blockIdx.y) * BM;
        colTile = (COLMAJ ? blockIdx.y : blockIdx.x) * BN;
    }

    const int md = *modeflag;
    const int z = blockIdx.z;
    const ll zo = z / HB, zi = z % HB;
    const u16* Ab = A + zo * offAo + zi * offAi;
    const u16* Bb = Bt + zo * offBo + zi * offBi;

    const int tid  = threadIdx.x;
    const int lane = tid & 63, wid = tid >> 6;
    const int wr = wid / WGN, wc = wid % WGN;
    const int lr = lane >> 3, lc8 = (lane & 7) << 3;

    f32x4 zero = {0.f, 0.f, 0.f, 0.f};
    f32x4 acc[MF][NF];
    #pragma unroll
    for (int m = 0; m < MF; ++m)
        #pragma unroll
        for (int n = 0; n < NF; ++n) acc[m][n] = zero;

    const int nkt = CK ? ((rowTile + BM) >> 6) : (K >> 6);
    for (int kt = 0; kt < nkt; ++kt) {
        const int k0 = kt << 6;
        #pragma unroll
        for (int i = 0; i < BM / 32; ++i) {
            int c = i * 4 + wid;
            gload16(Ab + (size_t)(rowTile + c * 8 + lr) * lda + k0 + lc8, &sA[c * 512]);
        }
        #pragma unroll
        for (int i = 0; i < BN / 32; ++i) {
            int c = i * 4 + wid;
            gload16(Bb + (size_t)(colTile + c * 8 + lr) * ldb + k0 + lc8, &sB[c * 512]);
        }
        asm volatile("s_waitcnt vmcnt(0)" ::: "memory");
        __syncthreads();
        #pragma unroll
        for (int kk = 0; kk < 2; ++kk) {
            const int ko = kk * 32 + (lane >> 4) * 8;
            bf16x8 af[MF], bfv[NF];
            #pragma unroll
            for (int m = 0; m < MF; ++m)
                af[m] = *(const bf16x8*)&sA[(wr * (BM / WGM) + m * 16 + (lane & 15)) * 64 + ko];
            #pragma unroll
            for (int n = 0; n < NF; ++n)
                bfv[n] = *(const bf16x8*)&sB[(wc * (BN / WGN) + n * 16 + (lane & 15)) * 64 + ko];
            #pragma unroll
            for (int m = 0; m < MF; ++m)
                #pragma unroll
                for (int n = 0; n < NF; ++n)
                    acc[m][n] = __builtin_amdgcn_mfma_f32_16x16x32_bf16(af[m], bfv[n], acc[m][n], 0, 0, 0);
        }
        __syncthreads();
    }

    const ll offC = zo * offCo + zi * offCi;
    #pragma unroll
    for (int m = 0; m < MF; ++m) {
        #pragma unroll
        for (int n = 0; n < NF; ++n) {
            const int col = colTile + wc * (BN / WGN) + n * 16 + (lane & 15);
            float bvv = 0.f;
            if constexpr (BIASK == 1) bvv = inp(bias, bias_off + col, md);
            if constexpr (BIASK == 2) bvv = ((const float*)bias)[bias_off + col];
            #pragma unroll
            for (int r = 0; r < 4; ++r) {
                const int row = rowTile + wr * (BM / WGM) + m * 16 + ((lane >> 4) << 2) + r;
                float xv = acc[m][n][r] * scale + bvv;
                if constexpr (GELU) xv = 0.5f * xv * (1.f + erff(xv * 0.70710678118654752f));
                const size_t idx = (size_t)row * ldc + col;
                if (r1) xv += r1[idx];
                if (r2) xv += r2[idx];
                if constexpr (OUTK == 1)      ((u16*)Cv)[offC + idx] = f2b(xv);
                else if constexpr (OUTK == 0) ((float*)Cv)[offC + idx] = xv;
                else {
                    if (md) ((u16*)Cv)[offC + idx] = f2b(xv);
                    else    ((float*)Cv)[offC + idx] = xv;
                }
            }
        }
    }
}

// ------- transpose input weight (bf16 OR f32) -> bf16 ---------------------------------
__global__ __launch_bounds__(256)
void transpose_k(const void* __restrict__ in, u16* __restrict__ out,
                 int R, int C, int ins, int outs,
                 ll base, ll iStride, ll oStride,
                 const int* __restrict__ modeflag)
{
    __shared__ u16 tile[32][33];
    const int md = *modeflag;
    const int z = blockIdx.z;
    const ll ioff = base + (ll)z * iStride;
    u16* op = out + (ll)z * oStride;
    const int tx = threadIdx.x & 31, ty = threadIdx.x >> 5;
    const int c0 = blockIdx.x * 32, r0 = blockIdx.y * 32;
    #pragma unroll
    for (int i = 0; i < 32; i += 8) {
        int r = r0 + ty + i, c = c0 + tx;
        if (r < R && c < C) tile[ty + i][tx] = f2b(inp(in, ioff + (ll)r * ins + c, md));
    }
    __syncthreads();
    #pragma unroll
    for (int i = 0; i < 32; i += 8) {
        int c = c0 + ty + i, r = r0 + tx;
        if (c < C && r < R) op[(size_t)c * outs + r] = tile[tx][ty + i];
    }
}

// ------- fused per-layer weight transposes: QKV + O + In + Out in ONE launch ----------
__global__ __launch_bounds__(256)
void transw_k(const void* __restrict__ Qw, const void* __restrict__ Kw,
              const void* __restrict__ Vw, const void* __restrict__ Ow,
              const void* __restrict__ Inw, const void* __restrict__ Outw,
              u16* __restrict__ WqkvT, u16* __restrict__ WoT,
              u16* __restrict__ WinT, u16* __restrict__ WoutT,
              int l, const int* __restrict__ modeflag)
{
    __shared__ u16 tile[32][33];
    const int md = *modeflag;
    const int b = blockIdx.x;
    const void* in; u16* out; int ins, outs, tx_, ty_; ll ibase;
    if (b < 1728) {
        const int seg = b / 576, rem = b % 576, hd = rem / 48, tt = rem % 48;
        in = seg == 0 ? Qw : (seg == 1 ? Kw : Vw);
        ibase = (ll)l * cH * cD * cDH + (ll)hd * cD * cDH;
        out = WqkvT + (ll)seg * cD * cD + (ll)hd * cDH * cD;
        ins = cDH; outs = cD; tx_ = tt % 2; ty_ = tt / 2;
    } else if (b < 2304) {
        const int tt = b - 1728;
        in = Ow; ibase = (ll)l * cD * cD; out = WoT;
        ins = cD; outs = cD; tx_ = tt % 24; ty_ = tt / 24;
    } else if (b < 4608) {
        const int tt = b - 2304;
        in = Inw; ibase = (ll)l * cD * cM; out = WinT;
        ins = cM; outs = cD; tx_ = tt % 96; ty_ = tt / 96;
    } else {
        const int tt = b - 4608;
        in = Outw; ibase = (ll)l * cM * cD; out = WoutT;
        ins = cD; outs = cM; tx_ = tt % 24; ty_ = tt / 24;
    }
    const int tx = threadIdx.x & 31, ty = threadIdx.x >> 5;
    const int c0 = tx_ * 32, r0 = ty_ * 32;
    #pragma unroll
    for (int i = 0; i < 32; i += 8)
        tile[ty + i][tx] = f2b(inp(in, ibase + (ll)(r0 + ty + i) * ins + c0 + tx, md));
    __syncthreads();
    #pragma unroll
    for (int i = 0; i < 32; i += 8)
        out[(size_t)(c0 + ty + i) * outs + (r0 + tx)] = tile[tx][ty + i];
}

// ---- bf16 transpose for internal V slice (qkv cols) ----------------------------------
__global__ __launch_bounds__(256)
void transpose_b_k(const u16* __restrict__ in, u16* __restrict__ out,
                   int R, int C, int ins, int outs,
                   ll iOo, ll iOi, ll oOo, ll oOi, int HB)
{
    __shared__ u16 tile[32][33];
    const int z = blockIdx.z;
    const u16* ip = in  + (ll)(z / HB) * iOo + (ll)(z % HB) * iOi;
    u16*       op = out + (ll)(z / HB) * oOo + (ll)(z % HB) * oOi;
    const int tx = threadIdx.x & 31, ty = threadIdx.x >> 5;
    const int c0 = blockIdx.x * 32, r0 = blockIdx.y * 32;
    #pragma unroll
    for (int i = 0; i < 32; i += 8) {
        int r = r0 + ty + i, c = c0 + tx;
        if (r < R && c < C) tile[ty + i][tx] = ip[(size_t)r * ins + c];
    }
    __syncthreads();
    #pragma unroll
    for (int i = 0; i < 32; i += 8) {
        int c = c0 + ty + i, r = r0 + tx;
        if (c < C && r < R) op[(size_t)c * outs + r] = tile[tx][ty + i];
    }
}

// ---------------- embedding: res = E[x] + P (f32 out) ---------------------------------
__global__ __launch_bounds__(192)
void embed_k(const int* __restrict__ x, const void* __restrict__ E,
             const void* __restrict__ P, float* __restrict__ res,
             const int* __restrict__ modeflag)
{
    const int md = *modeflag;
    const int tok = blockIdx.x, t = threadIdx.x;
    const int s = tok & (cS - 1);
    const ll  eb = (ll)x[tok] * cD, pb = (ll)s * cD;
    float4 o;
    o.x = inp(E, eb + t * 4 + 0, md) + inp(P, pb + t * 4 + 0, md);
    o.y = inp(E, eb + t * 4 + 1, md) + inp(P, pb + t * 4 + 1, md);
    o.z = inp(E, eb + t * 4 + 2, md) + inp(P, pb + t * 4 + 2, md);
    o.w = inp(E, eb + t * 4 + 3, md) + inp(P, pb + t * 4 + 3, md);
    ((float4*)(res + (size_t)tok * cD))[t] = o;
}

// ---------------- layernorm (unbiased std, ddof=1), f32 in, bf16 out ------------------
__global__ __launch_bounds__(192)
void ln_k(const float* __restrict__ in, const void* __restrict__ w,
          const void* __restrict__ b, ll wb_off, u16* __restrict__ out,
          const int* __restrict__ modeflag)
{
    __shared__ float sm[8];
    const int md = *modeflag;
    const int row = blockIdx.x, t = threadIdx.x;
    const float4 x = ((const float4*)(in + (size_t)row * cD))[t];
    float s = wave_sum(x.x + x.y + x.z + x.w);
    const int lane = t & 63, wv = t >> 6;
    if (!lane) sm[wv] = s;
    __syncthreads();
    const float mu = (sm[0] + sm[1] + sm[2]) * (1.f / (float)cD);
    const float dx = x.x - mu, dy = x.y - mu, dz = x.z - mu, dw = x.w - mu;
    float ss = wave_sum(dx * dx + dy * dy + dz * dz + dw * dw);
    if (!lane) sm[4 + wv] = ss;
    __syncthreads();
    const float var = (sm[4] + sm[5] + sm[6]) * (1.f / (float)(cD - 1));
    const float rs  = 1.f / sqrtf(var);
    const ll o4 = wb_off + (ll)t * 4;
    ushort4 o;
    o.x = f2b(inp(w, o4 + 0, md) * (dx * rs) + inp(b, o4 + 0, md));
    o.y = f2b(inp(w, o4 + 1, md) * (dy * rs) + inp(b, o4 + 1, md));
    o.z = f2b(inp(w, o4 + 2, md) * (dz * rs) + inp(b, o4 + 2, md));
    o.w = f2b(inp(w, o4 + 3, md) * (dw * rs) + inp(b, o4 + 3, md));
    ((ushort4*)(out + (size_t)row * cD))[t] = o;
}

// ---------------- causal softmax, in-place on bf16 [rows=BH*S][S] ----------------------
__global__ __launch_bounds__(256)
void softmax_k(u16* __restrict__ p)
{
    __shared__ float sm[8];
    const int row = blockIdx.x;
    const int q = row & (cS - 1);
    u16* pr = p + (size_t)row * cS;
    const int t = threadIdx.x;
    const int j0 = t * 4;
    ushort4 v = {0, 0, 0, 0};
    if (j0 <= q) v = ((const ushort4*)pr)[t];
    float x0 = (j0 + 0 <= q) ? b2f(v.x) : -100000.f;
    float x1 = (j0 + 1 <= q) ? b2f(v.y) : -100000.f;
    float x2 = (j0 + 2 <= q) ? b2f(v.z) : -100000.f;
    float x3 = (j0 + 3 <= q) ? b2f(v.w) : -100000.f;
    float mx = wave_max(fmaxf(fmaxf(x0, x1), fmaxf(x2, x3)));
    const int lane = t & 63, wv = t >> 6;
    if (!lane) sm[wv] = mx;
    __syncthreads();
    const float MX = fmaxf(fmaxf(sm[0], sm[1]), fmaxf(sm[2], sm[3]));
    const float e0 = expf(x0 - MX), e1 = expf(x1 - MX), e2 = expf(x2 - MX), e3 = expf(x3 - MX);
    float ssum = wave_sum(e0 + e1 + e2 + e3);
    if (!lane) sm[4 + wv] = ssum;
    __syncthreads();
    const float inv = 1.f / (sm[4] + sm[5] + sm[6] + sm[7]);
    ushort4 o;
    o.x = f2b(e0 * inv); o.y = f2b(e1 * inv); o.z = f2b(e2 * inv); o.w = f2b(e3 * inv);
    ((ushort4*)pr)[t] = o;
}

// =====================================================================================
extern "C" void kernel_launch(void* const* d_in, const int* in_sizes, int n_in,
                              void* d_out, int out_size, void* d_ws, size_t ws_size,
                              hipStream_t stream)
{
    (void)in_sizes; (void)n_in; (void)out_size;
    const int*  x     = (const int*)d_in[0];
    const void* E_w   = d_in[1];
    const void* P_w   = d_in[2];
    const void* ln1_w = d_in[3];
    const void* ln1_b = d_in[4];
    const void* Q_w   = d_in[5];
    const void* Q_b   = d_in[6];
    const void* K_w   = d_in[7];
    const void* K_b   = d_in[8];
    const void* V_w   = d_in[9];
    const void* V_b   = d_in[10];
    const void* O_w   = d_in[11];
    const void* O_b   = d_in[12];
    const void* ln2_w = d_in[13];
    const void* ln2_b = d_in[14];
    const void* In_w  = d_in[15];
    const void* In_b  = d_in[16];
    const void* Out_w = d_in[17];
    const void* Out_b = d_in[18];
    const void* lnf_w = d_in[19];
    const void* lnf_b = d_in[20];
    const void* U_w   = d_in[21];
    const void* U_b   = d_in[22];

    // ---- workspace carve with aliasing (~99 MB) ----
    char* wp = (char*)d_ws;
    auto carve = [&](size_t bytes) { char* r = wp; wp += (bytes + 255) & ~(size_t)255; return r; };
    int*   modeflag = (int*)carve(256);
    float* biasQKV  = (float*)carve((size_t)cL * cQKV * 4);
    float* res   = (float*)carve((size_t)cT * cD * 4);
    float* resat = (float*)carve((size_t)cT * cD * 4);
    u16* h     = (u16*)carve((size_t)cT * cD * 2);
    u16* attnb = (u16*)carve((size_t)cT * cD * 2);
    u16* vt    = (u16*)carve((size_t)cT * cD * 2);
    u16* qkv   = (u16*)carve((size_t)cT * cM * 2);       // aliased by mlpb
    u16* mlpb  = qkv;
    u16* WqkvT = (u16*)carve((size_t)cQKV * cD * 2);
    u16* WoT   = (u16*)carve((size_t)cD * cD * 2);
    u16* WinT  = (u16*)carve((size_t)cD * cM * 2);
    u16* WoutT = (u16*)carve((size_t)cD * cM * 2);
    u16* pbuf  = (u16*)carve((size_t)cBH * cS * cS * 2);
    u16* WuT   = pbuf;                                   // alias (pbuf dead after layers)

    if (ws_size && (size_t)(wp - (char*)d_ws) > ws_size) return;  // tripwire

    detect_k<<<1, 64, 0, stream>>>((const uint*)E_w, modeflag);
    packbias_k<<<(cL * cQKV) / 256, 256, 0, stream>>>(Q_b, K_b, V_b, biasQKV, modeflag);
    embed_k<<<cT, 192, 0, stream>>>(x, E_w, P_w, res, modeflag);

    for (int l = 0; l < cL; ++l) {
        // fused weight transposes for this layer (1 launch)
        transw_k<<<6912, 256, 0, stream>>>(Q_w, K_w, V_w, O_w, In_w, Out_w,
                                           WqkvT, WoT, WinT, WoutT, l, modeflag);

        // LN1
        ln_k<<<cT, 192, 0, stream>>>(res, ln1_w, ln1_b, (ll)l * cD, h, modeflag);

        // fused QKV projection (gemm_bt 128^2, 288 blocks): [2048,768] @ [2304,768]^T
        gemm_bt<128, 128, 2, 2, 1, false, true, false, false, 2>
            <<<dim3(cT / 128, cQKV / 128, 1), 256, 0, stream>>>(
            h, cD, 0, 0, WqkvT, cD, 0, 0, qkv, cQKV, 0, 0, 1, cD,
            biasQKV, (ll)l * cQKV, 1.f, nullptr, nullptr, modeflag);

        // V slice -> vt [B,H,DH,S]
        transpose_b_k<<<dim3(2, cS / 32, cBH), 256, 0, stream>>>(
            qkv + 2 * cD, vt, cS, cDH, cQKV, cS,
            (ll)cS * cQKV, cDH, (ll)cH * cDH * cS, (ll)cDH * cS, cH);

        // logits = Q K^T * 1/8, batched over (b,h), compact triangular grid (36 tiles)
        gemm_bt<128, 128, 2, 2, 1, false, false, true, false, 0>
            <<<dim3(36, 1, cBH), 256, 0, stream>>>(
            qkv, cQKV, (ll)cS * cQKV, cDH,
            qkv + cD, cQKV, (ll)cS * cQKV, cDH,
            pbuf, cS, (ll)cH * cS * cS, (ll)cS * cS,
            cH, cDH, nullptr, 0, 0.125f, nullptr, nullptr, modeflag);

        softmax_k<<<cBH * cS, 256, 0, stream>>>(pbuf);

        // attn = P V, batched, causal K-limit; 64x64 tiles -> 384 blocks
        gemm_bt<64, 64, 2, 2, 1, false, false, false, true, 0>
            <<<dim3(1, 16, cBH), 256, 0, stream>>>(
            pbuf, cS, (ll)cH * cS * cS, (ll)cS * cS,
            vt, cS, (ll)cH * cDH * cS, (ll)cDH * cS,
            attnb, cD, (ll)cS * cD, cDH,
            cH, cS, nullptr, 0, 1.f, nullptr, nullptr, modeflag);

        // O projection + residual -> resat (f32)
        gemm_bt<128, 128, 2, 2, 0, false, true, false, false, 1>
            <<<dim3(cT / 128, cD / 128, 1), 256, 0, stream>>>(
            attnb, cD, 0, 0, WoT, cD, 0, 0, resat, cD, 0, 0, 1, cD,
            O_b, (ll)l * cD, 1.f, res, nullptr, modeflag);

        // LN2
        ln_k<<<cT, 192, 0, stream>>>(resat, ln2_w, ln2_b, (ll)l * cD, h, modeflag);

        // MLP in (gemm_bt 128^2, 384 blocks): gelu(h @ Win + bIn)
        gemm_bt<128, 128, 2, 2, 1, true, true, false, false, 1>
            <<<dim3(cT / 128, cM / 128, 1), 256, 0, stream>>>(
            h, cD, 0, 0, WinT, cD, 0, 0, mlpb, cM, 0, 0, 1, cD,
            In_b, (ll)l * cM, 1.f, nullptr, nullptr, modeflag);

        // MLP out + double residual (64^2 tiles -> 384 blocks)
        gemm_bt<64, 64, 2, 2, 0, false, true, false, false, 1>
            <<<dim3(cT / 64, cD / 64, 1), 256, 0, stream>>>(
            mlpb, cM, 0, 0, WoutT, cM, 0, 0, res, cD, 0, 0, 1, cM,
            Out_b, (ll)l * cD, 1.f, res, resat, modeflag);
    }

    // unembed weight transpose (WuT aliases pbuf), final LN, unembed (8-phase template)
    transpose_k<<<dim3(cV / 32, cD / 32, 1), 256, 0, stream>>>(
        U_w, WuT, cD, cV, cV, cD, 0, 0, 0, modeflag);
    ln_k<<<cT, 192, 0, stream>>>(res, lnf_w, lnf_b, 0, h, modeflag);
    gemm8p<2, false, 1><<<dim3(cT / 256, cV / 256, 1), 512, 0, stream>>>(
        h, cD, WuT, cD, d_out, cV, cD, U_b, 0, modeflag);
}

// Round 11
// 1084.668 us; speedup vs baseline: 1.1490x; 1.1490x over previous
//
#include <hip/hip_runtime.h>

using uint = unsigned int;
using u16  = unsigned short;
using ll   = long long;

constexpr int cL = 4, cH = 12, cDH = 64, cD = 768, cM = 3072, cV = 32000, cS = 1024, cB = 2;
constexpr int cT  = cB * cS;   // 2048 tokens
constexpr int cBH = cB * cH;   // 24
constexpr int cQKV = 3 * cD;   // 2304

using bf16x8 = __bf16 __attribute__((ext_vector_type(8)));
using f32x4  = float  __attribute__((ext_vector_type(4)));

__device__ __forceinline__ float b2f(u16 u) {
    union { uint i; float f; } v; v.i = ((uint)u) << 16; return v.f;
}
__device__ __forceinline__ u16 f2b(float f) {
    union { float f; uint i; } v; v.f = f;
    uint u = v.i;
    return (u16)((u + 0x7fffu + ((u >> 16) & 1u)) >> 16);   // RNE
}
// read input element `idx` as float, per mode (1 = bf16, 0 = f32)
__device__ __forceinline__ float inp(const void* p, ll idx, int md) {
    return md ? b2f(((const u16*)p)[idx]) : ((const float*)p)[idx];
}
__device__ __forceinline__ float wave_sum(float v) {
    #pragma unroll
    for (int m = 32; m; m >>= 1) v += __shfl_xor(v, m);
    return v;
}
__device__ __forceinline__ float wave_max(float v) {
    #pragma unroll
    for (int m = 32; m; m >>= 1) v = fmaxf(v, __shfl_xor(v, m));
    return v;
}
__device__ __forceinline__ void gload16(const u16* g, u16* l) {
    __builtin_amdgcn_global_load_lds(
        (const __attribute__((address_space(1))) uint*)g,
        (__attribute__((address_space(3))) uint*)l,
        16, 0, 0);
}

// ---------------- dtype detector ------------------------------------------------------
__global__ void detect_k(const uint* __restrict__ e, int* __restrict__ flag)
{
    const int l = threadIdx.x;
    int hits = 0;
    #pragma unroll
    for (int i = 0; i < 4; ++i) {
        uint w  = e[l * 4 + i];
        uint ex = (w >> 7) & 0xffu;
        hits += (ex >= 100u && ex <= 126u) ? 1 : 0;
    }
    float s = wave_sum((float)hits);
    if (l == 0) *flag = (s >= 128.f) ? 1 : 0;   // 1 = bf16 inputs, 0 = f32 inputs
}

// ---------------- pack QKV biases -> f32 [L][2304] ------------------------------------
__global__ __launch_bounds__(256)
void packbias_k(const void* __restrict__ Qb, const void* __restrict__ Kb,
                const void* __restrict__ Vb, float* __restrict__ out,
                const int* __restrict__ modeflag)
{
    const int md = *modeflag;
    const int i = blockIdx.x * 256 + threadIdx.x;   // i < L*2304
    const int l = i / cQKV, c = i % cQKV;
    float v;
    if (c < cD)           v = inp(Qb, (ll)l * cD + c, md);
    else if (c < 2 * cD)  v = inp(Kb, (ll)l * cD + c - cD, md);
    else                  v = inp(Vb, (ll)l * cD + c - 2 * cD, md);
    out[i] = v;
}

// =============== gemm8p: m201-template 8-phase 256x256, BK=64, 8 waves ================
// (kept: best measured unembed variant, 179.6 us median; schedule verified bit-exact)
template<int OUTK, bool GELU, int BIASK>
__global__ __launch_bounds__(512, 1)
void gemm8p(const u16* __restrict__ A, int lda,
            const u16* __restrict__ Bt, int ldb,
            void* __restrict__ Cv, int ldc, int K,
            const void* __restrict__ bias, ll bias_off,
            const int* __restrict__ modeflag)
{
    __shared__ __align__(16) u16 lds[2 * 32768];   // 128 KiB

    const int nwg = gridDim.x * gridDim.y;
    const int lin = blockIdx.y * gridDim.x + blockIdx.x;
    const int q8 = nwg >> 3, r8 = nwg & 7;
    const int xcd = lin & 7, idx = lin >> 3;
    const int n_  = (xcd < r8 ? xcd * (q8 + 1) : r8 * (q8 + 1) + (xcd - r8) * q8) + idx;
    const int rowTile = (n_ % gridDim.x) * 256;
    const int colTile = (n_ / gridDim.x) * 256;

    const int md = *modeflag;
    const int tid = threadIdx.x;
    const int lane = tid & 63, wid = tid >> 6;
    const int wr = wid >> 2, wc = wid & 3;
    const int l15 = lane & 15, l16 = lane >> 4;
    const int nt = K >> 6;                          // BK=64; nt even
    const int niter = nt >> 1;

    auto stA = [&](int t, int h) {
        #pragma unroll
        for (int j = 0; j < 2; ++j) {
            const int r = h * 128 + j * 64 + (tid >> 3);
            const int g = tid & 7;
            gload16(A + (size_t)(rowTile + r) * lda + t * 64 + ((g ^ (r & 7)) << 3),
                    &lds[(t & 1) * 32768 + (h * 128 + j * 64 + (wid << 3)) * 64]);
        }
    };
    auto stB = [&](int t, int h) {
        #pragma unroll
        for (int j = 0; j < 2; ++j) {
            const int r = h * 128 + j * 64 + (tid >> 3);
            const int g = tid & 7;
            gload16(Bt + (size_t)(colTile + r) * ldb + t * 64 + ((g ^ (r & 7)) << 3),
                    &lds[(t & 1) * 32768 + 16384 + (h * 128 + j * 64 + (wid << 3)) * 64]);
        }
    };

    f32x4 acc[8][4];
    #pragma unroll
    for (int m = 0; m < 8; ++m)
        #pragma unroll
        for (int n = 0; n < 4; ++n) acc[m][n] = f32x4{0.f, 0.f, 0.f, 0.f};

    bf16x8 af[4][2], bv[2][2];

#define RD_A(BUF, MH)                                                                  \
    { _Pragma("unroll") for (int m = 0; m < 4; ++m) {                                  \
        const int row = (MH) * 128 + wr * 64 + m * 16 + l15;                           \
        _Pragma("unroll") for (int ks = 0; ks < 2; ++ks) {                             \
            const int sg = (ks * 4 + l16) ^ (row & 7);                                 \
            af[m][ks] = *(const bf16x8*)&lds[(BUF) + row * 64 + sg * 8]; } } }
#define RD_B(BUF, NH)                                                                  \
    { _Pragma("unroll") for (int nn = 0; nn < 2; ++nn) {                               \
        const int row = (NH) * 128 + wc * 32 + nn * 16 + l15;                          \
        _Pragma("unroll") for (int ks = 0; ks < 2; ++ks) {                             \
            const int sg = (ks * 4 + l16) ^ (row & 7);                                 \
            bv[nn][ks] = *(const bf16x8*)&lds[(BUF) + 16384 + row * 64 + sg * 8]; } } }
#define MFMA_Q(MO, NO)                                                                 \
    __builtin_amdgcn_s_barrier();                                                      \
    asm volatile("s_waitcnt lgkmcnt(0)" ::: "memory");                                 \
    __builtin_amdgcn_sched_barrier(0);                                                 \
    __builtin_amdgcn_s_setprio(1);                                                     \
    { _Pragma("unroll") for (int m = 0; m < 4; ++m)                                    \
      _Pragma("unroll") for (int nn = 0; nn < 2; ++nn)                                 \
      _Pragma("unroll") for (int ks = 0; ks < 2; ++ks)                                 \
        acc[(MO) + m][(NO) + nn] =                                                     \
            __builtin_amdgcn_mfma_f32_16x16x32_bf16(af[m][ks], bv[nn][ks],             \
                                                    acc[(MO) + m][(NO) + nn], 0, 0, 0); } \
    __builtin_amdgcn_s_setprio(0);                                                     \
    __builtin_amdgcn_s_barrier();

    stA(0, 0); stB(0, 1); stA(0, 1); stB(0, 0);
    asm volatile("s_waitcnt vmcnt(4)" ::: "memory");
    stA(1, 0); stB(1, 1); stA(1, 1);
    asm volatile("s_waitcnt vmcnt(6)" ::: "memory");
    __builtin_amdgcn_s_barrier();

    for (int it = 0; it < niter; ++it) {
        const int a = 2 * it, b = a + 1;
        const bool more = (it + 1 < niter);
        RD_A(0, 0) RD_B(0, 0)
        stB(b, 0);
        MFMA_Q(0, 0)
        RD_B(0, 1)
        if (more) stA(a + 2, 0);
        MFMA_Q(0, 2)
        RD_A(0, 1)
        if (more) stB(a + 2, 1);
        MFMA_Q(4, 2)
        RD_B(0, 0)
        if (more) {
            stA(a + 2, 1);
            asm volatile("s_waitcnt vmcnt(6)" ::: "memory");
        } else {
            asm volatile("s_waitcnt vmcnt(0)" ::: "memory");
        }
        MFMA_Q(4, 0)
        RD_A(32768, 0) RD_B(32768, 0)
        if (more) stB(a + 2, 0);
        MFMA_Q(0, 0)
        RD_B(32768, 1)
        if (more) stA(b + 2, 0);
        MFMA_Q(0, 2)
        RD_A(32768, 1)
        if (more) stB(b + 2, 1);
        MFMA_Q(4, 2)
        RD_B(32768, 0)
        if (more) {
            stA(b + 2, 1);
            asm volatile("s_waitcnt vmcnt(6)" ::: "memory");
        }
        MFMA_Q(4, 0)
    }
#undef RD_A
#undef RD_B
#undef MFMA_Q

    #pragma unroll
    for (int n = 0; n < 4; ++n) {
        const int col = colTile + (n >> 1) * 128 + wc * 32 + (n & 1) * 16 + l15;
        float bvv = 0.f;
        if constexpr (BIASK == 1) bvv = inp(bias, bias_off + col, md);
        if constexpr (BIASK == 2) bvv = ((const float*)bias)[bias_off + col];
        #pragma unroll
        for (int m = 0; m < 8; ++m) {
            const int rbase = rowTile + (m >> 2) * 128 + wr * 64 + (m & 3) * 16 + l16 * 4;
            #pragma unroll
            for (int r = 0; r < 4; ++r) {
                float xv = acc[m][n][r] + bvv;
                if constexpr (GELU) xv = 0.5f * xv * (1.f + erff(xv * 0.70710678118654752f));
                const size_t idx = (size_t)(rbase + r) * ldc + col;
                if constexpr (OUTK == 1)      ((u16*)Cv)[idx] = f2b(xv);
                else if constexpr (OUTK == 0) ((float*)Cv)[idx] = xv;
                else {
                    if (md) ((u16*)Cv)[idx] = f2b(xv);
                    else    ((float*)Cv)[idx] = xv;
                }
            }
        }
    }
}

// ---------------- GEMM (m97-style, 4 waves) — small/odd shapes ------------------------
template<int BM, int BN, int WGM, int WGN, int OUTK, bool GELU,
         bool COLMAJ, bool CSKIP, bool CK, int BIASK>
__global__ __launch_bounds__(256)
void gemm_bt(const u16* __restrict__ A, int lda, ll offAo, ll offAi,
             const u16* __restrict__ Bt, int ldb, ll offBo, ll offBi,
             void* __restrict__ Cv, int ldc, ll offCo, ll offCi,
             int HB, int K,
             const void* __restrict__ bias, ll bias_off, float scale,
             const float* __restrict__ r1, const float* __restrict__ r2,
             const int* __restrict__ modeflag)
{
    constexpr int MF = BM / WGM / 16;
    constexpr int NF = BN / WGN / 16;
    static_assert(BM % (WGM * 16) == 0 && BN % (WGN * 16) == 0, "tile/wave mismatch");
    static_assert(WGM * WGN == 4, "4 waves");
    __shared__ __align__(16) u16 sA[BM * 64];
    __shared__ __align__(16) u16 sB[BN * 64];

    int rowTile, colTile;
    if constexpr (CSKIP) {
        const int bi = blockIdx.x;
        int r = (int)((sqrtf(8.f * bi + 1.f) - 1.f) * 0.5f);
        while ((r + 1) * (r + 2) / 2 <= bi) ++r;
        while (r * (r + 1) / 2 > bi) --r;
        rowTile = r * BM;
        colTile = (bi - r * (r + 1) / 2) * BN;
    } else {
        rowTile = (COLMAJ ? blockIdx.x : blockIdx.y) * BM;
        colTile = (COLMAJ ? blockIdx.y : blockIdx.x) * BN;
    }

    const int md = *modeflag;
    const int z = blockIdx.z;
    const ll zo = z / HB, zi = z % HB;
    const u16* Ab = A + zo * offAo + zi * offAi;
    const u16* Bb = Bt + zo * offBo + zi * offBi;

    const int tid  = threadIdx.x;
    const int lane = tid & 63, wid = tid >> 6;
    const int wr = wid / WGN, wc = wid % WGN;
    const int lr = lane >> 3, lc8 = (lane & 7) << 3;

    f32x4 zero = {0.f, 0.f, 0.f, 0.f};
    f32x4 acc[MF][NF];
    #pragma unroll
    for (int m = 0; m < MF; ++m)
        #pragma unroll
        for (int n = 0; n < NF; ++n) acc[m][n] = zero;

    const int nkt = CK ? ((rowTile + BM) >> 6) : (K >> 6);
    for (int kt = 0; kt < nkt; ++kt) {
        const int k0 = kt << 6;
        #pragma unroll
        for (int i = 0; i < BM / 32; ++i) {
            int c = i * 4 + wid;
            gload16(Ab + (size_t)(rowTile + c * 8 + lr) * lda + k0 + lc8, &sA[c * 512]);
        }
        #pragma unroll
        for (int i = 0; i < BN / 32; ++i) {
            int c = i * 4 + wid;
            gload16(Bb + (size_t)(colTile + c * 8 + lr) * ldb + k0 + lc8, &sB[c * 512]);
        }
        asm volatile("s_waitcnt vmcnt(0)" ::: "memory");
        __syncthreads();
        #pragma unroll
        for (int kk = 0; kk < 2; ++kk) {
            const int ko = kk * 32 + (lane >> 4) * 8;
            bf16x8 af[MF], bfv[NF];
            #pragma unroll
            for (int m = 0; m < MF; ++m)
                af[m] = *(const bf16x8*)&sA[(wr * (BM / WGM) + m * 16 + (lane & 15)) * 64 + ko];
            #pragma unroll
            for (int n = 0; n < NF; ++n)
                bfv[n] = *(const bf16x8*)&sB[(wc * (BN / WGN) + n * 16 + (lane & 15)) * 64 + ko];
            #pragma unroll
            for (int m = 0; m < MF; ++m)
                #pragma unroll
                for (int n = 0; n < NF; ++n)
                    acc[m][n] = __builtin_amdgcn_mfma_f32_16x16x32_bf16(af[m], bfv[n], acc[m][n], 0, 0, 0);
        }
        __syncthreads();
    }

    const ll offC = zo * offCo + zi * offCi;
    #pragma unroll
    for (int m = 0; m < MF; ++m) {
        #pragma unroll
        for (int n = 0; n < NF; ++n) {
            const int col = colTile + wc * (BN / WGN) + n * 16 + (lane & 15);
            float bvv = 0.f;
            if constexpr (BIASK == 1) bvv = inp(bias, bias_off + col, md);
            if constexpr (BIASK == 2) bvv = ((const float*)bias)[bias_off + col];
            #pragma unroll
            for (int r = 0; r < 4; ++r) {
                const int row = rowTile + wr * (BM / WGM) + m * 16 + ((lane >> 4) << 2) + r;
                float xv = acc[m][n][r] * scale + bvv;
                if constexpr (GELU) xv = 0.5f * xv * (1.f + erff(xv * 0.70710678118654752f));
                const size_t idx = (size_t)row * ldc + col;
                if (r1) xv += r1[idx];
                if (r2) xv += r2[idx];
                if constexpr (OUTK == 1)      ((u16*)Cv)[offC + idx] = f2b(xv);
                else if constexpr (OUTK == 0) ((float*)Cv)[offC + idx] = xv;
                else {
                    if (md) ((u16*)Cv)[offC + idx] = f2b(xv);
                    else    ((float*)Cv)[offC + idx] = xv;
                }
            }
        }
    }
}

// ------- transpose input weight (bf16 OR f32) -> bf16 ---------------------------------
__global__ __launch_bounds__(256)
void transpose_k(const void* __restrict__ in, u16* __restrict__ out,
                 int R, int C, int ins, int outs,
                 ll base, ll iStride, ll oStride,
                 const int* __restrict__ modeflag)
{
    __shared__ u16 tile[32][33];
    const int md = *modeflag;
    const int z = blockIdx.z;
    const ll ioff = base + (ll)z * iStride;
    u16* op = out + (ll)z * oStride;
    const int tx = threadIdx.x & 31, ty = threadIdx.x >> 5;
    const int c0 = blockIdx.x * 32, r0 = blockIdx.y * 32;
    #pragma unroll
    for (int i = 0; i < 32; i += 8) {
        int r = r0 + ty + i, c = c0 + tx;
        if (r < R && c < C) tile[ty + i][tx] = f2b(inp(in, ioff + (ll)r * ins + c, md));
    }
    __syncthreads();
    #pragma unroll
    for (int i = 0; i < 32; i += 8) {
        int c = c0 + ty + i, r = r0 + tx;
        if (c < C && r < R) op[(size_t)c * outs + r] = tile[tx][ty + i];
    }
}

// ------- fused per-layer weight transposes: QKV + O + In + Out in ONE launch ----------
__global__ __launch_bounds__(256)
void transw_k(const void* __restrict__ Qw, const void* __restrict__ Kw,
              const void* __restrict__ Vw, const void* __restrict__ Ow,
              const void* __restrict__ Inw, const void* __restrict__ Outw,
              u16* __restrict__ WqkvT, u16* __restrict__ WoT,
              u16* __restrict__ WinT, u16* __restrict__ WoutT,
              int l, const int* __restrict__ modeflag)
{
    __shared__ u16 tile[32][33];
    const int md = *modeflag;
    const int b = blockIdx.x;
    const void* in; u16* out; int ins, outs, tx_, ty_; ll ibase;
    if (b < 1728) {
        const int seg = b / 576, rem = b % 576, hd = rem / 48, tt = rem % 48;
        in = seg == 0 ? Qw : (seg == 1 ? Kw : Vw);
        ibase = (ll)l * cH * cD * cDH + (ll)hd * cD * cDH;
        out = WqkvT + (ll)seg * cD * cD + (ll)hd * cDH * cD;
        ins = cDH; outs = cD; tx_ = tt % 2; ty_ = tt / 2;
    } else if (b < 2304) {
        const int tt = b - 1728;
        in = Ow; ibase = (ll)l * cD * cD; out = WoT;
        ins = cD; outs = cD; tx_ = tt % 24; ty_ = tt / 24;
    } else if (b < 4608) {
        const int tt = b - 2304;
        in = Inw; ibase = (ll)l * cD * cM; out = WinT;
        ins = cM; outs = cD; tx_ = tt % 96; ty_ = tt / 96;
    } else {
        const int tt = b - 4608;
        in = Outw; ibase = (ll)l * cM * cD; out = WoutT;
        ins = cD; outs = cM; tx_ = tt % 24; ty_ = tt / 24;
    }
    const int tx = threadIdx.x & 31, ty = threadIdx.x >> 5;
    const int c0 = tx_ * 32, r0 = ty_ * 32;
    #pragma unroll
    for (int i = 0; i < 32; i += 8)
        tile[ty + i][tx] = f2b(inp(in, ibase + (ll)(r0 + ty + i) * ins + c0 + tx, md));
    __syncthreads();
    #pragma unroll
    for (int i = 0; i < 32; i += 8)
        out[(size_t)(c0 + ty + i) * outs + (r0 + tx)] = tile[tx][ty + i];
}

// ---- bf16 transpose for internal V slice (qkv cols) ----------------------------------
__global__ __launch_bounds__(256)
void transpose_b_k(const u16* __restrict__ in, u16* __restrict__ out,
                   int R, int C, int ins, int outs,
                   ll iOo, ll iOi, ll oOo, ll oOi, int HB)
{
    __shared__ u16 tile[32][33];
    const int z = blockIdx.z;
    const u16* ip = in  + (ll)(z / HB) * iOo + (ll)(z % HB) * iOi;
    u16*       op = out + (ll)(z / HB) * oOo + (ll)(z % HB) * oOi;
    const int tx = threadIdx.x & 31, ty = threadIdx.x >> 5;
    const int c0 = blockIdx.x * 32, r0 = blockIdx.y * 32;
    #pragma unroll
    for (int i = 0; i < 32; i += 8) {
        int r = r0 + ty + i, c = c0 + tx;
        if (r < R && c < C) tile[ty + i][tx] = ip[(size_t)r * ins + c];
    }
    __syncthreads();
    #pragma unroll
    for (int i = 0; i < 32; i += 8) {
        int c = c0 + ty + i, r = r0 + tx;
        if (c < C && r < R) op[(size_t)c * outs + r] = tile[tx][ty + i];
    }
}

// ---------------- embedding: res = E[x] + P (f32 out) ---------------------------------
__global__ __launch_bounds__(192)
void embed_k(const int* __restrict__ x, const void* __restrict__ E,
             const void* __restrict__ P, float* __restrict__ res,
             const int* __restrict__ modeflag)
{
    const int md = *modeflag;
    const int tok = blockIdx.x, t = threadIdx.x;
    const int s = tok & (cS - 1);
    const ll  eb = (ll)x[tok] * cD, pb = (ll)s * cD;
    float4 o;
    o.x = inp(E, eb + t * 4 + 0, md) + inp(P, pb + t * 4 + 0, md);
    o.y = inp(E, eb + t * 4 + 1, md) + inp(P, pb + t * 4 + 1, md);
    o.z = inp(E, eb + t * 4 + 2, md) + inp(P, pb + t * 4 + 2, md);
    o.w = inp(E, eb + t * 4 + 3, md) + inp(P, pb + t * 4 + 3, md);
    ((float4*)(res + (size_t)tok * cD))[t] = o;
}

// ---------------- layernorm (unbiased std, ddof=1), f32 in, bf16 out ------------------
__global__ __launch_bounds__(192)
void ln_k(const float* __restrict__ in, const void* __restrict__ w,
          const void* __restrict__ b, ll wb_off, u16* __restrict__ out,
          const int* __restrict__ modeflag)
{
    __shared__ float sm[8];
    const int md = *modeflag;
    const int row = blockIdx.x, t = threadIdx.x;
    const float4 x = ((const float4*)(in + (size_t)row * cD))[t];
    float s = wave_sum(x.x + x.y + x.z + x.w);
    const int lane = t & 63, wv = t >> 6;
    if (!lane) sm[wv] = s;
    __syncthreads();
    const float mu = (sm[0] + sm[1] + sm[2]) * (1.f / (float)cD);
    const float dx = x.x - mu, dy = x.y - mu, dz = x.z - mu, dw = x.w - mu;
    float ss = wave_sum(dx * dx + dy * dy + dz * dz + dw * dw);
    if (!lane) sm[4 + wv] = ss;
    __syncthreads();
    const float var = (sm[4] + sm[5] + sm[6]) * (1.f / (float)(cD - 1));
    const float rs  = 1.f / sqrtf(var);
    const ll o4 = wb_off + (ll)t * 4;
    ushort4 o;
    o.x = f2b(inp(w, o4 + 0, md) * (dx * rs) + inp(b, o4 + 0, md));
    o.y = f2b(inp(w, o4 + 1, md) * (dy * rs) + inp(b, o4 + 1, md));
    o.z = f2b(inp(w, o4 + 2, md) * (dz * rs) + inp(b, o4 + 2, md));
    o.w = f2b(inp(w, o4 + 3, md) * (dw * rs) + inp(b, o4 + 3, md));
    ((ushort4*)(out + (size_t)row * cD))[t] = o;
}

// ------- causal softmax, 4 rows/block, 1 wave per row, barrier-free, full writes ------
__global__ __launch_bounds__(256)
void softmax4_k(u16* __restrict__ p)
{
    const int row = blockIdx.x * 4 + (threadIdx.x >> 6);
    const int q = row & (cS - 1);
    u16* pr = p + (size_t)row * cS;
    const int lane = threadIdx.x & 63;

    ushort4 v[4];
    float xs[16];
    float mx = -3.4e38f;
    #pragma unroll
    for (int c = 0; c < 4; ++c) {
        const int j0 = (lane + c * 64) * 4;
        v[c] = make_ushort4(0, 0, 0, 0);
        if (j0 <= q) v[c] = ((const ushort4*)pr)[lane + c * 64];
        xs[c * 4 + 0] = (j0 + 0 <= q) ? b2f(v[c].x) : -100000.f;
        xs[c * 4 + 1] = (j0 + 1 <= q) ? b2f(v[c].y) : -100000.f;
        xs[c * 4 + 2] = (j0 + 2 <= q) ? b2f(v[c].z) : -100000.f;
        xs[c * 4 + 3] = (j0 + 3 <= q) ? b2f(v[c].w) : -100000.f;
        mx = fmaxf(mx, fmaxf(fmaxf(xs[c * 4], xs[c * 4 + 1]), fmaxf(xs[c * 4 + 2], xs[c * 4 + 3])));
    }
    mx = wave_max(mx);
    float sum = 0.f;
    #pragma unroll
    for (int j = 0; j < 16; ++j) {
        xs[j] = expf(xs[j] - mx);
        sum += xs[j];
    }
    sum = wave_sum(sum);
    const float inv = 1.f / sum;
    #pragma unroll
    for (int c = 0; c < 4; ++c) {
        ushort4 o;
        o.x = f2b(xs[c * 4 + 0] * inv);
        o.y = f2b(xs[c * 4 + 1] * inv);
        o.z = f2b(xs[c * 4 + 2] * inv);
        o.w = f2b(xs[c * 4 + 3] * inv);
        ((ushort4*)pr)[lane + c * 64] = o;
    }
}

// =====================================================================================
extern "C" void kernel_launch(void* const* d_in, const int* in_sizes, int n_in,
                              void* d_out, int out_size, void* d_ws, size_t ws_size,
                              hipStream_t stream)
{
    (void)in_sizes; (void)n_in; (void)out_size;
    const int*  x     = (const int*)d_in[0];
    const void* E_w   = d_in[1];
    const void* P_w   = d_in[2];
    const void* ln1_w = d_in[3];
    const void* ln1_b = d_in[4];
    const void* Q_w   = d_in[5];
    const void* Q_b   = d_in[6];
    const void* K_w   = d_in[7];
    const void* K_b   = d_in[8];
    const void* V_w   = d_in[9];
    const void* V_b   = d_in[10];
    const void* O_w   = d_in[11];
    const void* O_b   = d_in[12];
    const void* ln2_w = d_in[13];
    const void* ln2_b = d_in[14];
    const void* In_w  = d_in[15];
    const void* In_b  = d_in[16];
    const void* Out_w = d_in[17];
    const void* Out_b = d_in[18];
    const void* lnf_w = d_in[19];
    const void* lnf_b = d_in[20];
    const void* U_w   = d_in[21];
    const void* U_b   = d_in[22];

    // ---- workspace carve with aliasing (~99 MB) ----
    char* wp = (char*)d_ws;
    auto carve = [&](size_t bytes) { char* r = wp; wp += (bytes + 255) & ~(size_t)255; return r; };
    int*   modeflag = (int*)carve(256);
    float* biasQKV  = (float*)carve((size_t)cL * cQKV * 4);
    float* res   = (float*)carve((size_t)cT * cD * 4);
    float* resat = (float*)carve((size_t)cT * cD * 4);
    u16* h     = (u16*)carve((size_t)cT * cD * 2);
    u16* attnb = (u16*)carve((size_t)cT * cD * 2);
    u16* vt    = (u16*)carve((size_t)cT * cD * 2);
    u16* qkv   = (u16*)carve((size_t)cT * cM * 2);       // aliased by mlpb
    u16* mlpb  = qkv;
    u16* WqkvT = (u16*)carve((size_t)cQKV * cD * 2);
    u16* WoT   = (u16*)carve((size_t)cD * cD * 2);
    u16* WinT  = (u16*)carve((size_t)cD * cM * 2);
    u16* WoutT = (u16*)carve((size_t)cD * cM * 2);
    u16* pbuf  = (u16*)carve((size_t)cBH * cS * cS * 2);
    u16* WuT   = pbuf;                                   // alias (pbuf dead after layers)

    if (ws_size && (size_t)(wp - (char*)d_ws) > ws_size) return;  // tripwire

    detect_k<<<1, 64, 0, stream>>>((const uint*)E_w, modeflag);
    packbias_k<<<(cL * cQKV) / 256, 256, 0, stream>>>(Q_b, K_b, V_b, biasQKV, modeflag);
    embed_k<<<cT, 192, 0, stream>>>(x, E_w, P_w, res, modeflag);

    for (int l = 0; l < cL; ++l) {
        // fused weight transposes for this layer (1 launch)
        transw_k<<<6912, 256, 0, stream>>>(Q_w, K_w, V_w, O_w, In_w, Out_w,
                                           WqkvT, WoT, WinT, WoutT, l, modeflag);

        // LN1
        ln_k<<<cT, 192, 0, stream>>>(res, ln1_w, ln1_b, (ll)l * cD, h, modeflag);

        // fused QKV projection: 64x128 tiles -> 576 blocks (2.25/CU)
        gemm_bt<64, 128, 1, 4, 1, false, true, false, false, 2>
            <<<dim3(cT / 64, cQKV / 128, 1), 256, 0, stream>>>(
            h, cD, 0, 0, WqkvT, cD, 0, 0, qkv, cQKV, 0, 0, 1, cD,
            biasQKV, (ll)l * cQKV, 1.f, nullptr, nullptr, modeflag);

        // V slice -> vt [B,H,DH,S]
        transpose_b_k<<<dim3(2, cS / 32, cBH), 256, 0, stream>>>(
            qkv + 2 * cD, vt, cS, cDH, cQKV, cS,
            (ll)cS * cQKV, cDH, (ll)cH * cDH * cS, (ll)cDH * cS, cH);

        // logits = Q K^T * 1/8, batched over (b,h), compact triangular grid (36 tiles)
        gemm_bt<128, 128, 2, 2, 1, false, false, true, false, 0>
            <<<dim3(36, 1, cBH), 256, 0, stream>>>(
            qkv, cQKV, (ll)cS * cQKV, cDH,
            qkv + cD, cQKV, (ll)cS * cQKV, cDH,
            pbuf, cS, (ll)cH * cS * cS, (ll)cS * cS,
            cH, cDH, nullptr, 0, 0.125f, nullptr, nullptr, modeflag);

        // causal softmax: 4 rows/block, barrier-free
        softmax4_k<<<cBH * cS / 4, 256, 0, stream>>>(pbuf);

        // attn = P V, batched, causal K-limit; 64x64 tiles -> 384 blocks
        gemm_bt<64, 64, 2, 2, 1, false, false, false, true, 0>
            <<<dim3(1, 16, cBH), 256, 0, stream>>>(
            pbuf, cS, (ll)cH * cS * cS, (ll)cS * cS,
            vt, cS, (ll)cH * cDH * cS, (ll)cDH * cS,
            attnb, cD, (ll)cS * cD, cDH,
            cH, cS, nullptr, 0, 1.f, nullptr, nullptr, modeflag);

        // O projection + residual -> resat (f32)
        gemm_bt<128, 128, 2, 2, 0, false, true, false, false, 1>
            <<<dim3(cT / 128, cD / 128, 1), 256, 0, stream>>>(
            attnb, cD, 0, 0, WoT, cD, 0, 0, resat, cD, 0, 0, 1, cD,
            O_b, (ll)l * cD, 1.f, res, nullptr, modeflag);

        // LN2
        ln_k<<<cT, 192, 0, stream>>>(resat, ln2_w, ln2_b, (ll)l * cD, h, modeflag);

        // MLP in: 64x128 tiles -> 768 blocks (3/CU): gelu(h @ Win + bIn)
        gemm_bt<64, 128, 1, 4, 1, true, true, false, false, 1>
            <<<dim3(cT / 64, cM / 128, 1), 256, 0, stream>>>(
            h, cD, 0, 0, WinT, cD, 0, 0, mlpb, cM, 0, 0, 1, cD,
            In_b, (ll)l * cM, 1.f, nullptr, nullptr, modeflag);

        // MLP out + double residual (64^2 tiles -> 384 blocks)
        gemm_bt<64, 64, 2, 2, 0, false, true, false, false, 1>
            <<<dim3(cT / 64, cD / 64, 1), 256, 0, stream>>>(
            mlpb, cM, 0, 0, WoutT, cM, 0, 0, res, cD, 0, 0, 1, cM,
            Out_b, (ll)l * cD, 1.f, res, resat, modeflag);
    }

    // unembed weight transpose (WuT aliases pbuf), final LN, unembed (8-phase template)
    transpose_k<<<dim3(cV / 32, cD / 32, 1), 256, 0, stream>>>(
        U_w, WuT, cD, cV, cV, cD, 0, 0, 0, modeflag);
    ln_k<<<cT, 192, 0, stream>>>(res, lnf_w, lnf_b, 0, h, modeflag);
    gemm8p<2, false, 1><<<dim3(cT / 256, cV / 256, 1), 512, 0, stream>>>(
        h, cD, WuT, cD, d_out, cV, cD, U_b, 0, modeflag);
}

// Round 12
// 1078.461 us; speedup vs baseline: 1.1556x; 1.0058x over previous
//
#include <hip/hip_runtime.h>

using uint = unsigned int;
using u16  = unsigned short;
using ll   = long long;

constexpr int cL = 4, cH = 12, cDH = 64, cD = 768, cM = 3072, cV = 32000, cS = 1024, cB = 2;
constexpr int cT  = cB * cS;   // 2048 tokens
constexpr int cBH = cB * cH;   // 24
constexpr int cQKV = 3 * cD;   // 2304

using bf16x8 = __bf16 __attribute__((ext_vector_type(8)));
using f32x4  = float  __attribute__((ext_vector_type(4)));

__device__ __forceinline__ float b2f(u16 u) {
    union { uint i; float f; } v; v.i = ((uint)u) << 16; return v.f;
}
__device__ __forceinline__ u16 f2b(float f) {
    union { float f; uint i; } v; v.f = f;
    uint u = v.i;
    return (u16)((u + 0x7fffu + ((u >> 16) & 1u)) >> 16);   // RNE
}
// read input element `idx` as float, per mode (1 = bf16, 0 = f32)
__device__ __forceinline__ float inp(const void* p, ll idx, int md) {
    return md ? b2f(((const u16*)p)[idx]) : ((const float*)p)[idx];
}
__device__ __forceinline__ float wave_sum(float v) {
    #pragma unroll
    for (int m = 32; m; m >>= 1) v += __shfl_xor(v, m);
    return v;
}
__device__ __forceinline__ float wave_max(float v) {
    #pragma unroll
    for (int m = 32; m; m >>= 1) v = fmaxf(v, __shfl_xor(v, m));
    return v;
}
__device__ __forceinline__ void gload16(const u16* g, u16* l) {
    __builtin_amdgcn_global_load_lds(
        (const __attribute__((address_space(1))) uint*)g,
        (__attribute__((address_space(3))) uint*)l,
        16, 0, 0);
}

// ---------------- dtype detector ------------------------------------------------------
__global__ void detect_k(const uint* __restrict__ e, int* __restrict__ flag)
{
    const int l = threadIdx.x;
    int hits = 0;
    #pragma unroll
    for (int i = 0; i < 4; ++i) {
        uint w  = e[l * 4 + i];
        uint ex = (w >> 7) & 0xffu;
        hits += (ex >= 100u && ex <= 126u) ? 1 : 0;
    }
    float s = wave_sum((float)hits);
    if (l == 0) *flag = (s >= 128.f) ? 1 : 0;   // 1 = bf16 inputs, 0 = f32 inputs
}

// ---------------- pack QKV biases -> f32 [L][2304] ------------------------------------
__global__ __launch_bounds__(256)
void packbias_k(const void* __restrict__ Qb, const void* __restrict__ Kb,
                const void* __restrict__ Vb, float* __restrict__ out,
                const int* __restrict__ modeflag)
{
    const int md = *modeflag;
    const int i = blockIdx.x * 256 + threadIdx.x;   // i < L*2304
    const int l = i / cQKV, c = i % cQKV;
    float v;
    if (c < cD)           v = inp(Qb, (ll)l * cD + c, md);
    else if (c < 2 * cD)  v = inp(Kb, (ll)l * cD + c - cD, md);
    else                  v = inp(Vb, (ll)l * cD + c - 2 * cD, md);
    out[i] = v;
}

// =============== gemm8p: kept for revert (uninstantiated this round) ==================
template<int OUTK, bool GELU, int BIASK>
__global__ __launch_bounds__(512, 1)
void gemm8p(const u16* __restrict__ A, int lda,
            const u16* __restrict__ Bt, int ldb,
            void* __restrict__ Cv, int ldc, int K,
            const void* __restrict__ bias, ll bias_off,
            const int* __restrict__ modeflag)
{
    __shared__ __align__(16) u16 lds[2 * 32768];

    const int nwg = gridDim.x * gridDim.y;
    const int lin = blockIdx.y * gridDim.x + blockIdx.x;
    const int q8 = nwg >> 3, r8 = nwg & 7;
    const int xcd = lin & 7, idx = lin >> 3;
    const int n_  = (xcd < r8 ? xcd * (q8 + 1) : r8 * (q8 + 1) + (xcd - r8) * q8) + idx;
    const int rowTile = (n_ % gridDim.x) * 256;
    const int colTile = (n_ / gridDim.x) * 256;

    const int md = *modeflag;
    const int tid = threadIdx.x;
    const int lane = tid & 63, wid = tid >> 6;
    const int wr = wid >> 2, wc = wid & 3;
    const int l15 = lane & 15, l16 = lane >> 4;
    const int nt = K >> 6;
    const int niter = nt >> 1;

    auto stA = [&](int t, int h) {
        #pragma unroll
        for (int j = 0; j < 2; ++j) {
            const int r = h * 128 + j * 64 + (tid >> 3);
            const int g = tid & 7;
            gload16(A + (size_t)(rowTile + r) * lda + t * 64 + ((g ^ (r & 7)) << 3),
                    &lds[(t & 1) * 32768 + (h * 128 + j * 64 + (wid << 3)) * 64]);
        }
    };
    auto stB = [&](int t, int h) {
        #pragma unroll
        for (int j = 0; j < 2; ++j) {
            const int r = h * 128 + j * 64 + (tid >> 3);
            const int g = tid & 7;
            gload16(Bt + (size_t)(colTile + r) * ldb + t * 64 + ((g ^ (r & 7)) << 3),
                    &lds[(t & 1) * 32768 + 16384 + (h * 128 + j * 64 + (wid << 3)) * 64]);
        }
    };

    f32x4 acc[8][4];
    #pragma unroll
    for (int m = 0; m < 8; ++m)
        #pragma unroll
        for (int n = 0; n < 4; ++n) acc[m][n] = f32x4{0.f, 0.f, 0.f, 0.f};

    bf16x8 af[4][2], bv[2][2];

#define RD_A(BUF, MH)                                                                  \
    { _Pragma("unroll") for (int m = 0; m < 4; ++m) {                                  \
        const int row = (MH) * 128 + wr * 64 + m * 16 + l15;                           \
        _Pragma("unroll") for (int ks = 0; ks < 2; ++ks) {                             \
            const int sg = (ks * 4 + l16) ^ (row & 7);                                 \
            af[m][ks] = *(const bf16x8*)&lds[(BUF) + row * 64 + sg * 8]; } } }
#define RD_B(BUF, NH)                                                                  \
    { _Pragma("unroll") for (int nn = 0; nn < 2; ++nn) {                               \
        const int row = (NH) * 128 + wc * 32 + nn * 16 + l15;                          \
        _Pragma("unroll") for (int ks = 0; ks < 2; ++ks) {                             \
            const int sg = (ks * 4 + l16) ^ (row & 7);                                 \
            bv[nn][ks] = *(const bf16x8*)&lds[(BUF) + 16384 + row * 64 + sg * 8]; } } }
#define MFMA_Q(MO, NO)                                                                 \
    __builtin_amdgcn_s_barrier();                                                      \
    asm volatile("s_waitcnt lgkmcnt(0)" ::: "memory");                                 \
    __builtin_amdgcn_sched_barrier(0);                                                 \
    __builtin_amdgcn_s_setprio(1);                                                     \
    { _Pragma("unroll") for (int m = 0; m < 4; ++m)                                    \
      _Pragma("unroll") for (int nn = 0; nn < 2; ++nn)                                 \
      _Pragma("unroll") for (int ks = 0; ks < 2; ++ks)                                 \
        acc[(MO) + m][(NO) + nn] =                                                     \
            __builtin_amdgcn_mfma_f32_16x16x32_bf16(af[m][ks], bv[nn][ks],             \
                                                    acc[(MO) + m][(NO) + nn], 0, 0, 0); } \
    __builtin_amdgcn_s_setprio(0);                                                     \
    __builtin_amdgcn_s_barrier();

    stA(0, 0); stB(0, 1); stA(0, 1); stB(0, 0);
    asm volatile("s_waitcnt vmcnt(4)" ::: "memory");
    stA(1, 0); stB(1, 1); stA(1, 1);
    asm volatile("s_waitcnt vmcnt(6)" ::: "memory");
    __builtin_amdgcn_s_barrier();

    for (int it = 0; it < niter; ++it) {
        const int a = 2 * it, b = a + 1;
        const bool more = (it + 1 < niter);
        RD_A(0, 0) RD_B(0, 0)
        stB(b, 0);
        MFMA_Q(0, 0)
        RD_B(0, 1)
        if (more) stA(a + 2, 0);
        MFMA_Q(0, 2)
        RD_A(0, 1)
        if (more) stB(a + 2, 1);
        MFMA_Q(4, 2)
        RD_B(0, 0)
        if (more) {
            stA(a + 2, 1);
            asm volatile("s_waitcnt vmcnt(6)" ::: "memory");
        } else {
            asm volatile("s_waitcnt vmcnt(0)" ::: "memory");
        }
        MFMA_Q(4, 0)
        RD_A(32768, 0) RD_B(32768, 0)
        if (more) stB(a + 2, 0);
        MFMA_Q(0, 0)
        RD_B(32768, 1)
        if (more) stA(b + 2, 0);
        MFMA_Q(0, 2)
        RD_A(32768, 1)
        if (more) stB(b + 2, 1);
        MFMA_Q(4, 2)
        RD_B(32768, 0)
        if (more) {
            stA(b + 2, 1);
            asm volatile("s_waitcnt vmcnt(6)" ::: "memory");
        }
        MFMA_Q(4, 0)
    }
#undef RD_A
#undef RD_B
#undef MFMA_Q

    #pragma unroll
    for (int n = 0; n < 4; ++n) {
        const int col = colTile + (n >> 1) * 128 + wc * 32 + (n & 1) * 16 + l15;
        float bvv = 0.f;
        if constexpr (BIASK == 1) bvv = inp(bias, bias_off + col, md);
        if constexpr (BIASK == 2) bvv = ((const float*)bias)[bias_off + col];
        #pragma unroll
        for (int m = 0; m < 8; ++m) {
            const int rbase = rowTile + (m >> 2) * 128 + wr * 64 + (m & 3) * 16 + l16 * 4;
            #pragma unroll
            for (int r = 0; r < 4; ++r) {
                float xv = acc[m][n][r] + bvv;
                if constexpr (GELU) xv = 0.5f * xv * (1.f + erff(xv * 0.70710678118654752f));
                const size_t idx = (size_t)(rbase + r) * ldc + col;
                if constexpr (OUTK == 1)      ((u16*)Cv)[idx] = f2b(xv);
                else if constexpr (OUTK == 0) ((float*)Cv)[idx] = xv;
                else {
                    if (md) ((u16*)Cv)[idx] = f2b(xv);
                    else    ((float*)Cv)[idx] = xv;
                }
            }
        }
    }
}

// ---------------- GEMM (m97-style, 4 waves) — small/odd shapes ------------------------
// CSKIP: causal QK^T compact triangular grid. XCDS: bijective XCD swizzle on 2D grid
// (x-fastest row tiles; consecutive same-XCD blocks share the B col-panel).
template<int BM, int BN, int WGM, int WGN, int OUTK, bool GELU,
         bool COLMAJ, bool CSKIP, bool CK, int BIASK, bool XCDS = false>
__global__ __launch_bounds__(256)
void gemm_bt(const u16* __restrict__ A, int lda, ll offAo, ll offAi,
             const u16* __restrict__ Bt, int ldb, ll offBo, ll offBi,
             void* __restrict__ Cv, int ldc, ll offCo, ll offCi,
             int HB, int K,
             const void* __restrict__ bias, ll bias_off, float scale,
             const float* __restrict__ r1, const float* __restrict__ r2,
             const int* __restrict__ modeflag)
{
    constexpr int MF = BM / WGM / 16;
    constexpr int NF = BN / WGN / 16;
    static_assert(BM % (WGM * 16) == 0 && BN % (WGN * 16) == 0, "tile/wave mismatch");
    static_assert(WGM * WGN == 4, "4 waves");
    __shared__ __align__(16) u16 sA[BM * 64];
    __shared__ __align__(16) u16 sB[BN * 64];

    int rowTile, colTile;
    if constexpr (CSKIP) {
        const int bi = blockIdx.x;
        int r = (int)((sqrtf(8.f * bi + 1.f) - 1.f) * 0.5f);
        while ((r + 1) * (r + 2) / 2 <= bi) ++r;
        while (r * (r + 1) / 2 > bi) --r;
        rowTile = r * BM;
        colTile = (bi - r * (r + 1) / 2) * BN;
    } else if constexpr (XCDS) {
        const int nwg = gridDim.x * gridDim.y;
        const int lin = blockIdx.y * gridDim.x + blockIdx.x;
        const int q8 = nwg >> 3, r8 = nwg & 7;
        const int xcd = lin & 7, idx = lin >> 3;
        const int n_  = (xcd < r8 ? xcd * (q8 + 1) : r8 * (q8 + 1) + (xcd - r8) * q8) + idx;
        rowTile = (n_ % gridDim.x) * BM;
        colTile = (n_ / gridDim.x) * BN;
    } else {
        rowTile = (COLMAJ ? blockIdx.x : blockIdx.y) * BM;
        colTile = (COLMAJ ? blockIdx.y : blockIdx.x) * BN;
    }

    const int md = *modeflag;
    const int z = blockIdx.z;
    const ll zo = z / HB, zi = z % HB;
    const u16* Ab = A + zo * offAo + zi * offAi;
    const u16* Bb = Bt + zo * offBo + zi * offBi;

    const int tid  = threadIdx.x;
    const int lane = tid & 63, wid = tid >> 6;
    const int wr = wid / WGN, wc = wid % WGN;
    const int lr = lane >> 3, lc8 = (lane & 7) << 3;

    f32x4 zero = {0.f, 0.f, 0.f, 0.f};
    f32x4 acc[MF][NF];
    #pragma unroll
    for (int m = 0; m < MF; ++m)
        #pragma unroll
        for (int n = 0; n < NF; ++n) acc[m][n] = zero;

    const int nkt = CK ? ((rowTile + BM) >> 6) : (K >> 6);
    for (int kt = 0; kt < nkt; ++kt) {
        const int k0 = kt << 6;
        #pragma unroll
        for (int i = 0; i < BM / 32; ++i) {
            int c = i * 4 + wid;
            gload16(Ab + (size_t)(rowTile + c * 8 + lr) * lda + k0 + lc8, &sA[c * 512]);
        }
        #pragma unroll
        for (int i = 0; i < BN / 32; ++i) {
            int c = i * 4 + wid;
            gload16(Bb + (size_t)(colTile + c * 8 + lr) * ldb + k0 + lc8, &sB[c * 512]);
        }
        asm volatile("s_waitcnt vmcnt(0)" ::: "memory");
        __syncthreads();
        #pragma unroll
        for (int kk = 0; kk < 2; ++kk) {
            const int ko = kk * 32 + (lane >> 4) * 8;
            bf16x8 af[MF], bfv[NF];
            #pragma unroll
            for (int m = 0; m < MF; ++m)
                af[m] = *(const bf16x8*)&sA[(wr * (BM / WGM) + m * 16 + (lane & 15)) * 64 + ko];
            #pragma unroll
            for (int n = 0; n < NF; ++n)
                bfv[n] = *(const bf16x8*)&sB[(wc * (BN / WGN) + n * 16 + (lane & 15)) * 64 + ko];
            #pragma unroll
            for (int m = 0; m < MF; ++m)
                #pragma unroll
                for (int n = 0; n < NF; ++n)
                    acc[m][n] = __builtin_amdgcn_mfma_f32_16x16x32_bf16(af[m], bfv[n], acc[m][n], 0, 0, 0);
        }
        __syncthreads();
    }

    const ll offC = zo * offCo + zi * offCi;
    #pragma unroll
    for (int m = 0; m < MF; ++m) {
        #pragma unroll
        for (int n = 0; n < NF; ++n) {
            const int col = colTile + wc * (BN / WGN) + n * 16 + (lane & 15);
            float bvv = 0.f;
            if constexpr (BIASK == 1) bvv = inp(bias, bias_off + col, md);
            if constexpr (BIASK == 2) bvv = ((const float*)bias)[bias_off + col];
            #pragma unroll
            for (int r = 0; r < 4; ++r) {
                const int row = rowTile + wr * (BM / WGM) + m * 16 + ((lane >> 4) << 2) + r;
                float xv = acc[m][n][r] * scale + bvv;
                if constexpr (GELU) xv = 0.5f * xv * (1.f + erff(xv * 0.70710678118654752f));
                const size_t idx = (size_t)row * ldc + col;
                if (r1) xv += r1[idx];
                if (r2) xv += r2[idx];
                if constexpr (OUTK == 1)      ((u16*)Cv)[offC + idx] = f2b(xv);
                else if constexpr (OUTK == 0) ((float*)Cv)[offC + idx] = xv;
                else {
                    if (md) ((u16*)Cv)[offC + idx] = f2b(xv);
                    else    ((float*)Cv)[offC + idx] = xv;
                }
            }
        }
    }
}

// ------- transpose input weight (bf16 OR f32) -> bf16 ---------------------------------
__global__ __launch_bounds__(256)
void transpose_k(const void* __restrict__ in, u16* __restrict__ out,
                 int R, int C, int ins, int outs,
                 ll base, ll iStride, ll oStride,
                 const int* __restrict__ modeflag)
{
    __shared__ u16 tile[32][33];
    const int md = *modeflag;
    const int z = blockIdx.z;
    const ll ioff = base + (ll)z * iStride;
    u16* op = out + (ll)z * oStride;
    const int tx = threadIdx.x & 31, ty = threadIdx.x >> 5;
    const int c0 = blockIdx.x * 32, r0 = blockIdx.y * 32;
    #pragma unroll
    for (int i = 0; i < 32; i += 8) {
        int r = r0 + ty + i, c = c0 + tx;
        if (r < R && c < C) tile[ty + i][tx] = f2b(inp(in, ioff + (ll)r * ins + c, md));
    }
    __syncthreads();
    #pragma unroll
    for (int i = 0; i < 32; i += 8) {
        int c = c0 + ty + i, r = r0 + tx;
        if (c < C && r < R) op[(size_t)c * outs + r] = tile[tx][ty + i];
    }
}

// ------- fused per-layer weight transposes: QKV + O + In + Out in ONE launch ----------
__global__ __launch_bounds__(256)
void transw_k(const void* __restrict__ Qw, const void* __restrict__ Kw,
              const void* __restrict__ Vw, const void* __restrict__ Ow,
              const void* __restrict__ Inw, const void* __restrict__ Outw,
              u16* __restrict__ WqkvT, u16* __restrict__ WoT,
              u16* __restrict__ WinT, u16* __restrict__ WoutT,
              int l, const int* __restrict__ modeflag)
{
    __shared__ u16 tile[32][33];
    const int md = *modeflag;
    const int b = blockIdx.x;
    const void* in; u16* out; int ins, outs, tx_, ty_; ll ibase;
    if (b < 1728) {
        const int seg = b / 576, rem = b % 576, hd = rem / 48, tt = rem % 48;
        in = seg == 0 ? Qw : (seg == 1 ? Kw : Vw);
        ibase = (ll)l * cH * cD * cDH + (ll)hd * cD * cDH;
        out = WqkvT + (ll)seg * cD * cD + (ll)hd * cDH * cD;
        ins = cDH; outs = cD; tx_ = tt % 2; ty_ = tt / 2;
    } else if (b < 2304) {
        const int tt = b - 1728;
        in = Ow; ibase = (ll)l * cD * cD; out = WoT;
        ins = cD; outs = cD; tx_ = tt % 24; ty_ = tt / 24;
    } else if (b < 4608) {
        const int tt = b - 2304;
        in = Inw; ibase = (ll)l * cD * cM; out = WinT;
        ins = cM; outs = cD; tx_ = tt % 96; ty_ = tt / 96;
    } else {
        const int tt = b - 4608;
        in = Outw; ibase = (ll)l * cM * cD; out = WoutT;
        ins = cD; outs = cM; tx_ = tt % 24; ty_ = tt / 24;
    }
    const int tx = threadIdx.x & 31, ty = threadIdx.x >> 5;
    const int c0 = tx_ * 32, r0 = ty_ * 32;
    #pragma unroll
    for (int i = 0; i < 32; i += 8)
        tile[ty + i][tx] = f2b(inp(in, ibase + (ll)(r0 + ty + i) * ins + c0 + tx, md));
    __syncthreads();
    #pragma unroll
    for (int i = 0; i < 32; i += 8)
        out[(size_t)(c0 + ty + i) * outs + (r0 + tx)] = tile[tx][ty + i];
}

// ---- bf16 transpose for internal V slice (qkv cols) ----------------------------------
__global__ __launch_bounds__(256)
void transpose_b_k(const u16* __restrict__ in, u16* __restrict__ out,
                   int R, int C, int ins, int outs,
                   ll iOo, ll iOi, ll oOo, ll oOi, int HB)
{
    __shared__ u16 tile[32][33];
    const int z = blockIdx.z;
    const u16* ip = in  + (ll)(z / HB) * iOo + (ll)(z % HB) * iOi;
    u16*       op = out + (ll)(z / HB) * oOo + (ll)(z % HB) * oOi;
    const int tx = threadIdx.x & 31, ty = threadIdx.x >> 5;
    const int c0 = blockIdx.x * 32, r0 = blockIdx.y * 32;
    #pragma unroll
    for (int i = 0; i < 32; i += 8) {
        int r = r0 + ty + i, c = c0 + tx;
        if (r < R && c < C) tile[ty + i][tx] = ip[(size_t)r * ins + c];
    }
    __syncthreads();
    #pragma unroll
    for (int i = 0; i < 32; i += 8) {
        int c = c0 + ty + i, r = r0 + tx;
        if (c < C && r < R) op[(size_t)c * outs + r] = tile[tx][ty + i];
    }
}

// ---------------- embedding: res = E[x] + P (f32 out) ---------------------------------
__global__ __launch_bounds__(192)
void embed_k(const int* __restrict__ x, const void* __restrict__ E,
             const void* __restrict__ P, float* __restrict__ res,
             const int* __restrict__ modeflag)
{
    const int md = *modeflag;
    const int tok = blockIdx.x, t = threadIdx.x;
    const int s = tok & (cS - 1);
    const ll  eb = (ll)x[tok] * cD, pb = (ll)s * cD;
    float4 o;
    o.x = inp(E, eb + t * 4 + 0, md) + inp(P, pb + t * 4 + 0, md);
    o.y = inp(E, eb + t * 4 + 1, md) + inp(P, pb + t * 4 + 1, md);
    o.z = inp(E, eb + t * 4 + 2, md) + inp(P, pb + t * 4 + 2, md);
    o.w = inp(E, eb + t * 4 + 3, md) + inp(P, pb + t * 4 + 3, md);
    ((float4*)(res + (size_t)tok * cD))[t] = o;
}

// ---------------- layernorm (unbiased std, ddof=1), f32 in, bf16 out ------------------
__global__ __launch_bounds__(192)
void ln_k(const float* __restrict__ in, const void* __restrict__ w,
          const void* __restrict__ b, ll wb_off, u16* __restrict__ out,
          const int* __restrict__ modeflag)
{
    __shared__ float sm[8];
    const int md = *modeflag;
    const int row = blockIdx.x, t = threadIdx.x;
    const float4 x = ((const float4*)(in + (size_t)row * cD))[t];
    float s = wave_sum(x.x + x.y + x.z + x.w);
    const int lane = t & 63, wv = t >> 6;
    if (!lane) sm[wv] = s;
    __syncthreads();
    const float mu = (sm[0] + sm[1] + sm[2]) * (1.f / (float)cD);
    const float dx = x.x - mu, dy = x.y - mu, dz = x.z - mu, dw = x.w - mu;
    float ss = wave_sum(dx * dx + dy * dy + dz * dz + dw * dw);
    if (!lane) sm[4 + wv] = ss;
    __syncthreads();
    const float var = (sm[4] + sm[5] + sm[6]) * (1.f / (float)(cD - 1));
    const float rs  = 1.f / sqrtf(var);
    const ll o4 = wb_off + (ll)t * 4;
    ushort4 o;
    o.x = f2b(inp(w, o4 + 0, md) * (dx * rs) + inp(b, o4 + 0, md));
    o.y = f2b(inp(w, o4 + 1, md) * (dy * rs) + inp(b, o4 + 1, md));
    o.z = f2b(inp(w, o4 + 2, md) * (dz * rs) + inp(b, o4 + 2, md));
    o.w = f2b(inp(w, o4 + 3, md) * (dw * rs) + inp(b, o4 + 3, md));
    ((ushort4*)(out + (size_t)row * cD))[t] = o;
}

// ------- causal softmax, 4 rows/block, 1 wave per row, barrier-free, full writes ------
__global__ __launch_bounds__(256)
void softmax4_k(u16* __restrict__ p)
{
    const int row = blockIdx.x * 4 + (threadIdx.x >> 6);
    const int q = row & (cS - 1);
    u16* pr = p + (size_t)row * cS;
    const int lane = threadIdx.x & 63;

    ushort4 v[4];
    float xs[16];
    float mx = -3.4e38f;
    #pragma unroll
    for (int c = 0; c < 4; ++c) {
        const int j0 = (lane + c * 64) * 4;
        v[c] = make_ushort4(0, 0, 0, 0);
        if (j0 <= q) v[c] = ((const ushort4*)pr)[lane + c * 64];
        xs[c * 4 + 0] = (j0 + 0 <= q) ? b2f(v[c].x) : -100000.f;
        xs[c * 4 + 1] = (j0 + 1 <= q) ? b2f(v[c].y) : -100000.f;
        xs[c * 4 + 2] = (j0 + 2 <= q) ? b2f(v[c].z) : -100000.f;
        xs[c * 4 + 3] = (j0 + 3 <= q) ? b2f(v[c].w) : -100000.f;
        mx = fmaxf(mx, fmaxf(fmaxf(xs[c * 4], xs[c * 4 + 1]), fmaxf(xs[c * 4 + 2], xs[c * 4 + 3])));
    }
    mx = wave_max(mx);
    float sum = 0.f;
    #pragma unroll
    for (int j = 0; j < 16; ++j) {
        xs[j] = expf(xs[j] - mx);
        sum += xs[j];
    }
    sum = wave_sum(sum);
    const float inv = 1.f / sum;
    #pragma unroll
    for (int c = 0; c < 4; ++c) {
        ushort4 o;
        o.x = f2b(xs[c * 4 + 0] * inv);
        o.y = f2b(xs[c * 4 + 1] * inv);
        o.z = f2b(xs[c * 4 + 2] * inv);
        o.w = f2b(xs[c * 4 + 3] * inv);
        ((ushort4*)pr)[lane + c * 64] = o;
    }
}

// =====================================================================================
extern "C" void kernel_launch(void* const* d_in, const int* in_sizes, int n_in,
                              void* d_out, int out_size, void* d_ws, size_t ws_size,
                              hipStream_t stream)
{
    (void)in_sizes; (void)n_in; (void)out_size;
    const int*  x     = (const int*)d_in[0];
    const void* E_w   = d_in[1];
    const void* P_w   = d_in[2];
    const void* ln1_w = d_in[3];
    const void* ln1_b = d_in[4];
    const void* Q_w   = d_in[5];
    const void* Q_b   = d_in[6];
    const void* K_w   = d_in[7];
    const void* K_b   = d_in[8];
    const void* V_w   = d_in[9];
    const void* V_b   = d_in[10];
    const void* O_w   = d_in[11];
    const void* O_b   = d_in[12];
    const void* ln2_w = d_in[13];
    const void* ln2_b = d_in[14];
    const void* In_w  = d_in[15];
    const void* In_b  = d_in[16];
    const void* Out_w = d_in[17];
    const void* Out_b = d_in[18];
    const void* lnf_w = d_in[19];
    const void* lnf_b = d_in[20];
    const void* U_w   = d_in[21];
    const void* U_b   = d_in[22];

    // ---- workspace carve with aliasing (~99 MB) ----
    char* wp = (char*)d_ws;
    auto carve = [&](size_t bytes) { char* r = wp; wp += (bytes + 255) & ~(size_t)255; return r; };
    int*   modeflag = (int*)carve(256);
    float* biasQKV  = (float*)carve((size_t)cL * cQKV * 4);
    float* res   = (float*)carve((size_t)cT * cD * 4);
    float* resat = (float*)carve((size_t)cT * cD * 4);
    u16* h     = (u16*)carve((size_t)cT * cD * 2);
    u16* attnb = (u16*)carve((size_t)cT * cD * 2);
    u16* vt    = (u16*)carve((size_t)cT * cD * 2);
    u16* qkv   = (u16*)carve((size_t)cT * cM * 2);       // aliased by mlpb
    u16* mlpb  = qkv;
    u16* WqkvT = (u16*)carve((size_t)cQKV * cD * 2);
    u16* WoT   = (u16*)carve((size_t)cD * cD * 2);
    u16* WinT  = (u16*)carve((size_t)cD * cM * 2);
    u16* WoutT = (u16*)carve((size_t)cD * cM * 2);
    u16* pbuf  = (u16*)carve((size_t)cBH * cS * cS * 2);
    u16* WuT   = pbuf;                                   // alias (pbuf dead after layers)

    if (ws_size && (size_t)(wp - (char*)d_ws) > ws_size) return;  // tripwire

    detect_k<<<1, 64, 0, stream>>>((const uint*)E_w, modeflag);
    packbias_k<<<(cL * cQKV) / 256, 256, 0, stream>>>(Q_b, K_b, V_b, biasQKV, modeflag);
    embed_k<<<cT, 192, 0, stream>>>(x, E_w, P_w, res, modeflag);

    for (int l = 0; l < cL; ++l) {
        // fused weight transposes for this layer (1 launch)
        transw_k<<<6912, 256, 0, stream>>>(Q_w, K_w, V_w, O_w, In_w, Out_w,
                                           WqkvT, WoT, WinT, WoutT, l, modeflag);

        // LN1
        ln_k<<<cT, 192, 0, stream>>>(res, ln1_w, ln1_b, (ll)l * cD, h, modeflag);

        // fused QKV projection: 64x128 tiles -> 576 blocks (2.25/CU)
        gemm_bt<64, 128, 1, 4, 1, false, true, false, false, 2>
            <<<dim3(cT / 64, cQKV / 128, 1), 256, 0, stream>>>(
            h, cD, 0, 0, WqkvT, cD, 0, 0, qkv, cQKV, 0, 0, 1, cD,
            biasQKV, (ll)l * cQKV, 1.f, nullptr, nullptr, modeflag);

        // V slice -> vt [B,H,DH,S]
        transpose_b_k<<<dim3(2, cS / 32, cBH), 256, 0, stream>>>(
            qkv + 2 * cD, vt, cS, cDH, cQKV, cS,
            (ll)cS * cQKV, cDH, (ll)cH * cDH * cS, (ll)cDH * cS, cH);

        // logits = Q K^T * 1/8, batched over (b,h), compact triangular grid (36 tiles)
        gemm_bt<128, 128, 2, 2, 1, false, false, true, false, 0>
            <<<dim3(36, 1, cBH), 256, 0, stream>>>(
            qkv, cQKV, (ll)cS * cQKV, cDH,
            qkv + cD, cQKV, (ll)cS * cQKV, cDH,
            pbuf, cS, (ll)cH * cS * cS, (ll)cS * cS,
            cH, cDH, nullptr, 0, 0.125f, nullptr, nullptr, modeflag);

        // causal softmax: 4 rows/block, barrier-free
        softmax4_k<<<cBH * cS / 4, 256, 0, stream>>>(pbuf);

        // attn = P V, batched, causal K-limit; 64x64 tiles -> 384 blocks
        gemm_bt<64, 64, 2, 2, 1, false, false, false, true, 0>
            <<<dim3(1, 16, cBH), 256, 0, stream>>>(
            pbuf, cS, (ll)cH * cS * cS, (ll)cS * cS,
            vt, cS, (ll)cH * cDH * cS, (ll)cDH * cS,
            attnb, cD, (ll)cS * cD, cDH,
            cH, cS, nullptr, 0, 1.f, nullptr, nullptr, modeflag);

        // O projection + residual -> resat (f32)
        gemm_bt<128, 128, 2, 2, 0, false, true, false, false, 1>
            <<<dim3(cT / 128, cD / 128, 1), 256, 0, stream>>>(
            attnb, cD, 0, 0, WoT, cD, 0, 0, resat, cD, 0, 0, 1, cD,
            O_b, (ll)l * cD, 1.f, res, nullptr, modeflag);

        // LN2
        ln_k<<<cT, 192, 0, stream>>>(resat, ln2_w, ln2_b, (ll)l * cD, h, modeflag);

        // MLP in: 64x128 tiles -> 768 blocks (3/CU): gelu(h @ Win + bIn)
        gemm_bt<64, 128, 1, 4, 1, true, true, false, false, 1>
            <<<dim3(cT / 64, cM / 128, 1), 256, 0, stream>>>(
            h, cD, 0, 0, WinT, cD, 0, 0, mlpb, cM, 0, 0, 1, cD,
            In_b, (ll)l * cM, 1.f, nullptr, nullptr, modeflag);

        // MLP out + double residual (64^2 tiles -> 384 blocks)
        gemm_bt<64, 64, 2, 2, 0, false, true, false, false, 1>
            <<<dim3(cT / 64, cD / 64, 1), 256, 0, stream>>>(
            mlpb, cM, 0, 0, WoutT, cM, 0, 0, res, cD, 0, 0, 1, cM,
            Out_b, (ll)l * cD, 1.f, res, resat, modeflag);
    }

    // unembed weight transpose (WuT aliases pbuf), final LN, unembed:
    // 64x128 tiles -> 8000 blocks (~5-6 resident/CU) + bijective XCD swizzle.
    transpose_k<<<dim3(cV / 32, cD / 32, 1), 256, 0, stream>>>(
        U_w, WuT, cD, cV, cV, cD, 0, 0, 0, modeflag);
    ln_k<<<cT, 192, 0, stream>>>(res, lnf_w, lnf_b, 0, h, modeflag);
    gemm_bt<64, 128, 1, 4, 2, false, true, false, false, 1, true>
        <<<dim3(cT / 64, cV / 128, 1), 256, 0, stream>>>(
        h, cD, 0, 0, WuT, cD, 0, 0, d_out, cV, 0, 0, 1, cD,
        U_b, 0, 1.f, nullptr, nullptr, modeflag);
}

// Round 13
// 1018.490 us; speedup vs baseline: 1.2237x; 1.0589x over previous
//
#include <hip/hip_runtime.h>

using uint = unsigned int;
using u16  = unsigned short;
using ll   = long long;

constexpr int cL = 4, cH = 12, cDH = 64, cD = 768, cM = 3072, cV = 32000, cS = 1024, cB = 2;
constexpr int cT  = cB * cS;   // 2048 tokens
constexpr int cBH = cB * cH;   // 24
constexpr int cQKV = 3 * cD;   // 2304

using bf16x8 = __bf16 __attribute__((ext_vector_type(8)));
using f32x4  = float  __attribute__((ext_vector_type(4)));

__device__ __forceinline__ float b2f(u16 u) {
    union { uint i; float f; } v; v.i = ((uint)u) << 16; return v.f;
}
__device__ __forceinline__ u16 f2b(float f) {
    union { float f; uint i; } v; v.f = f;
    uint u = v.i;
    return (u16)((u + 0x7fffu + ((u >> 16) & 1u)) >> 16);   // RNE
}
// read input element `idx` as float, per mode (1 = bf16, 0 = f32)
__device__ __forceinline__ float inp(const void* p, ll idx, int md) {
    return md ? b2f(((const u16*)p)[idx]) : ((const float*)p)[idx];
}
__device__ __forceinline__ float wave_sum(float v) {
    #pragma unroll
    for (int m = 32; m; m >>= 1) v += __shfl_xor(v, m);
    return v;
}
__device__ __forceinline__ float wave_max(float v) {
    #pragma unroll
    for (int m = 32; m; m >>= 1) v = fmaxf(v, __shfl_xor(v, m));
    return v;
}
__device__ __forceinline__ void gload16(const u16* g, u16* l) {
    __builtin_amdgcn_global_load_lds(
        (const __attribute__((address_space(1))) uint*)g,
        (__attribute__((address_space(3))) uint*)l,
        16, 0, 0);
}

// ---------------- dtype detector ------------------------------------------------------
__global__ void detect_k(const uint* __restrict__ e, int* __restrict__ flag)
{
    const int l = threadIdx.x;
    int hits = 0;
    #pragma unroll
    for (int i = 0; i < 4; ++i) {
        uint w  = e[l * 4 + i];
        uint ex = (w >> 7) & 0xffu;
        hits += (ex >= 100u && ex <= 126u) ? 1 : 0;
    }
    float s = wave_sum((float)hits);
    if (l == 0) *flag = (s >= 128.f) ? 1 : 0;   // 1 = bf16 inputs, 0 = f32 inputs
}

// ---------------- pack QKV biases -> f32 [L][2304] ------------------------------------
__global__ __launch_bounds__(256)
void packbias_k(const void* __restrict__ Qb, const void* __restrict__ Kb,
                const void* __restrict__ Vb, float* __restrict__ out,
                const int* __restrict__ modeflag)
{
    const int md = *modeflag;
    const int i = blockIdx.x * 256 + threadIdx.x;   // i < L*2304
    const int l = i / cQKV, c = i % cQKV;
    float v;
    if (c < cD)           v = inp(Qb, (ll)l * cD + c, md);
    else if (c < 2 * cD)  v = inp(Kb, (ll)l * cD + c - cD, md);
    else                  v = inp(Vb, (ll)l * cD + c - 2 * cD, md);
    out[i] = v;
}

// ---------------- GEMM (m97-style, 4 waves) + T2 both-sides LDS swizzle ----------------
// LDS slot (row, gslot) holds global 16B-group (gslot ^ (row&7)); staging pre-swizzles
// the per-lane global source (linear LDS dest per gload_lds rule); reads XOR the group.
// Pattern measured conflict-free & bit-exact in gemm8p (r10).
// CSKIP: causal QK^T compact triangular grid. XCDS: bijective XCD swizzle on 2D grid.
template<int BM, int BN, int WGM, int WGN, int OUTK, bool GELU,
         bool COLMAJ, bool CSKIP, bool CK, int BIASK, bool XCDS = false>
__global__ __launch_bounds__(256)
void gemm_bt(const u16* __restrict__ A, int lda, ll offAo, ll offAi,
             const u16* __restrict__ Bt, int ldb, ll offBo, ll offBi,
             void* __restrict__ Cv, int ldc, ll offCo, ll offCi,
             int HB, int K,
             const void* __restrict__ bias, ll bias_off, float scale,
             const float* __restrict__ r1, const float* __restrict__ r2,
             const int* __restrict__ modeflag)
{
    constexpr int MF = BM / WGM / 16;
    constexpr int NF = BN / WGN / 16;
    static_assert(BM % (WGM * 16) == 0 && BN % (WGN * 16) == 0, "tile/wave mismatch");
    static_assert(WGM * WGN == 4, "4 waves");
    __shared__ __align__(16) u16 sA[BM * 64];
    __shared__ __align__(16) u16 sB[BN * 64];

    int rowTile, colTile;
    if constexpr (CSKIP) {
        const int bi = blockIdx.x;
        int r = (int)((sqrtf(8.f * bi + 1.f) - 1.f) * 0.5f);
        while ((r + 1) * (r + 2) / 2 <= bi) ++r;
        while (r * (r + 1) / 2 > bi) --r;
        rowTile = r * BM;
        colTile = (bi - r * (r + 1) / 2) * BN;
    } else if constexpr (XCDS) {
        const int nwg = gridDim.x * gridDim.y;
        const int lin = blockIdx.y * gridDim.x + blockIdx.x;
        const int q8 = nwg >> 3, r8 = nwg & 7;
        const int xcd = lin & 7, idx = lin >> 3;
        const int n_  = (xcd < r8 ? xcd * (q8 + 1) : r8 * (q8 + 1) + (xcd - r8) * q8) + idx;
        rowTile = (n_ % gridDim.x) * BM;
        colTile = (n_ / gridDim.x) * BN;
    } else {
        rowTile = (COLMAJ ? blockIdx.x : blockIdx.y) * BM;
        colTile = (COLMAJ ? blockIdx.y : blockIdx.x) * BN;
    }

    const int md = *modeflag;
    const int z = blockIdx.z;
    const ll zo = z / HB, zi = z % HB;
    const u16* Ab = A + zo * offAo + zi * offAi;
    const u16* Bb = Bt + zo * offBo + zi * offBi;

    const int tid  = threadIdx.x;
    const int lane = tid & 63, wid = tid >> 6;
    const int wr = wid / WGN, wc = wid % WGN;
    const int lr = lane >> 3;                       // row-in-chunk (== row & 7)
    const int lc8s = (((lane & 7) ^ lr) << 3);      // pre-swizzled global 16B-group

    f32x4 zero = {0.f, 0.f, 0.f, 0.f};
    f32x4 acc[MF][NF];
    #pragma unroll
    for (int m = 0; m < MF; ++m)
        #pragma unroll
        for (int n = 0; n < NF; ++n) acc[m][n] = zero;

    const int nkt = CK ? ((rowTile + BM) >> 6) : (K >> 6);
    for (int kt = 0; kt < nkt; ++kt) {
        const int k0 = kt << 6;
        #pragma unroll
        for (int i = 0; i < BM / 32; ++i) {
            int c = i * 4 + wid;
            gload16(Ab + (size_t)(rowTile + c * 8 + lr) * lda + k0 + lc8s, &sA[c * 512]);
        }
        #pragma unroll
        for (int i = 0; i < BN / 32; ++i) {
            int c = i * 4 + wid;
            gload16(Bb + (size_t)(colTile + c * 8 + lr) * ldb + k0 + lc8s, &sB[c * 512]);
        }
        asm volatile("s_waitcnt vmcnt(0)" ::: "memory");
        __syncthreads();
        #pragma unroll
        for (int kk = 0; kk < 2; ++kk) {
            const int g = kk * 4 + (lane >> 4);     // 16B-group index (0..7)
            bf16x8 af[MF], bfv[NF];
            #pragma unroll
            for (int m = 0; m < MF; ++m) {
                const int row = wr * (BM / WGM) + m * 16 + (lane & 15);
                af[m] = *(const bf16x8*)&sA[row * 64 + ((g ^ (row & 7)) << 3)];
            }
            #pragma unroll
            for (int n = 0; n < NF; ++n) {
                const int row = wc * (BN / WGN) + n * 16 + (lane & 15);
                bfv[n] = *(const bf16x8*)&sB[row * 64 + ((g ^ (row & 7)) << 3)];
            }
            #pragma unroll
            for (int m = 0; m < MF; ++m)
                #pragma unroll
                for (int n = 0; n < NF; ++n)
                    acc[m][n] = __builtin_amdgcn_mfma_f32_16x16x32_bf16(af[m], bfv[n], acc[m][n], 0, 0, 0);
        }
        __syncthreads();
    }

    const ll offC = zo * offCo + zi * offCi;
    #pragma unroll
    for (int m = 0; m < MF; ++m) {
        #pragma unroll
        for (int n = 0; n < NF; ++n) {
            const int col = colTile + wc * (BN / WGN) + n * 16 + (lane & 15);
            float bvv = 0.f;
            if constexpr (BIASK == 1) bvv = inp(bias, bias_off + col, md);
            if constexpr (BIASK == 2) bvv = ((const float*)bias)[bias_off + col];
            #pragma unroll
            for (int r = 0; r < 4; ++r) {
                const int row = rowTile + wr * (BM / WGM) + m * 16 + ((lane >> 4) << 2) + r;
                float xv = acc[m][n][r] * scale + bvv;
                if constexpr (GELU) xv = 0.5f * xv * (1.f + erff(xv * 0.70710678118654752f));
                const size_t idx = (size_t)row * ldc + col;
                if (r1) xv += r1[idx];
                if (r2) xv += r2[idx];
                if constexpr (OUTK == 1)      ((u16*)Cv)[offC + idx] = f2b(xv);
                else if constexpr (OUTK == 0) ((float*)Cv)[offC + idx] = xv;
                else {
                    if (md) ((u16*)Cv)[offC + idx] = f2b(xv);
                    else    ((float*)Cv)[offC + idx] = xv;
                }
            }
        }
    }
}

// ------- transpose input weight (bf16 OR f32) -> bf16 ---------------------------------
__global__ __launch_bounds__(256)
void transpose_k(const void* __restrict__ in, u16* __restrict__ out,
                 int R, int C, int ins, int outs,
                 ll base, ll iStride, ll oStride,
                 const int* __restrict__ modeflag)
{
    __shared__ u16 tile[32][33];
    const int md = *modeflag;
    const int z = blockIdx.z;
    const ll ioff = base + (ll)z * iStride;
    u16* op = out + (ll)z * oStride;
    const int tx = threadIdx.x & 31, ty = threadIdx.x >> 5;
    const int c0 = blockIdx.x * 32, r0 = blockIdx.y * 32;
    #pragma unroll
    for (int i = 0; i < 32; i += 8) {
        int r = r0 + ty + i, c = c0 + tx;
        if (r < R && c < C) tile[ty + i][tx] = f2b(inp(in, ioff + (ll)r * ins + c, md));
    }
    __syncthreads();
    #pragma unroll
    for (int i = 0; i < 32; i += 8) {
        int c = c0 + ty + i, r = r0 + tx;
        if (c < C && r < R) op[(size_t)c * outs + r] = tile[tx][ty + i];
    }
}

// ------- fused per-layer weight transposes: QKV + O + In + Out in ONE launch ----------
__global__ __launch_bounds__(256)
void transw_k(const void* __restrict__ Qw, const void* __restrict__ Kw,
              const void* __restrict__ Vw, const void* __restrict__ Ow,
              const void* __restrict__ Inw, const void* __restrict__ Outw,
              u16* __restrict__ WqkvT, u16* __restrict__ WoT,
              u16* __restrict__ WinT, u16* __restrict__ WoutT,
              int l, const int* __restrict__ modeflag)
{
    __shared__ u16 tile[32][33];
    const int md = *modeflag;
    const int b = blockIdx.x;
    const void* in; u16* out; int ins, outs, tx_, ty_; ll ibase;
    if (b < 1728) {
        const int seg = b / 576, rem = b % 576, hd = rem / 48, tt = rem % 48;
        in = seg == 0 ? Qw : (seg == 1 ? Kw : Vw);
        ibase = (ll)l * cH * cD * cDH + (ll)hd * cD * cDH;
        out = WqkvT + (ll)seg * cD * cD + (ll)hd * cDH * cD;
        ins = cDH; outs = cD; tx_ = tt % 2; ty_ = tt / 2;
    } else if (b < 2304) {
        const int tt = b - 1728;
        in = Ow; ibase = (ll)l * cD * cD; out = WoT;
        ins = cD; outs = cD; tx_ = tt % 24; ty_ = tt / 24;
    } else if (b < 4608) {
        const int tt = b - 2304;
        in = Inw; ibase = (ll)l * cD * cM; out = WinT;
        ins = cM; outs = cD; tx_ = tt % 96; ty_ = tt / 96;
    } else {
        const int tt = b - 4608;
        in = Outw; ibase = (ll)l * cM * cD; out = WoutT;
        ins = cD; outs = cM; tx_ = tt % 24; ty_ = tt / 24;
    }
    const int tx = threadIdx.x & 31, ty = threadIdx.x >> 5;
    const int c0 = tx_ * 32, r0 = ty_ * 32;
    #pragma unroll
    for (int i = 0; i < 32; i += 8)
        tile[ty + i][tx] = f2b(inp(in, ibase + (ll)(r0 + ty + i) * ins + c0 + tx, md));
    __syncthreads();
    #pragma unroll
    for (int i = 0; i < 32; i += 8)
        out[(size_t)(c0 + ty + i) * outs + (r0 + tx)] = tile[tx][ty + i];
}

// ---- bf16 transpose for internal V slice (qkv cols) ----------------------------------
__global__ __launch_bounds__(256)
void transpose_b_k(const u16* __restrict__ in, u16* __restrict__ out,
                   int R, int C, int ins, int outs,
                   ll iOo, ll iOi, ll oOo, ll oOi, int HB)
{
    __shared__ u16 tile[32][33];
    const int z = blockIdx.z;
    const u16* ip = in  + (ll)(z / HB) * iOo + (ll)(z % HB) * iOi;
    u16*       op = out + (ll)(z / HB) * oOo + (ll)(z % HB) * oOi;
    const int tx = threadIdx.x & 31, ty = threadIdx.x >> 5;
    const int c0 = blockIdx.x * 32, r0 = blockIdx.y * 32;
    #pragma unroll
    for (int i = 0; i < 32; i += 8) {
        int r = r0 + ty + i, c = c0 + tx;
        if (r < R && c < C) tile[ty + i][tx] = ip[(size_t)r * ins + c];
    }
    __syncthreads();
    #pragma unroll
    for (int i = 0; i < 32; i += 8) {
        int c = c0 + ty + i, r = r0 + tx;
        if (c < C && r < R) op[(size_t)c * outs + r] = tile[tx][ty + i];
    }
}

// ---------------- embedding: res = E[x] + P (f32 out) ---------------------------------
__global__ __launch_bounds__(192)
void embed_k(const int* __restrict__ x, const void* __restrict__ E,
             const void* __restrict__ P, float* __restrict__ res,
             const int* __restrict__ modeflag)
{
    const int md = *modeflag;
    const int tok = blockIdx.x, t = threadIdx.x;
    const int s = tok & (cS - 1);
    const ll  eb = (ll)x[tok] * cD, pb = (ll)s * cD;
    float4 o;
    o.x = inp(E, eb + t * 4 + 0, md) + inp(P, pb + t * 4 + 0, md);
    o.y = inp(E, eb + t * 4 + 1, md) + inp(P, pb + t * 4 + 1, md);
    o.z = inp(E, eb + t * 4 + 2, md) + inp(P, pb + t * 4 + 2, md);
    o.w = inp(E, eb + t * 4 + 3, md) + inp(P, pb + t * 4 + 3, md);
    ((float4*)(res + (size_t)tok * cD))[t] = o;
}

// ---------------- layernorm (unbiased std, ddof=1), f32 in, bf16 out ------------------
__global__ __launch_bounds__(192)
void ln_k(const float* __restrict__ in, const void* __restrict__ w,
          const void* __restrict__ b, ll wb_off, u16* __restrict__ out,
          const int* __restrict__ modeflag)
{
    __shared__ float sm[8];
    const int md = *modeflag;
    const int row = blockIdx.x, t = threadIdx.x;
    const float4 x = ((const float4*)(in + (size_t)row * cD))[t];
    float s = wave_sum(x.x + x.y + x.z + x.w);
    const int lane = t & 63, wv = t >> 6;
    if (!lane) sm[wv] = s;
    __syncthreads();
    const float mu = (sm[0] + sm[1] + sm[2]) * (1.f / (float)cD);
    const float dx = x.x - mu, dy = x.y - mu, dz = x.z - mu, dw = x.w - mu;
    float ss = wave_sum(dx * dx + dy * dy + dz * dz + dw * dw);
    if (!lane) sm[4 + wv] = ss;
    __syncthreads();
    const float var = (sm[4] + sm[5] + sm[6]) * (1.f / (float)(cD - 1));
    const float rs  = 1.f / sqrtf(var);
    const ll o4 = wb_off + (ll)t * 4;
    ushort4 o;
    o.x = f2b(inp(w, o4 + 0, md) * (dx * rs) + inp(b, o4 + 0, md));
    o.y = f2b(inp(w, o4 + 1, md) * (dy * rs) + inp(b, o4 + 1, md));
    o.z = f2b(inp(w, o4 + 2, md) * (dz * rs) + inp(b, o4 + 2, md));
    o.w = f2b(inp(w, o4 + 3, md) * (dw * rs) + inp(b, o4 + 3, md));
    ((ushort4*)(out + (size_t)row * cD))[t] = o;
}

// ------- causal softmax, 4 rows/block, 1 wave per row, barrier-free, full writes ------
__global__ __launch_bounds__(256)
void softmax4_k(u16* __restrict__ p)
{
    const int row = blockIdx.x * 4 + (threadIdx.x >> 6);
    const int q = row & (cS - 1);
    u16* pr = p + (size_t)row * cS;
    const int lane = threadIdx.x & 63;

    ushort4 v[4];
    float xs[16];
    float mx = -3.4e38f;
    #pragma unroll
    for (int c = 0; c < 4; ++c) {
        const int j0 = (lane + c * 64) * 4;
        v[c] = make_ushort4(0, 0, 0, 0);
        if (j0 <= q) v[c] = ((const ushort4*)pr)[lane + c * 64];
        xs[c * 4 + 0] = (j0 + 0 <= q) ? b2f(v[c].x) : -100000.f;
        xs[c * 4 + 1] = (j0 + 1 <= q) ? b2f(v[c].y) : -100000.f;
        xs[c * 4 + 2] = (j0 + 2 <= q) ? b2f(v[c].z) : -100000.f;
        xs[c * 4 + 3] = (j0 + 3 <= q) ? b2f(v[c].w) : -100000.f;
        mx = fmaxf(mx, fmaxf(fmaxf(xs[c * 4], xs[c * 4 + 1]), fmaxf(xs[c * 4 + 2], xs[c * 4 + 3])));
    }
    mx = wave_max(mx);
    float sum = 0.f;
    #pragma unroll
    for (int j = 0; j < 16; ++j) {
        xs[j] = expf(xs[j] - mx);
        sum += xs[j];
    }
    sum = wave_sum(sum);
    const float inv = 1.f / sum;
    #pragma unroll
    for (int c = 0; c < 4; ++c) {
        ushort4 o;
        o.x = f2b(xs[c * 4 + 0] * inv);
        o.y = f2b(xs[c * 4 + 1] * inv);
        o.z = f2b(xs[c * 4 + 2] * inv);
        o.w = f2b(xs[c * 4 + 3] * inv);
        ((ushort4*)pr)[lane + c * 64] = o;
    }
}

// =====================================================================================
extern "C" void kernel_launch(void* const* d_in, const int* in_sizes, int n_in,
                              void* d_out, int out_size, void* d_ws, size_t ws_size,
                              hipStream_t stream)
{
    (void)in_sizes; (void)n_in; (void)out_size;
    const int*  x     = (const int*)d_in[0];
    const void* E_w   = d_in[1];
    const void* P_w   = d_in[2];
    const void* ln1_w = d_in[3];
    const void* ln1_b = d_in[4];
    const void* Q_w   = d_in[5];
    const void* Q_b   = d_in[6];
    const void* K_w   = d_in[7];
    const void* K_b   = d_in[8];
    const void* V_w   = d_in[9];
    const void* V_b   = d_in[10];
    const void* O_w   = d_in[11];
    const void* O_b   = d_in[12];
    const void* ln2_w = d_in[13];
    const void* ln2_b = d_in[14];
    const void* In_w  = d_in[15];
    const void* In_b  = d_in[16];
    const void* Out_w = d_in[17];
    const void* Out_b = d_in[18];
    const void* lnf_w = d_in[19];
    const void* lnf_b = d_in[20];
    const void* U_w   = d_in[21];
    const void* U_b   = d_in[22];

    // ---- workspace carve with aliasing (~99 MB) ----
    char* wp = (char*)d_ws;
    auto carve = [&](size_t bytes) { char* r = wp; wp += (bytes + 255) & ~(size_t)255; return r; };
    int*   modeflag = (int*)carve(256);
    float* biasQKV  = (float*)carve((size_t)cL * cQKV * 4);
    float* res   = (float*)carve((size_t)cT * cD * 4);
    float* resat = (float*)carve((size_t)cT * cD * 4);
    u16* h     = (u16*)carve((size_t)cT * cD * 2);
    u16* attnb = (u16*)carve((size_t)cT * cD * 2);
    u16* vt    = (u16*)carve((size_t)cT * cD * 2);
    u16* qkv   = (u16*)carve((size_t)cT * cM * 2);       // aliased by mlpb
    u16* mlpb  = qkv;
    u16* WqkvT = (u16*)carve((size_t)cQKV * cD * 2);
    u16* WoT   = (u16*)carve((size_t)cD * cD * 2);
    u16* WinT  = (u16*)carve((size_t)cD * cM * 2);
    u16* WoutT = (u16*)carve((size_t)cD * cM * 2);
    u16* pbuf  = (u16*)carve((size_t)cBH * cS * cS * 2);
    u16* WuT   = pbuf;                                   // alias (pbuf dead after layers)

    if (ws_size && (size_t)(wp - (char*)d_ws) > ws_size) return;  // tripwire

    detect_k<<<1, 64, 0, stream>>>((const uint*)E_w, modeflag);
    packbias_k<<<(cL * cQKV) / 256, 256, 0, stream>>>(Q_b, K_b, V_b, biasQKV, modeflag);
    embed_k<<<cT, 192, 0, stream>>>(x, E_w, P_w, res, modeflag);

    for (int l = 0; l < cL; ++l) {
        // fused weight transposes for this layer (1 launch)
        transw_k<<<6912, 256, 0, stream>>>(Q_w, K_w, V_w, O_w, In_w, Out_w,
                                           WqkvT, WoT, WinT, WoutT, l, modeflag);

        // LN1
        ln_k<<<cT, 192, 0, stream>>>(res, ln1_w, ln1_b, (ll)l * cD, h, modeflag);

        // fused QKV projection: 64x128 tiles -> 576 blocks (2.25/CU)
        gemm_bt<64, 128, 1, 4, 1, false, true, false, false, 2>
            <<<dim3(cT / 64, cQKV / 128, 1), 256, 0, stream>>>(
            h, cD, 0, 0, WqkvT, cD, 0, 0, qkv, cQKV, 0, 0, 1, cD,
            biasQKV, (ll)l * cQKV, 1.f, nullptr, nullptr, modeflag);

        // V slice -> vt [B,H,DH,S]
        transpose_b_k<<<dim3(2, cS / 32, cBH), 256, 0, stream>>>(
            qkv + 2 * cD, vt, cS, cDH, cQKV, cS,
            (ll)cS * cQKV, cDH, (ll)cH * cDH * cS, (ll)cDH * cS, cH);

        // logits = Q K^T * 1/8, batched over (b,h), compact triangular grid (36 tiles)
        gemm_bt<128, 128, 2, 2, 1, false, false, true, false, 0>
            <<<dim3(36, 1, cBH), 256, 0, stream>>>(
            qkv, cQKV, (ll)cS * cQKV, cDH,
            qkv + cD, cQKV, (ll)cS * cQKV, cDH,
            pbuf, cS, (ll)cH * cS * cS, (ll)cS * cS,
            cH, cDH, nullptr, 0, 0.125f, nullptr, nullptr, modeflag);

        // causal softmax: 4 rows/block, barrier-free
        softmax4_k<<<cBH * cS / 4, 256, 0, stream>>>(pbuf);

        // attn = P V, batched, causal K-limit; 64x64 tiles -> 384 blocks
        gemm_bt<64, 64, 2, 2, 1, false, false, false, true, 0>
            <<<dim3(1, 16, cBH), 256, 0, stream>>>(
            pbuf, cS, (ll)cH * cS * cS, (ll)cS * cS,
            vt, cS, (ll)cH * cDH * cS, (ll)cDH * cS,
            attnb, cD, (ll)cS * cD, cDH,
            cH, cS, nullptr, 0, 1.f, nullptr, nullptr, modeflag);

        // O projection + residual -> resat (f32)
        gemm_bt<128, 128, 2, 2, 0, false, true, false, false, 1>
            <<<dim3(cT / 128, cD / 128, 1), 256, 0, stream>>>(
            attnb, cD, 0, 0, WoT, cD, 0, 0, resat, cD, 0, 0, 1, cD,
            O_b, (ll)l * cD, 1.f, res, nullptr, modeflag);

        // LN2
        ln_k<<<cT, 192, 0, stream>>>(resat, ln2_w, ln2_b, (ll)l * cD, h, modeflag);

        // MLP in: 64x128 tiles -> 768 blocks (3/CU): gelu(h @ Win + bIn)
        gemm_bt<64, 128, 1, 4, 1, true, true, false, false, 1>
            <<<dim3(cT / 64, cM / 128, 1), 256, 0, stream>>>(
            h, cD, 0, 0, WinT, cD, 0, 0, mlpb, cM, 0, 0, 1, cD,
            In_b, (ll)l * cM, 1.f, nullptr, nullptr, modeflag);

        // MLP out + double residual (64^2 tiles -> 384 blocks)
        gemm_bt<64, 64, 2, 2, 0, false, true, false, false, 1>
            <<<dim3(cT / 64, cD / 64, 1), 256, 0, stream>>>(
            mlpb, cM, 0, 0, WoutT, cM, 0, 0, res, cD, 0, 0, 1, cM,
            Out_b, (ll)l * cD, 1.f, res, resat, modeflag);
    }

    // unembed weight transpose (WuT aliases pbuf), final LN, unembed:
    // 64x128 tiles -> 8000 blocks + bijective XCD swizzle + T2 LDS swizzle.
    transpose_k<<<dim3(cV / 32, cD / 32, 1), 256, 0, stream>>>(
        U_w, WuT, cD, cV, cV, cD, 0, 0, 0, modeflag);
    ln_k<<<cT, 192, 0, stream>>>(res, lnf_w, lnf_b, 0, h, modeflag);
    gemm_bt<64, 128, 1, 4, 2, false, true, false, false, 1, true>
        <<<dim3(cT / 64, cV / 128, 1), 256, 0, stream>>>(
        h, cD, 0, 0, WuT, cD, 0, 0, d_out, cV, 0, 0, 1, cD,
        U_b, 0, 1.f, nullptr, nullptr, modeflag);
}

// Round 14
// 928.025 us; speedup vs baseline: 1.3430x; 1.0975x over previous
//
#include <hip/hip_runtime.h>

using uint = unsigned int;
using u16  = unsigned short;
using ll   = long long;

constexpr int cL = 4, cH = 12, cDH = 64, cD = 768, cM = 3072, cV = 32000, cS = 1024, cB = 2;
constexpr int cT  = cB * cS;   // 2048 tokens
constexpr int cBH = cB * cH;   // 24
constexpr int cQKV = 3 * cD;   // 2304

using bf16x8 = __bf16 __attribute__((ext_vector_type(8)));
using f32x4  = float  __attribute__((ext_vector_type(4)));

__device__ __forceinline__ float b2f(u16 u) {
    union { uint i; float f; } v; v.i = ((uint)u) << 16; return v.f;
}
__device__ __forceinline__ u16 f2b(float f) {
    union { float f; uint i; } v; v.f = f;
    uint u = v.i;
    return (u16)((u + 0x7fffu + ((u >> 16) & 1u)) >> 16);   // RNE
}
// read input element `idx` as float, per mode (1 = bf16, 0 = f32)
__device__ __forceinline__ float inp(const void* p, ll idx, int md) {
    return md ? b2f(((const u16*)p)[idx]) : ((const float*)p)[idx];
}
__device__ __forceinline__ float wave_sum(float v) {
    #pragma unroll
    for (int m = 32; m; m >>= 1) v += __shfl_xor(v, m);
    return v;
}
__device__ __forceinline__ float wave_max(float v) {
    #pragma unroll
    for (int m = 32; m; m >>= 1) v = fmaxf(v, __shfl_xor(v, m));
    return v;
}
__device__ __forceinline__ void gload16(const u16* g, u16* l) {
    __builtin_amdgcn_global_load_lds(
        (const __attribute__((address_space(1))) uint*)g,
        (__attribute__((address_space(3))) uint*)l,
        16, 0, 0);
}

// ---------------- dtype detector ------------------------------------------------------
__global__ void detect_k(const uint* __restrict__ e, int* __restrict__ flag)
{
    const int l = threadIdx.x;
    int hits = 0;
    #pragma unroll
    for (int i = 0; i < 4; ++i) {
        uint w  = e[l * 4 + i];
        uint ex = (w >> 7) & 0xffu;
        hits += (ex >= 100u && ex <= 126u) ? 1 : 0;
    }
    float s = wave_sum((float)hits);
    if (l == 0) *flag = (s >= 128.f) ? 1 : 0;   // 1 = bf16 inputs, 0 = f32 inputs
}

// ---------------- pack QKV biases -> f32 [L][2304] ------------------------------------
__global__ __launch_bounds__(256)
void packbias_k(const void* __restrict__ Qb, const void* __restrict__ Kb,
                const void* __restrict__ Vb, float* __restrict__ out,
                const int* __restrict__ modeflag)
{
    const int md = *modeflag;
    const int i = blockIdx.x * 256 + threadIdx.x;   // i < L*2304
    const int l = i / cQKV, c = i % cQKV;
    float v;
    if (c < cD)           v = inp(Qb, (ll)l * cD + c, md);
    else if (c < 2 * cD)  v = inp(Kb, (ll)l * cD + c - cD, md);
    else                  v = inp(Vb, (ll)l * cD + c - 2 * cD, md);
    out[i] = v;
}

// ---------------- GEMM (m97-style, 4 waves) + T2 both-sides LDS swizzle ----------------
// LDS slot (row, gslot) holds global 16B-group (gslot ^ (row&7)); staging pre-swizzles
// the per-lane global source (linear LDS dest per gload_lds rule); reads XOR the group.
// CSKIP: causal QK^T compact triangular grid. XCDS: bijective XCD swizzle on 2D grid
// (x = row dim, fastest; consecutive same-XCD blocks share the B col-panel).
template<int BM, int BN, int WGM, int WGN, int OUTK, bool GELU,
         bool COLMAJ, bool CSKIP, bool CK, int BIASK, bool XCDS = false>
__global__ __launch_bounds__(256)
void gemm_bt(const u16* __restrict__ A, int lda, ll offAo, ll offAi,
             const u16* __restrict__ Bt, int ldb, ll offBo, ll offBi,
             void* __restrict__ Cv, int ldc, ll offCo, ll offCi,
             int HB, int K,
             const void* __restrict__ bias, ll bias_off, float scale,
             const float* __restrict__ r1, const float* __restrict__ r2,
             const int* __restrict__ modeflag)
{
    constexpr int MF = BM / WGM / 16;
    constexpr int NF = BN / WGN / 16;
    static_assert(BM % (WGM * 16) == 0 && BN % (WGN * 16) == 0, "tile/wave mismatch");
    static_assert(WGM * WGN == 4, "4 waves");
    __shared__ __align__(16) u16 sA[BM * 64];
    __shared__ __align__(16) u16 sB[BN * 64];

    int rowTile, colTile;
    if constexpr (CSKIP) {
        const int bi = blockIdx.x;
        int r = (int)((sqrtf(8.f * bi + 1.f) - 1.f) * 0.5f);
        while ((r + 1) * (r + 2) / 2 <= bi) ++r;
        while (r * (r + 1) / 2 > bi) --r;
        rowTile = r * BM;
        colTile = (bi - r * (r + 1) / 2) * BN;
    } else if constexpr (XCDS) {
        const int nwg = gridDim.x * gridDim.y;
        const int lin = blockIdx.y * gridDim.x + blockIdx.x;
        const int q8 = nwg >> 3, r8 = nwg & 7;
        const int xcd = lin & 7, idx = lin >> 3;
        const int n_  = (xcd < r8 ? xcd * (q8 + 1) : r8 * (q8 + 1) + (xcd - r8) * q8) + idx;
        rowTile = (n_ % gridDim.x) * BM;
        colTile = (n_ / gridDim.x) * BN;
    } else {
        rowTile = (COLMAJ ? blockIdx.x : blockIdx.y) * BM;
        colTile = (COLMAJ ? blockIdx.y : blockIdx.x) * BN;
    }

    const int md = *modeflag;
    const int z = blockIdx.z;
    const ll zo = z / HB, zi = z % HB;
    const u16* Ab = A + zo * offAo + zi * offAi;
    const u16* Bb = Bt + zo * offBo + zi * offBi;

    const int tid  = threadIdx.x;
    const int lane = tid & 63, wid = tid >> 6;
    const int wr = wid / WGN, wc = wid % WGN;
    const int lr = lane >> 3;                       // row-in-chunk (== row & 7)
    const int lc8s = (((lane & 7) ^ lr) << 3);      // pre-swizzled global 16B-group

    f32x4 zero = {0.f, 0.f, 0.f, 0.f};
    f32x4 acc[MF][NF];
    #pragma unroll
    for (int m = 0; m < MF; ++m)
        #pragma unroll
        for (int n = 0; n < NF; ++n) acc[m][n] = zero;

    const int nkt = CK ? ((rowTile + BM) >> 6) : (K >> 6);
    for (int kt = 0; kt < nkt; ++kt) {
        const int k0 = kt << 6;
        #pragma unroll
        for (int i = 0; i < BM / 32; ++i) {
            int c = i * 4 + wid;
            gload16(Ab + (size_t)(rowTile + c * 8 + lr) * lda + k0 + lc8s, &sA[c * 512]);
        }
        #pragma unroll
        for (int i = 0; i < BN / 32; ++i) {
            int c = i * 4 + wid;
            gload16(Bb + (size_t)(colTile + c * 8 + lr) * ldb + k0 + lc8s, &sB[c * 512]);
        }
        asm volatile("s_waitcnt vmcnt(0)" ::: "memory");
        __syncthreads();
        #pragma unroll
        for (int kk = 0; kk < 2; ++kk) {
            const int g = kk * 4 + (lane >> 4);     // 16B-group index (0..7)
            bf16x8 af[MF], bfv[NF];
            #pragma unroll
            for (int m = 0; m < MF; ++m) {
                const int row = wr * (BM / WGM) + m * 16 + (lane & 15);
                af[m] = *(const bf16x8*)&sA[row * 64 + ((g ^ (row & 7)) << 3)];
            }
            #pragma unroll
            for (int n = 0; n < NF; ++n) {
                const int row = wc * (BN / WGN) + n * 16 + (lane & 15);
                bfv[n] = *(const bf16x8*)&sB[row * 64 + ((g ^ (row & 7)) << 3)];
            }
            #pragma unroll
            for (int m = 0; m < MF; ++m)
                #pragma unroll
                for (int n = 0; n < NF; ++n)
                    acc[m][n] = __builtin_amdgcn_mfma_f32_16x16x32_bf16(af[m], bfv[n], acc[m][n], 0, 0, 0);
        }
        __syncthreads();
    }

    const ll offC = zo * offCo + zi * offCi;
    #pragma unroll
    for (int m = 0; m < MF; ++m) {
        #pragma unroll
        for (int n = 0; n < NF; ++n) {
            const int col = colTile + wc * (BN / WGN) + n * 16 + (lane & 15);
            float bvv = 0.f;
            if constexpr (BIASK == 1) bvv = inp(bias, bias_off + col, md);
            if constexpr (BIASK == 2) bvv = ((const float*)bias)[bias_off + col];
            #pragma unroll
            for (int r = 0; r < 4; ++r) {
                const int row = rowTile + wr * (BM / WGM) + m * 16 + ((lane >> 4) << 2) + r;
                float xv = acc[m][n][r] * scale + bvv;
                if constexpr (GELU) xv = 0.5f * xv * (1.f + erff(xv * 0.70710678118654752f));
                const size_t idx = (size_t)row * ldc + col;
                if (r1) xv += r1[idx];
                if (r2) xv += r2[idx];
                if constexpr (OUTK == 1)      ((u16*)Cv)[offC + idx] = f2b(xv);
                else if constexpr (OUTK == 0) ((float*)Cv)[offC + idx] = xv;
                else {
                    if (md) ((u16*)Cv)[offC + idx] = f2b(xv);
                    else    ((float*)Cv)[offC + idx] = xv;
                }
            }
        }
    }
}

// ------- transpose input weight (bf16 OR f32) -> bf16 ---------------------------------
__global__ __launch_bounds__(256)
void transpose_k(const void* __restrict__ in, u16* __restrict__ out,
                 int R, int C, int ins, int outs,
                 ll base, ll iStride, ll oStride,
                 const int* __restrict__ modeflag)
{
    __shared__ u16 tile[32][33];
    const int md = *modeflag;
    const int z = blockIdx.z;
    const ll ioff = base + (ll)z * iStride;
    u16* op = out + (ll)z * oStride;
    const int tx = threadIdx.x & 31, ty = threadIdx.x >> 5;
    const int c0 = blockIdx.x * 32, r0 = blockIdx.y * 32;
    #pragma unroll
    for (int i = 0; i < 32; i += 8) {
        int r = r0 + ty + i, c = c0 + tx;
        if (r < R && c < C) tile[ty + i][tx] = f2b(inp(in, ioff + (ll)r * ins + c, md));
    }
    __syncthreads();
    #pragma unroll
    for (int i = 0; i < 32; i += 8) {
        int c = c0 + ty + i, r = r0 + tx;
        if (c < C && r < R) op[(size_t)c * outs + r] = tile[tx][ty + i];
    }
}

// ------- fused: per-layer weight transposes (blocks 0..6911) + LN1 (6912..8959) -------
__global__ __launch_bounds__(256)
void transln_k(const void* __restrict__ Qw, const void* __restrict__ Kw,
               const void* __restrict__ Vw, const void* __restrict__ Ow,
               const void* __restrict__ Inw, const void* __restrict__ Outw,
               u16* __restrict__ WqkvT, u16* __restrict__ WoT,
               u16* __restrict__ WinT, u16* __restrict__ WoutT,
               const float* __restrict__ res, const void* __restrict__ lnw,
               const void* __restrict__ lnb, ll wb_off, u16* __restrict__ hout,
               int l, const int* __restrict__ modeflag)
{
    __shared__ u16 tile[32][33];
    __shared__ float sm[8];
    const int md = *modeflag;
    const int b = blockIdx.x;

    if (b >= 6912) {
        // ---- LN1 path: one row per block, 192 active threads of 256 ----
        const int row = b - 6912, t = threadIdx.x;
        float4 x = {0.f, 0.f, 0.f, 0.f};
        if (t < 192) x = ((const float4*)(res + (size_t)row * cD))[t];
        float s = wave_sum(x.x + x.y + x.z + x.w);
        const int lane = t & 63, wv = t >> 6;
        if (!lane) sm[wv] = s;
        __syncthreads();
        const float mu = (sm[0] + sm[1] + sm[2]) * (1.f / (float)cD);
        const float dx = x.x - mu, dy = x.y - mu, dz = x.z - mu, dw = x.w - mu;
        float ss = wave_sum(dx * dx + dy * dy + dz * dz + dw * dw);
        if (!lane) sm[4 + wv] = ss;
        __syncthreads();
        const float var = (sm[4] + sm[5] + sm[6]) * (1.f / (float)(cD - 1));
        const float rs  = 1.f / sqrtf(var);
        if (t < 192) {
            const ll o4 = wb_off + (ll)t * 4;
            ushort4 o;
            o.x = f2b(inp(lnw, o4 + 0, md) * (dx * rs) + inp(lnb, o4 + 0, md));
            o.y = f2b(inp(lnw, o4 + 1, md) * (dy * rs) + inp(lnb, o4 + 1, md));
            o.z = f2b(inp(lnw, o4 + 2, md) * (dz * rs) + inp(lnb, o4 + 2, md));
            o.w = f2b(inp(lnw, o4 + 3, md) * (dw * rs) + inp(lnb, o4 + 3, md));
            ((ushort4*)(hout + (size_t)row * cD))[t] = o;
        }
        return;
    }

    // ---- weight transpose path (identical to r13 transw_k) ----
    const void* in; u16* out; int ins, outs, tx_, ty_; ll ibase;
    if (b < 1728) {
        const int seg = b / 576, rem = b % 576, hd = rem / 48, tt = rem % 48;
        in = seg == 0 ? Qw : (seg == 1 ? Kw : Vw);
        ibase = (ll)l * cH * cD * cDH + (ll)hd * cD * cDH;
        out = WqkvT + (ll)seg * cD * cD + (ll)hd * cDH * cD;
        ins = cDH; outs = cD; tx_ = tt % 2; ty_ = tt / 2;
    } else if (b < 2304) {
        const int tt = b - 1728;
        in = Ow; ibase = (ll)l * cD * cD; out = WoT;
        ins = cD; outs = cD; tx_ = tt % 24; ty_ = tt / 24;
    } else if (b < 4608) {
        const int tt = b - 2304;
        in = Inw; ibase = (ll)l * cD * cM; out = WinT;
        ins = cM; outs = cD; tx_ = tt % 96; ty_ = tt / 96;
    } else {
        const int tt = b - 4608;
        in = Outw; ibase = (ll)l * cM * cD; out = WoutT;
        ins = cD; outs = cM; tx_ = tt % 24; ty_ = tt / 24;
    }
    const int tx = threadIdx.x & 31, ty = threadIdx.x >> 5;
    const int c0 = tx_ * 32, r0 = ty_ * 32;
    #pragma unroll
    for (int i = 0; i < 32; i += 8)
        tile[ty + i][tx] = f2b(inp(in, ibase + (ll)(r0 + ty + i) * ins + c0 + tx, md));
    __syncthreads();
    #pragma unroll
    for (int i = 0; i < 32; i += 8)
        out[(size_t)(c0 + ty + i) * outs + (r0 + tx)] = tile[tx][ty + i];
}

// ---- bf16 transpose for internal V slice (qkv cols) ----------------------------------
__global__ __launch_bounds__(256)
void transpose_b_k(const u16* __restrict__ in, u16* __restrict__ out,
                   int R, int C, int ins, int outs,
                   ll iOo, ll iOi, ll oOo, ll oOi, int HB)
{
    __shared__ u16 tile[32][33];
    const int z = blockIdx.z;
    const u16* ip = in  + (ll)(z / HB) * iOo + (ll)(z % HB) * iOi;
    u16*       op = out + (ll)(z / HB) * oOo + (ll)(z % HB) * oOi;
    const int tx = threadIdx.x & 31, ty = threadIdx.x >> 5;
    const int c0 = blockIdx.x * 32, r0 = blockIdx.y * 32;
    #pragma unroll
    for (int i = 0; i < 32; i += 8) {
        int r = r0 + ty + i, c = c0 + tx;
        if (r < R && c < C) tile[ty + i][tx] = ip[(size_t)r * ins + c];
    }
    __syncthreads();
    #pragma unroll
    for (int i = 0; i < 32; i += 8) {
        int c = c0 + ty + i, r = r0 + tx;
        if (c < C && r < R) op[(size_t)c * outs + r] = tile[tx][ty + i];
    }
}

// ---------------- embedding: res = E[x] + P (f32 out) ---------------------------------
__global__ __launch_bounds__(192)
void embed_k(const int* __restrict__ x, const void* __restrict__ E,
             const void* __restrict__ P, float* __restrict__ res,
             const int* __restrict__ modeflag)
{
    const int md = *modeflag;
    const int tok = blockIdx.x, t = threadIdx.x;
    const int s = tok & (cS - 1);
    const ll  eb = (ll)x[tok] * cD, pb = (ll)s * cD;
    float4 o;
    o.x = inp(E, eb + t * 4 + 0, md) + inp(P, pb + t * 4 + 0, md);
    o.y = inp(E, eb + t * 4 + 1, md) + inp(P, pb + t * 4 + 1, md);
    o.z = inp(E, eb + t * 4 + 2, md) + inp(P, pb + t * 4 + 2, md);
    o.w = inp(E, eb + t * 4 + 3, md) + inp(P, pb + t * 4 + 3, md);
    ((float4*)(res + (size_t)tok * cD))[t] = o;
}

// ---------------- layernorm (unbiased std, ddof=1), f32 in, bf16 out ------------------
__global__ __launch_bounds__(192)
void ln_k(const float* __restrict__ in, const void* __restrict__ w,
          const void* __restrict__ b, ll wb_off, u16* __restrict__ out,
          const int* __restrict__ modeflag)
{
    __shared__ float sm[8];
    const int md = *modeflag;
    const int row = blockIdx.x, t = threadIdx.x;
    const float4 x = ((const float4*)(in + (size_t)row * cD))[t];
    float s = wave_sum(x.x + x.y + x.z + x.w);
    const int lane = t & 63, wv = t >> 6;
    if (!lane) sm[wv] = s;
    __syncthreads();
    const float mu = (sm[0] + sm[1] + sm[2]) * (1.f / (float)cD);
    const float dx = x.x - mu, dy = x.y - mu, dz = x.z - mu, dw = x.w - mu;
    float ss = wave_sum(dx * dx + dy * dy + dz * dz + dw * dw);
    if (!lane) sm[4 + wv] = ss;
    __syncthreads();
    const float var = (sm[4] + sm[5] + sm[6]) * (1.f / (float)(cD - 1));
    const float rs  = 1.f / sqrtf(var);
    const ll o4 = wb_off + (ll)t * 4;
    ushort4 o;
    o.x = f2b(inp(w, o4 + 0, md) * (dx * rs) + inp(b, o4 + 0, md));
    o.y = f2b(inp(w, o4 + 1, md) * (dy * rs) + inp(b, o4 + 1, md));
    o.z = f2b(inp(w, o4 + 2, md) * (dz * rs) + inp(b, o4 + 2, md));
    o.w = f2b(inp(w, o4 + 3, md) * (dw * rs) + inp(b, o4 + 3, md));
    ((ushort4*)(out + (size_t)row * cD))[t] = o;
}

// ------- causal softmax, 4 rows/block, 1 wave per row, barrier-free, full writes ------
__global__ __launch_bounds__(256)
void softmax4_k(u16* __restrict__ p)
{
    const int row = blockIdx.x * 4 + (threadIdx.x >> 6);
    const int q = row & (cS - 1);
    u16* pr = p + (size_t)row * cS;
    const int lane = threadIdx.x & 63;

    ushort4 v[4];
    float xs[16];
    float mx = -3.4e38f;
    #pragma unroll
    for (int c = 0; c < 4; ++c) {
        const int j0 = (lane + c * 64) * 4;
        v[c] = make_ushort4(0, 0, 0, 0);
        if (j0 <= q) v[c] = ((const ushort4*)pr)[lane + c * 64];
        xs[c * 4 + 0] = (j0 + 0 <= q) ? b2f(v[c].x) : -100000.f;
        xs[c * 4 + 1] = (j0 + 1 <= q) ? b2f(v[c].y) : -100000.f;
        xs[c * 4 + 2] = (j0 + 2 <= q) ? b2f(v[c].z) : -100000.f;
        xs[c * 4 + 3] = (j0 + 3 <= q) ? b2f(v[c].w) : -100000.f;
        mx = fmaxf(mx, fmaxf(fmaxf(xs[c * 4], xs[c * 4 + 1]), fmaxf(xs[c * 4 + 2], xs[c * 4 + 3])));
    }
    mx = wave_max(mx);
    float sum = 0.f;
    #pragma unroll
    for (int j = 0; j < 16; ++j) {
        xs[j] = expf(xs[j] - mx);
        sum += xs[j];
    }
    sum = wave_sum(sum);
    const float inv = 1.f / sum;
    #pragma unroll
    for (int c = 0; c < 4; ++c) {
        ushort4 o;
        o.x = f2b(xs[c * 4 + 0] * inv);
        o.y = f2b(xs[c * 4 + 1] * inv);
        o.z = f2b(xs[c * 4 + 2] * inv);
        o.w = f2b(xs[c * 4 + 3] * inv);
        ((ushort4*)pr)[lane + c * 64] = o;
    }
}

// =====================================================================================
extern "C" void kernel_launch(void* const* d_in, const int* in_sizes, int n_in,
                              void* d_out, int out_size, void* d_ws, size_t ws_size,
                              hipStream_t stream)
{
    (void)in_sizes; (void)n_in; (void)out_size;
    const int*  x     = (const int*)d_in[0];
    const void* E_w   = d_in[1];
    const void* P_w   = d_in[2];
    const void* ln1_w = d_in[3];
    const void* ln1_b = d_in[4];
    const void* Q_w   = d_in[5];
    const void* Q_b   = d_in[6];
    const void* K_w   = d_in[7];
    const void* K_b   = d_in[8];
    const void* V_w   = d_in[9];
    const void* V_b   = d_in[10];
    const void* O_w   = d_in[11];
    const void* O_b   = d_in[12];
    const void* ln2_w = d_in[13];
    const void* ln2_b = d_in[14];
    const void* In_w  = d_in[15];
    const void* In_b  = d_in[16];
    const void* Out_w = d_in[17];
    const void* Out_b = d_in[18];
    const void* lnf_w = d_in[19];
    const void* lnf_b = d_in[20];
    const void* U_w   = d_in[21];
    const void* U_b   = d_in[22];

    // ---- workspace carve with aliasing (~99 MB) ----
    char* wp = (char*)d_ws;
    auto carve = [&](size_t bytes) { char* r = wp; wp += (bytes + 255) & ~(size_t)255; return r; };
    int*   modeflag = (int*)carve(256);
    float* biasQKV  = (float*)carve((size_t)cL * cQKV * 4);
    float* res   = (float*)carve((size_t)cT * cD * 4);
    float* resat = (float*)carve((size_t)cT * cD * 4);
    u16* h     = (u16*)carve((size_t)cT * cD * 2);
    u16* attnb = (u16*)carve((size_t)cT * cD * 2);
    u16* vt    = (u16*)carve((size_t)cT * cD * 2);
    u16* qkv   = (u16*)carve((size_t)cT * cM * 2);       // aliased by mlpb
    u16* mlpb  = qkv;
    u16* WqkvT = (u16*)carve((size_t)cQKV * cD * 2);
    u16* WoT   = (u16*)carve((size_t)cD * cD * 2);
    u16* WinT  = (u16*)carve((size_t)cD * cM * 2);
    u16* WoutT = (u16*)carve((size_t)cD * cM * 2);
    u16* pbuf  = (u16*)carve((size_t)cBH * cS * cS * 2);
    u16* WuT   = pbuf;                                   // alias (pbuf dead after layers)

    if (ws_size && (size_t)(wp - (char*)d_ws) > ws_size) return;  // tripwire

    detect_k<<<1, 64, 0, stream>>>((const uint*)E_w, modeflag);
    packbias_k<<<(cL * cQKV) / 256, 256, 0, stream>>>(Q_b, K_b, V_b, biasQKV, modeflag);
    embed_k<<<cT, 192, 0, stream>>>(x, E_w, P_w, res, modeflag);

    for (int l = 0; l < cL; ++l) {
        // fused weight transposes + LN1 (one launch)
        transln_k<<<6912 + cT, 256, 0, stream>>>(
            Q_w, K_w, V_w, O_w, In_w, Out_w, WqkvT, WoT, WinT, WoutT,
            res, ln1_w, ln1_b, (ll)l * cD, h, l, modeflag);

        // fused QKV projection: 64x128 tiles -> 576 blocks
        gemm_bt<64, 128, 1, 4, 1, false, true, false, false, 2>
            <<<dim3(cT / 64, cQKV / 128, 1), 256, 0, stream>>>(
            h, cD, 0, 0, WqkvT, cD, 0, 0, qkv, cQKV, 0, 0, 1, cD,
            biasQKV, (ll)l * cQKV, 1.f, nullptr, nullptr, modeflag);

        // V slice -> vt [B,H,DH,S]
        transpose_b_k<<<dim3(2, cS / 32, cBH), 256, 0, stream>>>(
            qkv + 2 * cD, vt, cS, cDH, cQKV, cS,
            (ll)cS * cQKV, cDH, (ll)cH * cDH * cS, (ll)cDH * cS, cH);

        // logits = Q K^T * 1/8, 64^2 compact triangular grid (136 tiles x 24)
        gemm_bt<64, 64, 2, 2, 1, false, false, true, false, 0>
            <<<dim3(136, 1, cBH), 256, 0, stream>>>(
            qkv, cQKV, (ll)cS * cQKV, cDH,
            qkv + cD, cQKV, (ll)cS * cQKV, cDH,
            pbuf, cS, (ll)cH * cS * cS, (ll)cS * cS,
            cH, cDH, nullptr, 0, 0.125f, nullptr, nullptr, modeflag);

        // causal softmax: 4 rows/block, barrier-free
        softmax4_k<<<cBH * cS / 4, 256, 0, stream>>>(pbuf);

        // attn = P V, batched, causal K-limit; 64x64 tiles -> 384 blocks
        gemm_bt<64, 64, 2, 2, 1, false, false, false, true, 0>
            <<<dim3(1, 16, cBH), 256, 0, stream>>>(
            pbuf, cS, (ll)cH * cS * cS, (ll)cS * cS,
            vt, cS, (ll)cH * cDH * cS, (ll)cDH * cS,
            attnb, cD, (ll)cS * cD, cDH,
            cH, cS, nullptr, 0, 1.f, nullptr, nullptr, modeflag);

        // O projection + residual -> resat (f32): 64x64 -> 384 blocks
        gemm_bt<64, 64, 2, 2, 0, false, true, false, false, 1>
            <<<dim3(cT / 64, cD / 64, 1), 256, 0, stream>>>(
            attnb, cD, 0, 0, WoT, cD, 0, 0, resat, cD, 0, 0, 1, cD,
            O_b, (ll)l * cD, 1.f, res, nullptr, modeflag);

        // LN2
        ln_k<<<cT, 192, 0, stream>>>(resat, ln2_w, ln2_b, (ll)l * cD, h, modeflag);

        // MLP in: 64x128 tiles -> 768 blocks: gelu(h @ Win + bIn)
        gemm_bt<64, 128, 1, 4, 1, true, true, false, false, 1>
            <<<dim3(cT / 64, cM / 128, 1), 256, 0, stream>>>(
            h, cD, 0, 0, WinT, cD, 0, 0, mlpb, cM, 0, 0, 1, cD,
            In_b, (ll)l * cM, 1.f, nullptr, nullptr, modeflag);

        // MLP out + double residual (64^2 tiles -> 384 blocks)
        gemm_bt<64, 64, 2, 2, 0, false, true, false, false, 1>
            <<<dim3(cT / 64, cD / 64, 1), 256, 0, stream>>>(
            mlpb, cM, 0, 0, WoutT, cM, 0, 0, res, cD, 0, 0, 1, cM,
            Out_b, (ll)l * cD, 1.f, res, resat, modeflag);
    }

    // unembed: 128^2 tiles (better MFMA/byte) + T2 swizzle + bijective XCD swizzle;
    // grid (16 rows fast, 250 cols) -> 4000 blocks, ~4/CU.
    transpose_k<<<dim3(cV / 32, cD / 32, 1), 256, 0, stream>>>(
        U_w, WuT, cD, cV, cV, cD, 0, 0, 0, modeflag);
    ln_k<<<cT, 192, 0, stream>>>(res, lnf_w, lnf_b, 0, h, modeflag);
    gemm_bt<128, 128, 2, 2, 2, false, false, false, false, 1, true>
        <<<dim3(cT / 128, cV / 128, 1), 256, 0, stream>>>(
        h, cD, 0, 0, WuT, cD, 0, 0, d_out, cV, 0, 0, 1, cD,
        U_b, 0, 1.f, nullptr, nullptr, modeflag);
}

// Round 15
// 909.948 us; speedup vs baseline: 1.3696x; 1.0199x over previous
//
#include <hip/hip_runtime.h>

using uint = unsigned int;
using u16  = unsigned short;
using ll   = long long;

constexpr int cL = 4, cH = 12, cDH = 64, cD = 768, cM = 3072, cV = 32000, cS = 1024, cB = 2;
constexpr int cT  = cB * cS;   // 2048 tokens
constexpr int cBH = cB * cH;   // 24
constexpr int cQKV = 3 * cD;   // 2304

using bf16x8 = __bf16 __attribute__((ext_vector_type(8)));
using f32x4  = float  __attribute__((ext_vector_type(4)));

__device__ __forceinline__ float b2f(u16 u) {
    union { uint i; float f; } v; v.i = ((uint)u) << 16; return v.f;
}
__device__ __forceinline__ u16 f2b(float f) {
    union { float f; uint i; } v; v.f = f;
    uint u = v.i;
    return (u16)((u + 0x7fffu + ((u >> 16) & 1u)) >> 16);   // RNE
}
// read input element `idx` as float, per mode (1 = bf16, 0 = f32)
__device__ __forceinline__ float inp(const void* p, ll idx, int md) {
    return md ? b2f(((const u16*)p)[idx]) : ((const float*)p)[idx];
}
__device__ __forceinline__ float wave_sum(float v) {
    #pragma unroll
    for (int m = 32; m; m >>= 1) v += __shfl_xor(v, m);
    return v;
}
__device__ __forceinline__ float wave_max(float v) {
    #pragma unroll
    for (int m = 32; m; m >>= 1) v = fmaxf(v, __shfl_xor(v, m));
    return v;
}
__device__ __forceinline__ void gload16(const u16* g, u16* l) {
    __builtin_amdgcn_global_load_lds(
        (const __attribute__((address_space(1))) uint*)g,
        (__attribute__((address_space(3))) uint*)l,
        16, 0, 0);
}

// ---------------- dtype detector ------------------------------------------------------
__global__ void detect_k(const uint* __restrict__ e, int* __restrict__ flag)
{
    const int l = threadIdx.x;
    int hits = 0;
    #pragma unroll
    for (int i = 0; i < 4; ++i) {
        uint w  = e[l * 4 + i];
        uint ex = (w >> 7) & 0xffu;
        hits += (ex >= 100u && ex <= 126u) ? 1 : 0;
    }
    float s = wave_sum((float)hits);
    if (l == 0) *flag = (s >= 128.f) ? 1 : 0;   // 1 = bf16 inputs, 0 = f32 inputs
}

// ---------------- pack QKV biases -> f32 [L][2304] ------------------------------------
__global__ __launch_bounds__(256)
void packbias_k(const void* __restrict__ Qb, const void* __restrict__ Kb,
                const void* __restrict__ Vb, float* __restrict__ out,
                const int* __restrict__ modeflag)
{
    const int md = *modeflag;
    const int i = blockIdx.x * 256 + threadIdx.x;   // i < L*2304
    const int l = i / cQKV, c = i % cQKV;
    float v;
    if (c < cD)           v = inp(Qb, (ll)l * cD + c, md);
    else if (c < 2 * cD)  v = inp(Kb, (ll)l * cD + c - cD, md);
    else                  v = inp(Vb, (ll)l * cD + c - 2 * cD, md);
    out[i] = v;
}

// ---------------- GEMM (m97-style, 4 waves) + T2 both-sides LDS swizzle ----------------
// LDS slot (row, gslot) holds global 16B-group (gslot ^ (row&7)); staging pre-swizzles
// the per-lane global source (linear LDS dest per gload_lds rule); reads XOR the group.
// CSKIP: causal QK^T compact triangular grid. XCDS: bijective XCD swizzle on 2D grid
// (x = row dim, fastest; consecutive same-XCD blocks share the B col-panel).
template<int BM, int BN, int WGM, int WGN, int OUTK, bool GELU,
         bool COLMAJ, bool CSKIP, bool CK, int BIASK, bool XCDS = false>
__global__ __launch_bounds__(256)
void gemm_bt(const u16* __restrict__ A, int lda, ll offAo, ll offAi,
             const u16* __restrict__ Bt, int ldb, ll offBo, ll offBi,
             void* __restrict__ Cv, int ldc, ll offCo, ll offCi,
             int HB, int K,
             const void* __restrict__ bias, ll bias_off, float scale,
             const float* __restrict__ r1, const float* __restrict__ r2,
             const int* __restrict__ modeflag)
{
    constexpr int MF = BM / WGM / 16;
    constexpr int NF = BN / WGN / 16;
    static_assert(BM % (WGM * 16) == 0 && BN % (WGN * 16) == 0, "tile/wave mismatch");
    static_assert(WGM * WGN == 4, "4 waves");
    __shared__ __align__(16) u16 sA[BM * 64];
    __shared__ __align__(16) u16 sB[BN * 64];

    int rowTile, colTile;
    if constexpr (CSKIP) {
        const int bi = blockIdx.x;
        int r = (int)((sqrtf(8.f * bi + 1.f) - 1.f) * 0.5f);
        while ((r + 1) * (r + 2) / 2 <= bi) ++r;
        while (r * (r + 1) / 2 > bi) --r;
        rowTile = r * BM;
        colTile = (bi - r * (r + 1) / 2) * BN;
    } else if constexpr (XCDS) {
        const int nwg = gridDim.x * gridDim.y;
        const int lin = blockIdx.y * gridDim.x + blockIdx.x;
        const int q8 = nwg >> 3, r8 = nwg & 7;
        const int xcd = lin & 7, idx = lin >> 3;
        const int n_  = (xcd < r8 ? xcd * (q8 + 1) : r8 * (q8 + 1) + (xcd - r8) * q8) + idx;
        rowTile = (n_ % gridDim.x) * BM;
        colTile = (n_ / gridDim.x) * BN;
    } else {
        rowTile = (COLMAJ ? blockIdx.x : blockIdx.y) * BM;
        colTile = (COLMAJ ? blockIdx.y : blockIdx.x) * BN;
    }

    const int md = *modeflag;
    const int z = blockIdx.z;
    const ll zo = z / HB, zi = z % HB;
    const u16* Ab = A + zo * offAo + zi * offAi;
    const u16* Bb = Bt + zo * offBo + zi * offBi;

    const int tid  = threadIdx.x;
    const int lane = tid & 63, wid = tid >> 6;
    const int wr = wid / WGN, wc = wid % WGN;
    const int lr = lane >> 3;                       // row-in-chunk (== row & 7)
    const int lc8s = (((lane & 7) ^ lr) << 3);      // pre-swizzled global 16B-group

    f32x4 zero = {0.f, 0.f, 0.f, 0.f};
    f32x4 acc[MF][NF];
    #pragma unroll
    for (int m = 0; m < MF; ++m)
        #pragma unroll
        for (int n = 0; n < NF; ++n) acc[m][n] = zero;

    const int nkt = CK ? ((rowTile + BM) >> 6) : (K >> 6);
    for (int kt = 0; kt < nkt; ++kt) {
        const int k0 = kt << 6;
        #pragma unroll
        for (int i = 0; i < BM / 32; ++i) {
            int c = i * 4 + wid;
            gload16(Ab + (size_t)(rowTile + c * 8 + lr) * lda + k0 + lc8s, &sA[c * 512]);
        }
        #pragma unroll
        for (int i = 0; i < BN / 32; ++i) {
            int c = i * 4 + wid;
            gload16(Bb + (size_t)(colTile + c * 8 + lr) * ldb + k0 + lc8s, &sB[c * 512]);
        }
        asm volatile("s_waitcnt vmcnt(0)" ::: "memory");
        __syncthreads();
        #pragma unroll
        for (int kk = 0; kk < 2; ++kk) {
            const int g = kk * 4 + (lane >> 4);     // 16B-group index (0..7)
            bf16x8 af[MF], bfv[NF];
            #pragma unroll
            for (int m = 0; m < MF; ++m) {
                const int row = wr * (BM / WGM) + m * 16 + (lane & 15);
                af[m] = *(const bf16x8*)&sA[row * 64 + ((g ^ (row & 7)) << 3)];
            }
            #pragma unroll
            for (int n = 0; n < NF; ++n) {
                const int row = wc * (BN / WGN) + n * 16 + (lane & 15);
                bfv[n] = *(const bf16x8*)&sB[row * 64 + ((g ^ (row & 7)) << 3)];
            }
            #pragma unroll
            for (int m = 0; m < MF; ++m)
                #pragma unroll
                for (int n = 0; n < NF; ++n)
                    acc[m][n] = __builtin_amdgcn_mfma_f32_16x16x32_bf16(af[m], bfv[n], acc[m][n], 0, 0, 0);
        }
        __syncthreads();
    }

    const ll offC = zo * offCo + zi * offCi;
    #pragma unroll
    for (int m = 0; m < MF; ++m) {
        #pragma unroll
        for (int n = 0; n < NF; ++n) {
            const int col = colTile + wc * (BN / WGN) + n * 16 + (lane & 15);
            float bvv = 0.f;
            if constexpr (BIASK == 1) bvv = inp(bias, bias_off + col, md);
            if constexpr (BIASK == 2) bvv = ((const float*)bias)[bias_off + col];
            #pragma unroll
            for (int r = 0; r < 4; ++r) {
                const int row = rowTile + wr * (BM / WGM) + m * 16 + ((lane >> 4) << 2) + r;
                float xv = acc[m][n][r] * scale + bvv;
                if constexpr (GELU) xv = 0.5f * xv * (1.f + erff(xv * 0.70710678118654752f));
                const size_t idx = (size_t)row * ldc + col;
                if (r1) xv += r1[idx];
                if (r2) xv += r2[idx];
                if constexpr (OUTK == 1)      ((u16*)Cv)[offC + idx] = f2b(xv);
                else if constexpr (OUTK == 0) ((float*)Cv)[offC + idx] = xv;
                else {
                    if (md) ((u16*)Cv)[offC + idx] = f2b(xv);
                    else    ((float*)Cv)[offC + idx] = xv;
                }
            }
        }
    }
}

// ------- transpose input weight (bf16 OR f32) -> bf16 ---------------------------------
__global__ __launch_bounds__(256)
void transpose_k(const void* __restrict__ in, u16* __restrict__ out,
                 int R, int C, int ins, int outs,
                 ll base, ll iStride, ll oStride,
                 const int* __restrict__ modeflag)
{
    __shared__ u16 tile[32][33];
    const int md = *modeflag;
    const int z = blockIdx.z;
    const ll ioff = base + (ll)z * iStride;
    u16* op = out + (ll)z * oStride;
    const int tx = threadIdx.x & 31, ty = threadIdx.x >> 5;
    const int c0 = blockIdx.x * 32, r0 = blockIdx.y * 32;
    #pragma unroll
    for (int i = 0; i < 32; i += 8) {
        int r = r0 + ty + i, c = c0 + tx;
        if (r < R && c < C) tile[ty + i][tx] = f2b(inp(in, ioff + (ll)r * ins + c, md));
    }
    __syncthreads();
    #pragma unroll
    for (int i = 0; i < 32; i += 8) {
        int c = c0 + ty + i, r = r0 + tx;
        if (c < C && r < R) op[(size_t)c * outs + r] = tile[tx][ty + i];
    }
}

// ------- fused: per-layer weight transposes (blocks 0..6911) + LN1 (6912..8959) -------
__global__ __launch_bounds__(256)
void transln_k(const void* __restrict__ Qw, const void* __restrict__ Kw,
               const void* __restrict__ Vw, const void* __restrict__ Ow,
               const void* __restrict__ Inw, const void* __restrict__ Outw,
               u16* __restrict__ WqkvT, u16* __restrict__ WoT,
               u16* __restrict__ WinT, u16* __restrict__ WoutT,
               const float* __restrict__ res, const void* __restrict__ lnw,
               const void* __restrict__ lnb, ll wb_off, u16* __restrict__ hout,
               int l, const int* __restrict__ modeflag)
{
    __shared__ u16 tile[32][33];
    __shared__ float sm[8];
    const int md = *modeflag;
    const int b = blockIdx.x;

    if (b >= 6912) {
        // ---- LN1 path: one row per block, 192 active threads of 256 ----
        const int row = b - 6912, t = threadIdx.x;
        float4 x = {0.f, 0.f, 0.f, 0.f};
        if (t < 192) x = ((const float4*)(res + (size_t)row * cD))[t];
        float s = wave_sum(x.x + x.y + x.z + x.w);
        const int lane = t & 63, wv = t >> 6;
        if (!lane) sm[wv] = s;
        __syncthreads();
        const float mu = (sm[0] + sm[1] + sm[2]) * (1.f / (float)cD);
        const float dx = x.x - mu, dy = x.y - mu, dz = x.z - mu, dw = x.w - mu;
        float ss = wave_sum(dx * dx + dy * dy + dz * dz + dw * dw);
        if (!lane) sm[4 + wv] = ss;
        __syncthreads();
        const float var = (sm[4] + sm[5] + sm[6]) * (1.f / (float)(cD - 1));
        const float rs  = 1.f / sqrtf(var);
        if (t < 192) {
            const ll o4 = wb_off + (ll)t * 4;
            ushort4 o;
            o.x = f2b(inp(lnw, o4 + 0, md) * (dx * rs) + inp(lnb, o4 + 0, md));
            o.y = f2b(inp(lnw, o4 + 1, md) * (dy * rs) + inp(lnb, o4 + 1, md));
            o.z = f2b(inp(lnw, o4 + 2, md) * (dz * rs) + inp(lnb, o4 + 2, md));
            o.w = f2b(inp(lnw, o4 + 3, md) * (dw * rs) + inp(lnb, o4 + 3, md));
            ((ushort4*)(hout + (size_t)row * cD))[t] = o;
        }
        return;
    }

    // ---- weight transpose path ----
    const void* in; u16* out; int ins, outs, tx_, ty_; ll ibase;
    if (b < 1728) {
        const int seg = b / 576, rem = b % 576, hd = rem / 48, tt = rem % 48;
        in = seg == 0 ? Qw : (seg == 1 ? Kw : Vw);
        ibase = (ll)l * cH * cD * cDH + (ll)hd * cD * cDH;
        out = WqkvT + (ll)seg * cD * cD + (ll)hd * cDH * cD;
        ins = cDH; outs = cD; tx_ = tt % 2; ty_ = tt / 2;
    } else if (b < 2304) {
        const int tt = b - 1728;
        in = Ow; ibase = (ll)l * cD * cD; out = WoT;
        ins = cD; outs = cD; tx_ = tt % 24; ty_ = tt / 24;
    } else if (b < 4608) {
        const int tt = b - 2304;
        in = Inw; ibase = (ll)l * cD * cM; out = WinT;
        ins = cM; outs = cD; tx_ = tt % 96; ty_ = tt / 96;
    } else {
        const int tt = b - 4608;
        in = Outw; ibase = (ll)l * cM * cD; out = WoutT;
        ins = cD; outs = cM; tx_ = tt % 24; ty_ = tt / 24;
    }
    const int tx = threadIdx.x & 31, ty = threadIdx.x >> 5;
    const int c0 = tx_ * 32, r0 = ty_ * 32;
    #pragma unroll
    for (int i = 0; i < 32; i += 8)
        tile[ty + i][tx] = f2b(inp(in, ibase + (ll)(r0 + ty + i) * ins + c0 + tx, md));
    __syncthreads();
    #pragma unroll
    for (int i = 0; i < 32; i += 8)
        out[(size_t)(c0 + ty + i) * outs + (r0 + tx)] = tile[tx][ty + i];
}

// ---- bf16 transpose for internal V slice (qkv cols) ----------------------------------
__global__ __launch_bounds__(256)
void transpose_b_k(const u16* __restrict__ in, u16* __restrict__ out,
                   int R, int C, int ins, int outs,
                   ll iOo, ll iOi, ll oOo, ll oOi, int HB)
{
    __shared__ u16 tile[32][33];
    const int z = blockIdx.z;
    const u16* ip = in  + (ll)(z / HB) * iOo + (ll)(z % HB) * iOi;
    u16*       op = out + (ll)(z / HB) * oOo + (ll)(z % HB) * oOi;
    const int tx = threadIdx.x & 31, ty = threadIdx.x >> 5;
    const int c0 = blockIdx.x * 32, r0 = blockIdx.y * 32;
    #pragma unroll
    for (int i = 0; i < 32; i += 8) {
        int r = r0 + ty + i, c = c0 + tx;
        if (r < R && c < C) tile[ty + i][tx] = ip[(size_t)r * ins + c];
    }
    __syncthreads();
    #pragma unroll
    for (int i = 0; i < 32; i += 8) {
        int c = c0 + ty + i, r = r0 + tx;
        if (c < C && r < R) op[(size_t)c * outs + r] = tile[tx][ty + i];
    }
}

// ---------------- embedding: res = E[x] + P (f32 out) ---------------------------------
__global__ __launch_bounds__(192)
void embed_k(const int* __restrict__ x, const void* __restrict__ E,
             const void* __restrict__ P, float* __restrict__ res,
             const int* __restrict__ modeflag)
{
    const int md = *modeflag;
    const int tok = blockIdx.x, t = threadIdx.x;
    const int s = tok & (cS - 1);
    const ll  eb = (ll)x[tok] * cD, pb = (ll)s * cD;
    float4 o;
    o.x = inp(E, eb + t * 4 + 0, md) + inp(P, pb + t * 4 + 0, md);
    o.y = inp(E, eb + t * 4 + 1, md) + inp(P, pb + t * 4 + 1, md);
    o.z = inp(E, eb + t * 4 + 2, md) + inp(P, pb + t * 4 + 2, md);
    o.w = inp(E, eb + t * 4 + 3, md) + inp(P, pb + t * 4 + 3, md);
    ((float4*)(res + (size_t)tok * cD))[t] = o;
}

// ---------------- layernorm (unbiased std, ddof=1), f32 in, bf16 out ------------------
__global__ __launch_bounds__(192)
void ln_k(const float* __restrict__ in, const void* __restrict__ w,
          const void* __restrict__ b, ll wb_off, u16* __restrict__ out,
          const int* __restrict__ modeflag)
{
    __shared__ float sm[8];
    const int md = *modeflag;
    const int row = blockIdx.x, t = threadIdx.x;
    const float4 x = ((const float4*)(in + (size_t)row * cD))[t];
    float s = wave_sum(x.x + x.y + x.z + x.w);
    const int lane = t & 63, wv = t >> 6;
    if (!lane) sm[wv] = s;
    __syncthreads();
    const float mu = (sm[0] + sm[1] + sm[2]) * (1.f / (float)cD);
    const float dx = x.x - mu, dy = x.y - mu, dz = x.z - mu, dw = x.w - mu;
    float ss = wave_sum(dx * dx + dy * dy + dz * dz + dw * dw);
    if (!lane) sm[4 + wv] = ss;
    __syncthreads();
    const float var = (sm[4] + sm[5] + sm[6]) * (1.f / (float)(cD - 1));
    const float rs  = 1.f / sqrtf(var);
    const ll o4 = wb_off + (ll)t * 4;
    ushort4 o;
    o.x = f2b(inp(w, o4 + 0, md) * (dx * rs) + inp(b, o4 + 0, md));
    o.y = f2b(inp(w, o4 + 1, md) * (dy * rs) + inp(b, o4 + 1, md));
    o.z = f2b(inp(w, o4 + 2, md) * (dz * rs) + inp(b, o4 + 2, md));
    o.w = f2b(inp(w, o4 + 3, md) * (dw * rs) + inp(b, o4 + 3, md));
    ((ushort4*)(out + (size_t)row * cD))[t] = o;
}

// ------- causal softmax, 4 rows/block, 1 wave per row, barrier-free, full writes ------
__global__ __launch_bounds__(256)
void softmax4_k(u16* __restrict__ p)
{
    const int row = blockIdx.x * 4 + (threadIdx.x >> 6);
    const int q = row & (cS - 1);
    u16* pr = p + (size_t)row * cS;
    const int lane = threadIdx.x & 63;

    ushort4 v[4];
    float xs[16];
    float mx = -3.4e38f;
    #pragma unroll
    for (int c = 0; c < 4; ++c) {
        const int j0 = (lane + c * 64) * 4;
        v[c] = make_ushort4(0, 0, 0, 0);
        if (j0 <= q) v[c] = ((const ushort4*)pr)[lane + c * 64];
        xs[c * 4 + 0] = (j0 + 0 <= q) ? b2f(v[c].x) : -100000.f;
        xs[c * 4 + 1] = (j0 + 1 <= q) ? b2f(v[c].y) : -100000.f;
        xs[c * 4 + 2] = (j0 + 2 <= q) ? b2f(v[c].z) : -100000.f;
        xs[c * 4 + 3] = (j0 + 3 <= q) ? b2f(v[c].w) : -100000.f;
        mx = fmaxf(mx, fmaxf(fmaxf(xs[c * 4], xs[c * 4 + 1]), fmaxf(xs[c * 4 + 2], xs[c * 4 + 3])));
    }
    mx = wave_max(mx);
    float sum = 0.f;
    #pragma unroll
    for (int j = 0; j < 16; ++j) {
        xs[j] = expf(xs[j] - mx);
        sum += xs[j];
    }
    sum = wave_sum(sum);
    const float inv = 1.f / sum;
    #pragma unroll
    for (int c = 0; c < 4; ++c) {
        ushort4 o;
        o.x = f2b(xs[c * 4 + 0] * inv);
        o.y = f2b(xs[c * 4 + 1] * inv);
        o.z = f2b(xs[c * 4 + 2] * inv);
        o.w = f2b(xs[c * 4 + 3] * inv);
        ((ushort4*)pr)[lane + c * 64] = o;
    }
}

// =====================================================================================
extern "C" void kernel_launch(void* const* d_in, const int* in_sizes, int n_in,
                              void* d_out, int out_size, void* d_ws, size_t ws_size,
                              hipStream_t stream)
{
    (void)in_sizes; (void)n_in; (void)out_size;
    const int*  x     = (const int*)d_in[0];
    const void* E_w   = d_in[1];
    const void* P_w   = d_in[2];
    const void* ln1_w = d_in[3];
    const void* ln1_b = d_in[4];
    const void* Q_w   = d_in[5];
    const void* Q_b   = d_in[6];
    const void* K_w   = d_in[7];
    const void* K_b   = d_in[8];
    const void* V_w   = d_in[9];
    const void* V_b   = d_in[10];
    const void* O_w   = d_in[11];
    const void* O_b   = d_in[12];
    const void* ln2_w = d_in[13];
    const void* ln2_b = d_in[14];
    const void* In_w  = d_in[15];
    const void* In_b  = d_in[16];
    const void* Out_w = d_in[17];
    const void* Out_b = d_in[18];
    const void* lnf_w = d_in[19];
    const void* lnf_b = d_in[20];
    const void* U_w   = d_in[21];
    const void* U_b   = d_in[22];

    // ---- workspace carve with aliasing (~99 MB) ----
    char* wp = (char*)d_ws;
    auto carve = [&](size_t bytes) { char* r = wp; wp += (bytes + 255) & ~(size_t)255; return r; };
    int*   modeflag = (int*)carve(256);
    float* biasQKV  = (float*)carve((size_t)cL * cQKV * 4);
    float* res   = (float*)carve((size_t)cT * cD * 4);
    float* resat = (float*)carve((size_t)cT * cD * 4);
    u16* h     = (u16*)carve((size_t)cT * cD * 2);
    u16* attnb = (u16*)carve((size_t)cT * cD * 2);
    u16* vt    = (u16*)carve((size_t)cT * cD * 2);
    u16* qkv   = (u16*)carve((size_t)cT * cM * 2);       // aliased by mlpb
    u16* mlpb  = qkv;
    u16* WqkvT = (u16*)carve((size_t)cQKV * cD * 2);
    u16* WoT   = (u16*)carve((size_t)cD * cD * 2);
    u16* WinT  = (u16*)carve((size_t)cD * cM * 2);
    u16* WoutT = (u16*)carve((size_t)cD * cM * 2);
    u16* pbuf  = (u16*)carve((size_t)cBH * cS * cS * 2);
    u16* WuT   = pbuf;                                   // alias (pbuf dead after layers)

    if (ws_size && (size_t)(wp - (char*)d_ws) > ws_size) return;  // tripwire

    detect_k<<<1, 64, 0, stream>>>((const uint*)E_w, modeflag);
    packbias_k<<<(cL * cQKV) / 256, 256, 0, stream>>>(Q_b, K_b, V_b, biasQKV, modeflag);
    embed_k<<<cT, 192, 0, stream>>>(x, E_w, P_w, res, modeflag);

    for (int l = 0; l < cL; ++l) {
        // fused weight transposes + LN1 (one launch)
        transln_k<<<6912 + cT, 256, 0, stream>>>(
            Q_w, K_w, V_w, O_w, In_w, Out_w, WqkvT, WoT, WinT, WoutT,
            res, ln1_w, ln1_b, (ll)l * cD, h, l, modeflag);

        // fused QKV projection: 64x128 tiles -> 576 blocks
        gemm_bt<64, 128, 1, 4, 1, false, true, false, false, 2>
            <<<dim3(cT / 64, cQKV / 128, 1), 256, 0, stream>>>(
            h, cD, 0, 0, WqkvT, cD, 0, 0, qkv, cQKV, 0, 0, 1, cD,
            biasQKV, (ll)l * cQKV, 1.f, nullptr, nullptr, modeflag);

        // V slice -> vt [B,H,DH,S]
        transpose_b_k<<<dim3(2, cS / 32, cBH), 256, 0, stream>>>(
            qkv + 2 * cD, vt, cS, cDH, cQKV, cS,
            (ll)cS * cQKV, cDH, (ll)cH * cDH * cS, (ll)cDH * cS, cH);

        // logits = Q K^T * 1/8, 64^2 compact triangular grid (136 tiles x 24)
        gemm_bt<64, 64, 2, 2, 1, false, false, true, false, 0>
            <<<dim3(136, 1, cBH), 256, 0, stream>>>(
            qkv, cQKV, (ll)cS * cQKV, cDH,
            qkv + cD, cQKV, (ll)cS * cQKV, cDH,
            pbuf, cS, (ll)cH * cS * cS, (ll)cS * cS,
            cH, cDH, nullptr, 0, 0.125f, nullptr, nullptr, modeflag);

        // causal softmax: 4 rows/block, barrier-free
        softmax4_k<<<cBH * cS / 4, 256, 0, stream>>>(pbuf);

        // attn = P V, batched, causal K-limit; 64x64 tiles -> 384 blocks
        gemm_bt<64, 64, 2, 2, 1, false, false, false, true, 0>
            <<<dim3(1, 16, cBH), 256, 0, stream>>>(
            pbuf, cS, (ll)cH * cS * cS, (ll)cS * cS,
            vt, cS, (ll)cH * cDH * cS, (ll)cDH * cS,
            attnb, cD, (ll)cS * cD, cDH,
            cH, cS, nullptr, 0, 1.f, nullptr, nullptr, modeflag);

        // O projection + residual -> resat (f32): 64x64 -> 384 blocks
        gemm_bt<64, 64, 2, 2, 0, false, true, false, false, 1>
            <<<dim3(cT / 64, cD / 64, 1), 256, 0, stream>>>(
            attnb, cD, 0, 0, WoT, cD, 0, 0, resat, cD, 0, 0, 1, cD,
            O_b, (ll)l * cD, 1.f, res, nullptr, modeflag);

        // LN2
        ln_k<<<cT, 192, 0, stream>>>(resat, ln2_w, ln2_b, (ll)l * cD, h, modeflag);

        // MLP in: 64x128 tiles -> 768 blocks: gelu(h @ Win + bIn)
        gemm_bt<64, 128, 1, 4, 1, true, true, false, false, 1>
            <<<dim3(cT / 64, cM / 128, 1), 256, 0, stream>>>(
            h, cD, 0, 0, WinT, cD, 0, 0, mlpb, cM, 0, 0, 1, cD,
            In_b, (ll)l * cM, 1.f, nullptr, nullptr, modeflag);

        // MLP out + double residual (64^2 tiles -> 384 blocks)
        gemm_bt<64, 64, 2, 2, 0, false, true, false, false, 1>
            <<<dim3(cT / 64, cD / 64, 1), 256, 0, stream>>>(
            mlpb, cM, 0, 0, WoutT, cM, 0, 0, res, cD, 0, 0, 1, cM,
            Out_b, (ll)l * cD, 1.f, res, resat, modeflag);
    }

    // unembed: REVERT to r13 config (measured 190 us): 64x128 tiles -> 8000 blocks
    // (~40% occupancy) + T2 LDS swizzle + bijective XCD swizzle. r14's 128^2 regressed
    // to 228 us (occupancy 21%).
    transpose_k<<<dim3(cV / 32, cD / 32, 1), 256, 0, stream>>>(
        U_w, WuT, cD, cV, cV, cD, 0, 0, 0, modeflag);
    ln_k<<<cT, 192, 0, stream>>>(res, lnf_w, lnf_b, 0, h, modeflag);
    gemm_bt<64, 128, 1, 4, 2, false, true, false, false, 1, true>
        <<<dim3(cT / 64, cV / 128, 1), 256, 0, stream>>>(
        h, cD, 0, 0, WuT, cD, 0, 0, d_out, cV, 0, 0, 1, cD,
        U_b, 0, 1.f, nullptr, nullptr, modeflag);
}

// Round 16
// 888.464 us; speedup vs baseline: 1.4028x; 1.0242x over previous
//
#include <hip/hip_runtime.h>

using uint = unsigned int;
using u16  = unsigned short;
using ll   = long long;

constexpr int cL = 4, cH = 12, cDH = 64, cD = 768, cM = 3072, cV = 32000, cS = 1024, cB = 2;
constexpr int cT  = cB * cS;   // 2048 tokens
constexpr int cBH = cB * cH;   // 24
constexpr int cQKV = 3 * cD;   // 2304

using bf16x8 = __bf16 __attribute__((ext_vector_type(8)));
using f32x4  = float  __attribute__((ext_vector_type(4)));

__device__ __forceinline__ float b2f(u16 u) {
    union { uint i; float f; } v; v.i = ((uint)u) << 16; return v.f;
}
__device__ __forceinline__ u16 f2b(float f) {
    union { float f; uint i; } v; v.f = f;
    uint u = v.i;
    return (u16)((u + 0x7fffu + ((u >> 16) & 1u)) >> 16);   // RNE
}
// read input element `idx` as float, per mode (1 = bf16, 0 = f32)
__device__ __forceinline__ float inp(const void* p, ll idx, int md) {
    return md ? b2f(((const u16*)p)[idx]) : ((const float*)p)[idx];
}
__device__ __forceinline__ float wave_sum(float v) {
    #pragma unroll
    for (int m = 32; m; m >>= 1) v += __shfl_xor(v, m);
    return v;
}
__device__ __forceinline__ float wave_max(float v) {
    #pragma unroll
    for (int m = 32; m; m >>= 1) v = fmaxf(v, __shfl_xor(v, m));
    return v;
}
__device__ __forceinline__ void gload16(const u16* g, u16* l) {
    __builtin_amdgcn_global_load_lds(
        (const __attribute__((address_space(1))) uint*)g,
        (__attribute__((address_space(3))) uint*)l,
        16, 0, 0);
}

// ---------------- dtype detector ------------------------------------------------------
__global__ void detect_k(const uint* __restrict__ e, int* __restrict__ flag)
{
    const int l = threadIdx.x;
    int hits = 0;
    #pragma unroll
    for (int i = 0; i < 4; ++i) {
        uint w  = e[l * 4 + i];
        uint ex = (w >> 7) & 0xffu;
        hits += (ex >= 100u && ex <= 126u) ? 1 : 0;
    }
    float s = wave_sum((float)hits);
    if (l == 0) *flag = (s >= 128.f) ? 1 : 0;   // 1 = bf16 inputs, 0 = f32 inputs
}

// ---------------- pack QKV biases -> f32 [L][2304] ------------------------------------
__global__ __launch_bounds__(256)
void packbias_k(const void* __restrict__ Qb, const void* __restrict__ Kb,
                const void* __restrict__ Vb, float* __restrict__ out,
                const int* __restrict__ modeflag)
{
    const int md = *modeflag;
    const int i = blockIdx.x * 256 + threadIdx.x;   // i < L*2304
    const int l = i / cQKV, c = i % cQKV;
    float v;
    if (c < cD)           v = inp(Qb, (ll)l * cD + c, md);
    else if (c < 2 * cD)  v = inp(Kb, (ll)l * cD + c - cD, md);
    else                  v = inp(Vb, (ll)l * cD + c - 2 * cD, md);
    out[i] = v;
}

// ---------------- GEMM (m97-style, 4 waves) + T2 both-sides LDS swizzle ----------------
// LDS slot (row, gslot) holds global 16B-group (gslot ^ (row&7)); staging pre-swizzles
// the per-lane global source (linear LDS dest per gload_lds rule); reads XOR the group.
// CSKIP: causal QK^T compact triangular grid. XCDS: bijective XCD swizzle on 2D grid.
// NTST: non-temporal C stores (ONLY for never-re-read outputs, e.g. unembed: avoids the
// 64B-segment RFO read stream that showed as FETCH ~= WRITE/2 on f32 outputs).
template<int BM, int BN, int WGM, int WGN, int OUTK, bool GELU,
         bool COLMAJ, bool CSKIP, bool CK, int BIASK, bool XCDS = false, bool NTST = false>
__global__ __launch_bounds__(256)
void gemm_bt(const u16* __restrict__ A, int lda, ll offAo, ll offAi,
             const u16* __restrict__ Bt, int ldb, ll offBo, ll offBi,
             void* __restrict__ Cv, int ldc, ll offCo, ll offCi,
             int HB, int K,
             const void* __restrict__ bias, ll bias_off, float scale,
             const float* __restrict__ r1, const float* __restrict__ r2,
             const int* __restrict__ modeflag)
{
    constexpr int MF = BM / WGM / 16;
    constexpr int NF = BN / WGN / 16;
    static_assert(BM % (WGM * 16) == 0 && BN % (WGN * 16) == 0, "tile/wave mismatch");
    static_assert(WGM * WGN == 4, "4 waves");
    __shared__ __align__(16) u16 sA[BM * 64];
    __shared__ __align__(16) u16 sB[BN * 64];

    int rowTile, colTile;
    if constexpr (CSKIP) {
        const int bi = blockIdx.x;
        int r = (int)((sqrtf(8.f * bi + 1.f) - 1.f) * 0.5f);
        while ((r + 1) * (r + 2) / 2 <= bi) ++r;
        while (r * (r + 1) / 2 > bi) --r;
        rowTile = r * BM;
        colTile = (bi - r * (r + 1) / 2) * BN;
    } else if constexpr (XCDS) {
        const int nwg = gridDim.x * gridDim.y;
        const int lin = blockIdx.y * gridDim.x + blockIdx.x;
        const int q8 = nwg >> 3, r8 = nwg & 7;
        const int xcd = lin & 7, idx = lin >> 3;
        const int n_  = (xcd < r8 ? xcd * (q8 + 1) : r8 * (q8 + 1) + (xcd - r8) * q8) + idx;
        rowTile = (n_ % gridDim.x) * BM;
        colTile = (n_ / gridDim.x) * BN;
    } else {
        rowTile = (COLMAJ ? blockIdx.x : blockIdx.y) * BM;
        colTile = (COLMAJ ? blockIdx.y : blockIdx.x) * BN;
    }

    const int md = *modeflag;
    const int z = blockIdx.z;
    const ll zo = z / HB, zi = z % HB;
    const u16* Ab = A + zo * offAo + zi * offAi;
    const u16* Bb = Bt + zo * offBo + zi * offBi;

    const int tid  = threadIdx.x;
    const int lane = tid & 63, wid = tid >> 6;
    const int wr = wid / WGN, wc = wid % WGN;
    const int lr = lane >> 3;                       // row-in-chunk (== row & 7)
    const int lc8s = (((lane & 7) ^ lr) << 3);      // pre-swizzled global 16B-group

    f32x4 zero = {0.f, 0.f, 0.f, 0.f};
    f32x4 acc[MF][NF];
    #pragma unroll
    for (int m = 0; m < MF; ++m)
        #pragma unroll
        for (int n = 0; n < NF; ++n) acc[m][n] = zero;

    const int nkt = CK ? ((rowTile + BM) >> 6) : (K >> 6);
    for (int kt = 0; kt < nkt; ++kt) {
        const int k0 = kt << 6;
        #pragma unroll
        for (int i = 0; i < BM / 32; ++i) {
            int c = i * 4 + wid;
            gload16(Ab + (size_t)(rowTile + c * 8 + lr) * lda + k0 + lc8s, &sA[c * 512]);
        }
        #pragma unroll
        for (int i = 0; i < BN / 32; ++i) {
            int c = i * 4 + wid;
            gload16(Bb + (size_t)(colTile + c * 8 + lr) * ldb + k0 + lc8s, &sB[c * 512]);
        }
        asm volatile("s_waitcnt vmcnt(0)" ::: "memory");
        __syncthreads();
        #pragma unroll
        for (int kk = 0; kk < 2; ++kk) {
            const int g = kk * 4 + (lane >> 4);     // 16B-group index (0..7)
            bf16x8 af[MF], bfv[NF];
            #pragma unroll
            for (int m = 0; m < MF; ++m) {
                const int row = wr * (BM / WGM) + m * 16 + (lane & 15);
                af[m] = *(const bf16x8*)&sA[row * 64 + ((g ^ (row & 7)) << 3)];
            }
            #pragma unroll
            for (int n = 0; n < NF; ++n) {
                const int row = wc * (BN / WGN) + n * 16 + (lane & 15);
                bfv[n] = *(const bf16x8*)&sB[row * 64 + ((g ^ (row & 7)) << 3)];
            }
            #pragma unroll
            for (int m = 0; m < MF; ++m)
                #pragma unroll
                for (int n = 0; n < NF; ++n)
                    acc[m][n] = __builtin_amdgcn_mfma_f32_16x16x32_bf16(af[m], bfv[n], acc[m][n], 0, 0, 0);
        }
        __syncthreads();
    }

    const ll offC = zo * offCo + zi * offCi;
    #pragma unroll
    for (int m = 0; m < MF; ++m) {
        #pragma unroll
        for (int n = 0; n < NF; ++n) {
            const int col = colTile + wc * (BN / WGN) + n * 16 + (lane & 15);
            float bvv = 0.f;
            if constexpr (BIASK == 1) bvv = inp(bias, bias_off + col, md);
            if constexpr (BIASK == 2) bvv = ((const float*)bias)[bias_off + col];
            #pragma unroll
            for (int r = 0; r < 4; ++r) {
                const int row = rowTile + wr * (BM / WGM) + m * 16 + ((lane >> 4) << 2) + r;
                float xv = acc[m][n][r] * scale + bvv;
                if constexpr (GELU) xv = 0.5f * xv * (1.f + erff(xv * 0.70710678118654752f));
                const size_t idx = (size_t)row * ldc + col;
                if (r1) xv += r1[idx];
                if (r2) xv += r2[idx];
                if constexpr (OUTK == 1) {
                    if constexpr (NTST) __builtin_nontemporal_store(f2b(xv), &((u16*)Cv)[offC + idx]);
                    else                ((u16*)Cv)[offC + idx] = f2b(xv);
                } else if constexpr (OUTK == 0) {
                    if constexpr (NTST) __builtin_nontemporal_store(xv, &((float*)Cv)[offC + idx]);
                    else                ((float*)Cv)[offC + idx] = xv;
                } else {
                    if (md) {
                        if constexpr (NTST) __builtin_nontemporal_store(f2b(xv), &((u16*)Cv)[offC + idx]);
                        else                ((u16*)Cv)[offC + idx] = f2b(xv);
                    } else {
                        if constexpr (NTST) __builtin_nontemporal_store(xv, &((float*)Cv)[offC + idx]);
                        else                ((float*)Cv)[offC + idx] = xv;
                    }
                }
            }
        }
    }
}

// ------- transpose input weight (bf16 OR f32) -> bf16 ---------------------------------
__global__ __launch_bounds__(256)
void transpose_k(const void* __restrict__ in, u16* __restrict__ out,
                 int R, int C, int ins, int outs,
                 ll base, ll iStride, ll oStride,
                 const int* __restrict__ modeflag)
{
    __shared__ u16 tile[32][33];
    const int md = *modeflag;
    const int z = blockIdx.z;
    const ll ioff = base + (ll)z * iStride;
    u16* op = out + (ll)z * oStride;
    const int tx = threadIdx.x & 31, ty = threadIdx.x >> 5;
    const int c0 = blockIdx.x * 32, r0 = blockIdx.y * 32;
    #pragma unroll
    for (int i = 0; i < 32; i += 8) {
        int r = r0 + ty + i, c = c0 + tx;
        if (r < R && c < C) tile[ty + i][tx] = f2b(inp(in, ioff + (ll)r * ins + c, md));
    }
    __syncthreads();
    #pragma unroll
    for (int i = 0; i < 32; i += 8) {
        int c = c0 + ty + i, r = r0 + tx;
        if (c < C && r < R) op[(size_t)c * outs + r] = tile[tx][ty + i];
    }
}

// ------- fused: per-layer weight transposes (blocks 0..6911) + LN1 (6912..8959) -------
__global__ __launch_bounds__(256)
void transln_k(const void* __restrict__ Qw, const void* __restrict__ Kw,
               const void* __restrict__ Vw, const void* __restrict__ Ow,
               const void* __restrict__ Inw, const void* __restrict__ Outw,
               u16* __restrict__ WqkvT, u16* __restrict__ WoT,
               u16* __restrict__ WinT, u16* __restrict__ WoutT,
               const float* __restrict__ res, const void* __restrict__ lnw,
               const void* __restrict__ lnb, ll wb_off, u16* __restrict__ hout,
               int l, const int* __restrict__ modeflag)
{
    __shared__ u16 tile[32][33];
    __shared__ float sm[8];
    const int md = *modeflag;
    const int b = blockIdx.x;

    if (b >= 6912) {
        // ---- LN1 path: one row per block, 192 active threads of 256 ----
        const int row = b - 6912, t = threadIdx.x;
        float4 x = {0.f, 0.f, 0.f, 0.f};
        if (t < 192) x = ((const float4*)(res + (size_t)row * cD))[t];
        float s = wave_sum(x.x + x.y + x.z + x.w);
        const int lane = t & 63, wv = t >> 6;
        if (!lane) sm[wv] = s;
        __syncthreads();
        const float mu = (sm[0] + sm[1] + sm[2]) * (1.f / (float)cD);
        const float dx = x.x - mu, dy = x.y - mu, dz = x.z - mu, dw = x.w - mu;
        float ss = wave_sum(dx * dx + dy * dy + dz * dz + dw * dw);
        if (!lane) sm[4 + wv] = ss;
        __syncthreads();
        const float var = (sm[4] + sm[5] + sm[6]) * (1.f / (float)(cD - 1));
        const float rs  = 1.f / sqrtf(var);
        if (t < 192) {
            const ll o4 = wb_off + (ll)t * 4;
            ushort4 o;
            o.x = f2b(inp(lnw, o4 + 0, md) * (dx * rs) + inp(lnb, o4 + 0, md));
            o.y = f2b(inp(lnw, o4 + 1, md) * (dy * rs) + inp(lnb, o4 + 1, md));
            o.z = f2b(inp(lnw, o4 + 2, md) * (dz * rs) + inp(lnb, o4 + 2, md));
            o.w = f2b(inp(lnw, o4 + 3, md) * (dw * rs) + inp(lnb, o4 + 3, md));
            ((ushort4*)(hout + (size_t)row * cD))[t] = o;
        }
        return;
    }

    // ---- weight transpose path ----
    const void* in; u16* out; int ins, outs, tx_, ty_; ll ibase;
    if (b < 1728) {
        const int seg = b / 576, rem = b % 576, hd = rem / 48, tt = rem % 48;
        in = seg == 0 ? Qw : (seg == 1 ? Kw : Vw);
        ibase = (ll)l * cH * cD * cDH + (ll)hd * cD * cDH;
        out = WqkvT + (ll)seg * cD * cD + (ll)hd * cDH * cD;
        ins = cDH; outs = cD; tx_ = tt % 2; ty_ = tt / 2;
    } else if (b < 2304) {
        const int tt = b - 1728;
        in = Ow; ibase = (ll)l * cD * cD; out = WoT;
        ins = cD; outs = cD; tx_ = tt % 24; ty_ = tt / 24;
    } else if (b < 4608) {
        const int tt = b - 2304;
        in = Inw; ibase = (ll)l * cD * cM; out = WinT;
        ins = cM; outs = cD; tx_ = tt % 96; ty_ = tt / 96;
    } else {
        const int tt = b - 4608;
        in = Outw; ibase = (ll)l * cM * cD; out = WoutT;
        ins = cD; outs = cM; tx_ = tt % 24; ty_ = tt / 24;
    }
    const int tx = threadIdx.x & 31, ty = threadIdx.x >> 5;
    const int c0 = tx_ * 32, r0 = ty_ * 32;
    #pragma unroll
    for (int i = 0; i < 32; i += 8)
        tile[ty + i][tx] = f2b(inp(in, ibase + (ll)(r0 + ty + i) * ins + c0 + tx, md));
    __syncthreads();
    #pragma unroll
    for (int i = 0; i < 32; i += 8)
        out[(size_t)(c0 + ty + i) * outs + (r0 + tx)] = tile[tx][ty + i];
}

// ---- bf16 transpose for internal V slice (qkv cols) ----------------------------------
__global__ __launch_bounds__(256)
void transpose_b_k(const u16* __restrict__ in, u16* __restrict__ out,
                   int R, int C, int ins, int outs,
                   ll iOo, ll iOi, ll oOo, ll oOi, int HB)
{
    __shared__ u16 tile[32][33];
    const int z = blockIdx.z;
    const u16* ip = in  + (ll)(z / HB) * iOo + (ll)(z % HB) * iOi;
    u16*       op = out + (ll)(z / HB) * oOo + (ll)(z % HB) * oOi;
    const int tx = threadIdx.x & 31, ty = threadIdx.x >> 5;
    const int c0 = blockIdx.x * 32, r0 = blockIdx.y * 32;
    #pragma unroll
    for (int i = 0; i < 32; i += 8) {
        int r = r0 + ty + i, c = c0 + tx;
        if (r < R && c < C) tile[ty + i][tx] = ip[(size_t)r * ins + c];
    }
    __syncthreads();
    #pragma unroll
    for (int i = 0; i < 32; i += 8) {
        int c = c0 + ty + i, r = r0 + tx;
        if (c < C && r < R) op[(size_t)c * outs + r] = tile[tx][ty + i];
    }
}

// ---------------- embedding: res = E[x] + P (f32 out) ---------------------------------
__global__ __launch_bounds__(192)
void embed_k(const int* __restrict__ x, const void* __restrict__ E,
             const void* __restrict__ P, float* __restrict__ res,
             const int* __restrict__ modeflag)
{
    const int md = *modeflag;
    const int tok = blockIdx.x, t = threadIdx.x;
    const int s = tok & (cS - 1);
    const ll  eb = (ll)x[tok] * cD, pb = (ll)s * cD;
    float4 o;
    o.x = inp(E, eb + t * 4 + 0, md) + inp(P, pb + t * 4 + 0, md);
    o.y = inp(E, eb + t * 4 + 1, md) + inp(P, pb + t * 4 + 1, md);
    o.z = inp(E, eb + t * 4 + 2, md) + inp(P, pb + t * 4 + 2, md);
    o.w = inp(E, eb + t * 4 + 3, md) + inp(P, pb + t * 4 + 3, md);
    ((float4*)(res + (size_t)tok * cD))[t] = o;
}

// ---------------- layernorm (unbiased std, ddof=1), f32 in, bf16 out ------------------
__global__ __launch_bounds__(192)
void ln_k(const float* __restrict__ in, const void* __restrict__ w,
          const void* __restrict__ b, ll wb_off, u16* __restrict__ out,
          const int* __restrict__ modeflag)
{
    __shared__ float sm[8];
    const int md = *modeflag;
    const int row = blockIdx.x, t = threadIdx.x;
    const float4 x = ((const float4*)(in + (size_t)row * cD))[t];
    float s = wave_sum(x.x + x.y + x.z + x.w);
    const int lane = t & 63, wv = t >> 6;
    if (!lane) sm[wv] = s;
    __syncthreads();
    const float mu = (sm[0] + sm[1] + sm[2]) * (1.f / (float)cD);
    const float dx = x.x - mu, dy = x.y - mu, dz = x.z - mu, dw = x.w - mu;
    float ss = wave_sum(dx * dx + dy * dy + dz * dz + dw * dw);
    if (!lane) sm[4 + wv] = ss;
    __syncthreads();
    const float var = (sm[4] + sm[5] + sm[6]) * (1.f / (float)(cD - 1));
    const float rs  = 1.f / sqrtf(var);
    const ll o4 = wb_off + (ll)t * 4;
    ushort4 o;
    o.x = f2b(inp(w, o4 + 0, md) * (dx * rs) + inp(b, o4 + 0, md));
    o.y = f2b(inp(w, o4 + 1, md) * (dy * rs) + inp(b, o4 + 1, md));
    o.z = f2b(inp(w, o4 + 2, md) * (dz * rs) + inp(b, o4 + 2, md));
    o.w = f2b(inp(w, o4 + 3, md) * (dw * rs) + inp(b, o4 + 3, md));
    ((ushort4*)(out + (size_t)row * cD))[t] = o;
}

// ------- causal softmax, 4 rows/block, 1 wave per row, barrier-free, full writes ------
__global__ __launch_bounds__(256)
void softmax4_k(u16* __restrict__ p)
{
    const int row = blockIdx.x * 4 + (threadIdx.x >> 6);
    const int q = row & (cS - 1);
    u16* pr = p + (size_t)row * cS;
    const int lane = threadIdx.x & 63;

    ushort4 v[4];
    float xs[16];
    float mx = -3.4e38f;
    #pragma unroll
    for (int c = 0; c < 4; ++c) {
        const int j0 = (lane + c * 64) * 4;
        v[c] = make_ushort4(0, 0, 0, 0);
        if (j0 <= q) v[c] = ((const ushort4*)pr)[lane + c * 64];
        xs[c * 4 + 0] = (j0 + 0 <= q) ? b2f(v[c].x) : -100000.f;
        xs[c * 4 + 1] = (j0 + 1 <= q) ? b2f(v[c].y) : -100000.f;
        xs[c * 4 + 2] = (j0 + 2 <= q) ? b2f(v[c].z) : -100000.f;
        xs[c * 4 + 3] = (j0 + 3 <= q) ? b2f(v[c].w) : -100000.f;
        mx = fmaxf(mx, fmaxf(fmaxf(xs[c * 4], xs[c * 4 + 1]), fmaxf(xs[c * 4 + 2], xs[c * 4 + 3])));
    }
    mx = wave_max(mx);
    float sum = 0.f;
    #pragma unroll
    for (int j = 0; j < 16; ++j) {
        xs[j] = expf(xs[j] - mx);
        sum += xs[j];
    }
    sum = wave_sum(sum);
    const float inv = 1.f / sum;
    #pragma unroll
    for (int c = 0; c < 4; ++c) {
        ushort4 o;
        o.x = f2b(xs[c * 4 + 0] * inv);
        o.y = f2b(xs[c * 4 + 1] * inv);
        o.z = f2b(xs[c * 4 + 2] * inv);
        o.w = f2b(xs[c * 4 + 3] * inv);
        ((ushort4*)pr)[lane + c * 64] = o;
    }
}

// =====================================================================================
extern "C" void kernel_launch(void* const* d_in, const int* in_sizes, int n_in,
                              void* d_out, int out_size, void* d_ws, size_t ws_size,
                              hipStream_t stream)
{
    (void)in_sizes; (void)n_in; (void)out_size;
    const int*  x     = (const int*)d_in[0];
    const void* E_w   = d_in[1];
    const void* P_w   = d_in[2];
    const void* ln1_w = d_in[3];
    const void* ln1_b = d_in[4];
    const void* Q_w   = d_in[5];
    const void* Q_b   = d_in[6];
    const void* K_w   = d_in[7];
    const void* K_b   = d_in[8];
    const void* V_w   = d_in[9];
    const void* V_b   = d_in[10];
    const void* O_w   = d_in[11];
    const void* O_b   = d_in[12];
    const void* ln2_w = d_in[13];
    const void* ln2_b = d_in[14];
    const void* In_w  = d_in[15];
    const void* In_b  = d_in[16];
    const void* Out_w = d_in[17];
    const void* Out_b = d_in[18];
    const void* lnf_w = d_in[19];
    const void* lnf_b = d_in[20];
    const void* U_w   = d_in[21];
    const void* U_b   = d_in[22];

    // ---- workspace carve with aliasing (~99 MB) ----
    char* wp = (char*)d_ws;
    auto carve = [&](size_t bytes) { char* r = wp; wp += (bytes + 255) & ~(size_t)255; return r; };
    int*   modeflag = (int*)carve(256);
    float* biasQKV  = (float*)carve((size_t)cL * cQKV * 4);
    float* res   = (float*)carve((size_t)cT * cD * 4);
    float* resat = (float*)carve((size_t)cT * cD * 4);
    u16* h     = (u16*)carve((size_t)cT * cD * 2);
    u16* attnb = (u16*)carve((size_t)cT * cD * 2);
    u16* vt    = (u16*)carve((size_t)cT * cD * 2);
    u16* qkv   = (u16*)carve((size_t)cT * cM * 2);       // aliased by mlpb
    u16* mlpb  = qkv;
    u16* WqkvT = (u16*)carve((size_t)cQKV * cD * 2);
    u16* WoT   = (u16*)carve((size_t)cD * cD * 2);
    u16* WinT  = (u16*)carve((size_t)cD * cM * 2);
    u16* WoutT = (u16*)carve((size_t)cD * cM * 2);
    u16* pbuf  = (u16*)carve((size_t)cBH * cS * cS * 2);
    u16* WuT   = pbuf;                                   // alias (pbuf dead after layers)

    if (ws_size && (size_t)(wp - (char*)d_ws) > ws_size) return;  // tripwire

    detect_k<<<1, 64, 0, stream>>>((const uint*)E_w, modeflag);
    packbias_k<<<(cL * cQKV) / 256, 256, 0, stream>>>(Q_b, K_b, V_b, biasQKV, modeflag);
    embed_k<<<cT, 192, 0, stream>>>(x, E_w, P_w, res, modeflag);

    for (int l = 0; l < cL; ++l) {
        // fused weight transposes + LN1 (one launch)
        transln_k<<<6912 + cT, 256, 0, stream>>>(
            Q_w, K_w, V_w, O_w, In_w, Out_w, WqkvT, WoT, WinT, WoutT,
            res, ln1_w, ln1_b, (ll)l * cD, h, l, modeflag);

        // fused QKV projection: 64x128 tiles -> 576 blocks
        gemm_bt<64, 128, 1, 4, 1, false, true, false, false, 2>
            <<<dim3(cT / 64, cQKV / 128, 1), 256, 0, stream>>>(
            h, cD, 0, 0, WqkvT, cD, 0, 0, qkv, cQKV, 0, 0, 1, cD,
            biasQKV, (ll)l * cQKV, 1.f, nullptr, nullptr, modeflag);

        // V slice -> vt [B,H,DH,S]
        transpose_b_k<<<dim3(2, cS / 32, cBH), 256, 0, stream>>>(
            qkv + 2 * cD, vt, cS, cDH, cQKV, cS,
            (ll)cS * cQKV, cDH, (ll)cH * cDH * cS, (ll)cDH * cS, cH);

        // logits = Q K^T * 1/8, 64^2 compact triangular grid (136 tiles x 24)
        gemm_bt<64, 64, 2, 2, 1, false, false, true, false, 0>
            <<<dim3(136, 1, cBH), 256, 0, stream>>>(
            qkv, cQKV, (ll)cS * cQKV, cDH,
            qkv + cD, cQKV, (ll)cS * cQKV, cDH,
            pbuf, cS, (ll)cH * cS * cS, (ll)cS * cS,
            cH, cDH, nullptr, 0, 0.125f, nullptr, nullptr, modeflag);

        // causal softmax: 4 rows/block, barrier-free
        softmax4_k<<<cBH * cS / 4, 256, 0, stream>>>(pbuf);

        // attn = P V, batched, causal K-limit; 64x64 tiles -> 384 blocks
        gemm_bt<64, 64, 2, 2, 1, false, false, false, true, 0>
            <<<dim3(1, 16, cBH), 256, 0, stream>>>(
            pbuf, cS, (ll)cH * cS * cS, (ll)cS * cS,
            vt, cS, (ll)cH * cDH * cS, (ll)cDH * cS,
            attnb, cD, (ll)cS * cD, cDH,
            cH, cS, nullptr, 0, 1.f, nullptr, nullptr, modeflag);

        // O projection + residual -> resat (f32): 64x64 -> 384 blocks
        gemm_bt<64, 64, 2, 2, 0, false, true, false, false, 1>
            <<<dim3(cT / 64, cD / 64, 1), 256, 0, stream>>>(
            attnb, cD, 0, 0, WoT, cD, 0, 0, resat, cD, 0, 0, 1, cD,
            O_b, (ll)l * cD, 1.f, res, nullptr, modeflag);

        // LN2
        ln_k<<<cT, 192, 0, stream>>>(resat, ln2_w, ln2_b, (ll)l * cD, h, modeflag);

        // MLP in: 64x128 tiles -> 768 blocks: gelu(h @ Win + bIn)
        gemm_bt<64, 128, 1, 4, 1, true, true, false, false, 1>
            <<<dim3(cT / 64, cM / 128, 1), 256, 0, stream>>>(
            h, cD, 0, 0, WinT, cD, 0, 0, mlpb, cM, 0, 0, 1, cD,
            In_b, (ll)l * cM, 1.f, nullptr, nullptr, modeflag);

        // MLP out + double residual (64^2 tiles -> 384 blocks)
        gemm_bt<64, 64, 2, 2, 0, false, true, false, false, 1>
            <<<dim3(cT / 64, cD / 64, 1), 256, 0, stream>>>(
            mlpb, cM, 0, 0, WoutT, cM, 0, 0, res, cD, 0, 0, 1, cM,
            Out_b, (ll)l * cD, 1.f, res, resat, modeflag);
    }

    // unembed: r13 config + NT stores (output never re-read; kills the RFO read stream
    // that showed as FETCH ~= WRITE/2). 64x128 tiles, 8000 blocks, T2 + XCD swizzle.
    transpose_k<<<dim3(cV / 32, cD / 32, 1), 256, 0, stream>>>(
        U_w, WuT, cD, cV, cV, cD, 0, 0, 0, modeflag);
    ln_k<<<cT, 192, 0, stream>>>(res, lnf_w, lnf_b, 0, h, modeflag);
    gemm_bt<64, 128, 1, 4, 2, false, true, false, false, 1, true, true>
        <<<dim3(cT / 64, cV / 128, 1), 256, 0, stream>>>(
        h, cD, 0, 0, WuT, cD, 0, 0, d_out, cV, 0, 0, 1, cD,
        U_b, 0, 1.f, nullptr, nullptr, modeflag);
}

// Round 18
// 868.170 us; speedup vs baseline: 1.4355x; 1.0234x over previous
//
#include <hip/hip_runtime.h>

using uint = unsigned int;
using u16  = unsigned short;
using ll   = long long;

constexpr int cL = 4, cH = 12, cDH = 64, cD = 768, cM = 3072, cV = 32000, cS = 1024, cB = 2;
constexpr int cT  = cB * cS;   // 2048 tokens
constexpr int cBH = cB * cH;   // 24
constexpr int cQKV = 3 * cD;   // 2304

using bf16x8 = __bf16 __attribute__((ext_vector_type(8)));
using f32x4  = float  __attribute__((ext_vector_type(4)));

__device__ __forceinline__ float b2f(u16 u) {
    union { uint i; float f; } v; v.i = ((uint)u) << 16; return v.f;
}
__device__ __forceinline__ u16 f2b(float f) {
    union { float f; uint i; } v; v.f = f;
    uint u = v.i;
    return (u16)((u + 0x7fffu + ((u >> 16) & 1u)) >> 16);   // RNE
}
// read input element `idx` as float, per mode (1 = bf16, 0 = f32)
__device__ __forceinline__ float inp(const void* p, ll idx, int md) {
    return md ? b2f(((const u16*)p)[idx]) : ((const float*)p)[idx];
}
__device__ __forceinline__ float wave_sum(float v) {
    #pragma unroll
    for (int m = 32; m; m >>= 1) v += __shfl_xor(v, m);
    return v;
}
__device__ __forceinline__ float wave_max(float v) {
    #pragma unroll
    for (int m = 32; m; m >>= 1) v = fmaxf(v, __shfl_xor(v, m));
    return v;
}
__device__ __forceinline__ void gload16(const u16* g, u16* l) {
    __builtin_amdgcn_global_load_lds(
        (const __attribute__((address_space(1))) uint*)g,
        (__attribute__((address_space(3))) uint*)l,
        16, 0, 0);
}

// ---------------- dtype detector ------------------------------------------------------
__global__ void detect_k(const uint* __restrict__ e, int* __restrict__ flag)
{
    const int l = threadIdx.x;
    int hits = 0;
    #pragma unroll
    for (int i = 0; i < 4; ++i) {
        uint w  = e[l * 4 + i];
        uint ex = (w >> 7) & 0xffu;
        hits += (ex >= 100u && ex <= 126u) ? 1 : 0;
    }
    float s = wave_sum((float)hits);
    if (l == 0) *flag = (s >= 128.f) ? 1 : 0;   // 1 = bf16 inputs, 0 = f32 inputs
}

// ---------------- pack QKV biases -> f32 [L][2304] ------------------------------------
__global__ __launch_bounds__(256)
void packbias_k(const void* __restrict__ Qb, const void* __restrict__ Kb,
                const void* __restrict__ Vb, float* __restrict__ out,
                const int* __restrict__ modeflag)
{
    const int md = *modeflag;
    const int i = blockIdx.x * 256 + threadIdx.x;   // i < L*2304
    const int l = i / cQKV, c = i % cQKV;
    float v;
    if (c < cD)           v = inp(Qb, (ll)l * cD + c, md);
    else if (c < 2 * cD)  v = inp(Kb, (ll)l * cD + c - cD, md);
    else                  v = inp(Vb, (ll)l * cD + c - 2 * cD, md);
    out[i] = v;
}

// ---------------- GEMM (m97-style, 4 waves) + T2 both-sides LDS swizzle ----------------
// LDS slot (row, gslot) holds global 16B-group (gslot ^ (row&7)); staging pre-swizzles
// the per-lane global source (linear LDS dest per gload_lds rule); reads XOR the group.
// CSKIP: causal QK^T compact triangular grid. XCDS: bijective XCD swizzle on 2D grid.
// NTST: non-temporal C stores (never-re-read outputs; kills the RFO read stream).
// COALST: LDS-staged coalesced f32x4 epilogue (requires BM=64,BN=128,WGM=1,!GELU);
//         reuses the dead staging LDS (32x132 f32, padded, 16.9KB) in two 32-row passes.
template<int BM, int BN, int WGM, int WGN, int OUTK, bool GELU,
         bool COLMAJ, bool CSKIP, bool CK, int BIASK, bool XCDS = false,
         bool NTST = false, bool COALST = false>
__global__ __launch_bounds__(256)
void gemm_bt(const u16* __restrict__ A, int lda, ll offAo, ll offAi,
             const u16* __restrict__ Bt, int ldb, ll offBo, ll offBi,
             void* __restrict__ Cv, int ldc, ll offCo, ll offCi,
             int HB, int K,
             const void* __restrict__ bias, ll bias_off, float scale,
             const float* __restrict__ r1, const float* __restrict__ r2,
             const int* __restrict__ modeflag)
{
    constexpr int MF = BM / WGM / 16;
    constexpr int NF = BN / WGN / 16;
    static_assert(BM % (WGM * 16) == 0 && BN % (WGN * 16) == 0, "tile/wave mismatch");
    static_assert(WGM * WGN == 4, "4 waves");
    __shared__ __align__(16) u16 smem[BM * 64 + BN * 64];
    u16* sA = smem;
    u16* sB = smem + BM * 64;

    int rowTile, colTile;
    if constexpr (CSKIP) {
        const int bi = blockIdx.x;
        int r = (int)((sqrtf(8.f * bi + 1.f) - 1.f) * 0.5f);
        while ((r + 1) * (r + 2) / 2 <= bi) ++r;
        while (r * (r + 1) / 2 > bi) --r;
        rowTile = r * BM;
        colTile = (bi - r * (r + 1) / 2) * BN;
    } else if constexpr (XCDS) {
        const int nwg = gridDim.x * gridDim.y;
        const int lin = blockIdx.y * gridDim.x + blockIdx.x;
        const int q8 = nwg >> 3, r8 = nwg & 7;
        const int xcd = lin & 7, idx = lin >> 3;
        const int n_  = (xcd < r8 ? xcd * (q8 + 1) : r8 * (q8 + 1) + (xcd - r8) * q8) + idx;
        rowTile = (n_ % gridDim.x) * BM;
        colTile = (n_ / gridDim.x) * BN;
    } else {
        rowTile = (COLMAJ ? blockIdx.x : blockIdx.y) * BM;
        colTile = (COLMAJ ? blockIdx.y : blockIdx.x) * BN;
    }

    const int md = *modeflag;
    const int z = blockIdx.z;
    const ll zo = z / HB, zi = z % HB;
    const u16* Ab = A + zo * offAo + zi * offAi;
    const u16* Bb = Bt + zo * offBo + zi * offBi;

    const int tid  = threadIdx.x;
    const int lane = tid & 63, wid = tid >> 6;
    const int wr = wid / WGN, wc = wid % WGN;
    const int lr = lane >> 3;                       // row-in-chunk (== row & 7)
    const int lc8s = (((lane & 7) ^ lr) << 3);      // pre-swizzled global 16B-group

    f32x4 zero = {0.f, 0.f, 0.f, 0.f};
    f32x4 acc[MF][NF];
    #pragma unroll
    for (int m = 0; m < MF; ++m)
        #pragma unroll
        for (int n = 0; n < NF; ++n) acc[m][n] = zero;

    const int nkt = CK ? ((rowTile + BM) >> 6) : (K >> 6);
    for (int kt = 0; kt < nkt; ++kt) {
        const int k0 = kt << 6;
        #pragma unroll
        for (int i = 0; i < BM / 32; ++i) {
            int c = i * 4 + wid;
            gload16(Ab + (size_t)(rowTile + c * 8 + lr) * lda + k0 + lc8s, &sA[c * 512]);
        }
        #pragma unroll
        for (int i = 0; i < BN / 32; ++i) {
            int c = i * 4 + wid;
            gload16(Bb + (size_t)(colTile + c * 8 + lr) * ldb + k0 + lc8s, &sB[c * 512]);
        }
        asm volatile("s_waitcnt vmcnt(0)" ::: "memory");
        __syncthreads();
        #pragma unroll
        for (int kk = 0; kk < 2; ++kk) {
            const int g = kk * 4 + (lane >> 4);     // 16B-group index (0..7)
            bf16x8 af[MF], bfv[NF];
            #pragma unroll
            for (int m = 0; m < MF; ++m) {
                const int row = wr * (BM / WGM) + m * 16 + (lane & 15);
                af[m] = *(const bf16x8*)&sA[row * 64 + ((g ^ (row & 7)) << 3)];
            }
            #pragma unroll
            for (int n = 0; n < NF; ++n) {
                const int row = wc * (BN / WGN) + n * 16 + (lane & 15);
                bfv[n] = *(const bf16x8*)&sB[row * 64 + ((g ^ (row & 7)) << 3)];
            }
            #pragma unroll
            for (int m = 0; m < MF; ++m)
                #pragma unroll
                for (int n = 0; n < NF; ++n)
                    acc[m][n] = __builtin_amdgcn_mfma_f32_16x16x32_bf16(af[m], bfv[n], acc[m][n], 0, 0, 0);
        }
        __syncthreads();
    }

    const ll offC = zo * offCo + zi * offCi;

    if constexpr (COALST) {
        // LDS-staged coalesced epilogue: two 32-row passes through a padded f32 buffer.
        static_assert(BM == 64 && BN == 128 && WGM == 1 && WGN == 4 && !GELU, "coalst shape");
        float* sf = (float*)smem;                    // [32][132] padded (16.9KB <= 24KB)
        #pragma unroll
        for (int half = 0; half < 2; ++half) {
            if (half) __syncthreads();               // prior pass reads done
            #pragma unroll
            for (int mm = 0; mm < 2; ++mm) {
                const int m = half * 2 + mm;
                #pragma unroll
                for (int n = 0; n < NF; ++n) {
                    const int col = wc * 32 + n * 16 + (lane & 15);
                    float bvv = 0.f;
                    if constexpr (BIASK == 1) bvv = inp(bias, bias_off + colTile + col, md);
                    if constexpr (BIASK == 2) bvv = ((const float*)bias)[bias_off + colTile + col];
                    #pragma unroll
                    for (int r = 0; r < 4; ++r) {
                        const int row = mm * 16 + ((lane >> 4) << 2) + r;
                        sf[row * 132 + col] = acc[m][n][r] * scale + bvv;
                    }
                }
            }
            __syncthreads();
            #pragma unroll
            for (int it = 0; it < 4; ++it) {
                const int slot = it * 256 + tid;     // 1024 slots = 32 rows x 32 f32x4
                const int row = slot >> 5;
                const int c4 = (slot & 31) << 2;
                const f32x4 v = *(const f32x4*)&sf[row * 132 + c4];
                const size_t gidx = (size_t)(rowTile + half * 32 + row) * ldc + colTile + c4;
                if (md) {
                    u16* dst = (u16*)Cv + offC + gidx;
                    dst[0] = f2b(v[0]); dst[1] = f2b(v[1]); dst[2] = f2b(v[2]); dst[3] = f2b(v[3]);
                } else {
                    __builtin_nontemporal_store(v, (f32x4*)&((float*)Cv)[offC + gidx]);
                }
            }
        }
        return;
    }

    #pragma unroll
    for (int m = 0; m < MF; ++m) {
        #pragma unroll
        for (int n = 0; n < NF; ++n) {
            const int col = colTile + wc * (BN / WGN) + n * 16 + (lane & 15);
            float bvv = 0.f;
            if constexpr (BIASK == 1) bvv = inp(bias, bias_off + col, md);
            if constexpr (BIASK == 2) bvv = ((const float*)bias)[bias_off + col];
            #pragma unroll
            for (int r = 0; r < 4; ++r) {
                const int row = rowTile + wr * (BM / WGM) + m * 16 + ((lane >> 4) << 2) + r;
                float xv = acc[m][n][r] * scale + bvv;
                if constexpr (GELU) xv = 0.5f * xv * (1.f + erff(xv * 0.70710678118654752f));
                const size_t idx = (size_t)row * ldc + col;
                if (r1) xv += r1[idx];
                if (r2) xv += r2[idx];
                if constexpr (OUTK == 1) {
                    if constexpr (NTST) __builtin_nontemporal_store(f2b(xv), &((u16*)Cv)[offC + idx]);
                    else                ((u16*)Cv)[offC + idx] = f2b(xv);
                } else if constexpr (OUTK == 0) {
                    if constexpr (NTST) __builtin_nontemporal_store(xv, &((float*)Cv)[offC + idx]);
                    else                ((float*)Cv)[offC + idx] = xv;
                } else {
                    if (md) {
                        if constexpr (NTST) __builtin_nontemporal_store(f2b(xv), &((u16*)Cv)[offC + idx]);
                        else                ((u16*)Cv)[offC + idx] = f2b(xv);
                    } else {
                        if constexpr (NTST) __builtin_nontemporal_store(xv, &((float*)Cv)[offC + idx]);
                        else                ((float*)Cv)[offC + idx] = xv;
                    }
                }
            }
        }
    }
}

// ------- transpose input weight (bf16 OR f32) -> bf16 ---------------------------------
__global__ __launch_bounds__(256)
void transpose_k(const void* __restrict__ in, u16* __restrict__ out,
                 int R, int C, int ins, int outs,
                 ll base, ll iStride, ll oStride,
                 const int* __restrict__ modeflag)
{
    __shared__ u16 tile[32][33];
    const int md = *modeflag;
    const int z = blockIdx.z;
    const ll ioff = base + (ll)z * iStride;
    u16* op = out + (ll)z * oStride;
    const int tx = threadIdx.x & 31, ty = threadIdx.x >> 5;
    const int c0 = blockIdx.x * 32, r0 = blockIdx.y * 32;
    #pragma unroll
    for (int i = 0; i < 32; i += 8) {
        int r = r0 + ty + i, c = c0 + tx;
        if (r < R && c < C) tile[ty + i][tx] = f2b(inp(in, ioff + (ll)r * ins + c, md));
    }
    __syncthreads();
    #pragma unroll
    for (int i = 0; i < 32; i += 8) {
        int c = c0 + ty + i, r = r0 + tx;
        if (c < C && r < R) op[(size_t)c * outs + r] = tile[tx][ty + i];
    }
}

// ------- fused: per-layer weight transposes (blocks 0..6911) + LN1 (6912..8959) -------
__global__ __launch_bounds__(256)
void transln_k(const void* __restrict__ Qw, const void* __restrict__ Kw,
               const void* __restrict__ Vw, const void* __restrict__ Ow,
               const void* __restrict__ Inw, const void* __restrict__ Outw,
               u16* __restrict__ WqkvT, u16* __restrict__ WoT,
               u16* __restrict__ WinT, u16* __restrict__ WoutT,
               const float* __restrict__ res, const void* __restrict__ lnw,
               const void* __restrict__ lnb, ll wb_off, u16* __restrict__ hout,
               int l, const int* __restrict__ modeflag)
{
    __shared__ u16 tile[32][33];
    __shared__ float sm[8];
    const int md = *modeflag;
    const int b = blockIdx.x;

    if (b >= 6912) {
        // ---- LN1 path: one row per block, 192 active threads of 256 ----
        const int row = b - 6912, t = threadIdx.x;
        float4 x = {0.f, 0.f, 0.f, 0.f};
        if (t < 192) x = ((const float4*)(res + (size_t)row * cD))[t];
        float s = wave_sum(x.x + x.y + x.z + x.w);
        const int lane = t & 63, wv = t >> 6;
        if (!lane) sm[wv] = s;
        __syncthreads();
        const float mu = (sm[0] + sm[1] + sm[2]) * (1.f / (float)cD);
        const float dx = x.x - mu, dy = x.y - mu, dz = x.z - mu, dw = x.w - mu;
        float ss = wave_sum(dx * dx + dy * dy + dz * dz + dw * dw);
        if (!lane) sm[4 + wv] = ss;
        __syncthreads();
        const float var = (sm[4] + sm[5] + sm[6]) * (1.f / (float)(cD - 1));
        const float rs  = 1.f / sqrtf(var);
        if (t < 192) {
            const ll o4 = wb_off + (ll)t * 4;
            ushort4 o;
            o.x = f2b(inp(lnw, o4 + 0, md) * (dx * rs) + inp(lnb, o4 + 0, md));
            o.y = f2b(inp(lnw, o4 + 1, md) * (dy * rs) + inp(lnb, o4 + 1, md));
            o.z = f2b(inp(lnw, o4 + 2, md) * (dz * rs) + inp(lnb, o4 + 2, md));
            o.w = f2b(inp(lnw, o4 + 3, md) * (dw * rs) + inp(lnb, o4 + 3, md));
            ((ushort4*)(hout + (size_t)row * cD))[t] = o;
        }
        return;
    }

    // ---- weight transpose path ----
    const void* in; u16* out; int ins, outs, tx_, ty_; ll ibase;
    if (b < 1728) {
        const int seg = b / 576, rem = b % 576, hd = rem / 48, tt = rem % 48;
        in = seg == 0 ? Qw : (seg == 1 ? Kw : Vw);
        ibase = (ll)l * cH * cD * cDH + (ll)hd * cD * cDH;
        out = WqkvT + (ll)seg * cD * cD + (ll)hd * cDH * cD;
        ins = cDH; outs = cD; tx_ = tt % 2; ty_ = tt / 2;
    } else if (b < 2304) {
        const int tt = b - 1728;
        in = Ow; ibase = (ll)l * cD * cD; out = WoT;
        ins = cD; outs = cD; tx_ = tt % 24; ty_ = tt / 24;
    } else if (b < 4608) {
        const int tt = b - 2304;
        in = Inw; ibase = (ll)l * cD * cM; out = WinT;
        ins = cM; outs = cD; tx_ = tt % 96; ty_ = tt / 96;
    } else {
        const int tt = b - 4608;
        in = Outw; ibase = (ll)l * cM * cD; out = WoutT;
        ins = cD; outs = cM; tx_ = tt % 24; ty_ = tt / 24;
    }
    const int tx = threadIdx.x & 31, ty = threadIdx.x >> 5;
    const int c0 = tx_ * 32, r0 = ty_ * 32;
    #pragma unroll
    for (int i = 0; i < 32; i += 8)
        tile[ty + i][tx] = f2b(inp(in, ibase + (ll)(r0 + ty + i) * ins + c0 + tx, md));
    __syncthreads();
    #pragma unroll
    for (int i = 0; i < 32; i += 8)
        out[(size_t)(c0 + ty + i) * outs + (r0 + tx)] = tile[tx][ty + i];
}

// ---- bf16 transpose for internal V slice (qkv cols) ----------------------------------
__global__ __launch_bounds__(256)
void transpose_b_k(const u16* __restrict__ in, u16* __restrict__ out,
                   int R, int C, int ins, int outs,
                   ll iOo, ll iOi, ll oOo, ll oOi, int HB)
{
    __shared__ u16 tile[32][33];
    const int z = blockIdx.z;
    const u16* ip = in  + (ll)(z / HB) * iOo + (ll)(z % HB) * iOi;
    u16*       op = out + (ll)(z / HB) * oOo + (ll)(z % HB) * oOi;
    const int tx = threadIdx.x & 31, ty = threadIdx.x >> 5;
    const int c0 = blockIdx.x * 32, r0 = blockIdx.y * 32;
    #pragma unroll
    for (int i = 0; i < 32; i += 8) {
        int r = r0 + ty + i, c = c0 + tx;
        if (r < R && c < C) tile[ty + i][tx] = ip[(size_t)r * ins + c];
    }
    __syncthreads();
    #pragma unroll
    for (int i = 0; i < 32; i += 8) {
        int c = c0 + ty + i, r = r0 + tx;
        if (c < C && r < R) op[(size_t)c * outs + r] = tile[tx][ty + i];
    }
}

// ---------------- embedding: res = E[x] + P (f32 out) ---------------------------------
__global__ __launch_bounds__(192)
void embed_k(const int* __restrict__ x, const void* __restrict__ E,
             const void* __restrict__ P, float* __restrict__ res,
             const int* __restrict__ modeflag)
{
    const int md = *modeflag;
    const int tok = blockIdx.x, t = threadIdx.x;
    const int s = tok & (cS - 1);
    const ll  eb = (ll)x[tok] * cD, pb = (ll)s * cD;
    float4 o;
    o.x = inp(E, eb + t * 4 + 0, md) + inp(P, pb + t * 4 + 0, md);
    o.y = inp(E, eb + t * 4 + 1, md) + inp(P, pb + t * 4 + 1, md);
    o.z = inp(E, eb + t * 4 + 2, md) + inp(P, pb + t * 4 + 2, md);
    o.w = inp(E, eb + t * 4 + 3, md) + inp(P, pb + t * 4 + 3, md);
    ((float4*)(res + (size_t)tok * cD))[t] = o;
}

// ---------------- layernorm (unbiased std, ddof=1), f32 in, bf16 out ------------------
__global__ __launch_bounds__(192)
void ln_k(const float* __restrict__ in, const void* __restrict__ w,
          const void* __restrict__ b, ll wb_off, u16* __restrict__ out,
          const int* __restrict__ modeflag)
{
    __shared__ float sm[8];
    const int md = *modeflag;
    const int row = blockIdx.x, t = threadIdx.x;
    const float4 x = ((const float4*)(in + (size_t)row * cD))[t];
    float s = wave_sum(x.x + x.y + x.z + x.w);
    const int lane = t & 63, wv = t >> 6;
    if (!lane) sm[wv] = s;
    __syncthreads();
    const float mu = (sm[0] + sm[1] + sm[2]) * (1.f / (float)cD);
    const float dx = x.x - mu, dy = x.y - mu, dz = x.z - mu, dw = x.w - mu;
    float ss = wave_sum(dx * dx + dy * dy + dz * dz + dw * dw);
    if (!lane) sm[4 + wv] = ss;
    __syncthreads();
    const float var = (sm[4] + sm[5] + sm[6]) * (1.f / (float)(cD - 1));
    const float rs  = 1.f / sqrtf(var);
    const ll o4 = wb_off + (ll)t * 4;
    ushort4 o;
    o.x = f2b(inp(w, o4 + 0, md) * (dx * rs) + inp(b, o4 + 0, md));
    o.y = f2b(inp(w, o4 + 1, md) * (dy * rs) + inp(b, o4 + 1, md));
    o.z = f2b(inp(w, o4 + 2, md) * (dz * rs) + inp(b, o4 + 2, md));
    o.w = f2b(inp(w, o4 + 3, md) * (dw * rs) + inp(b, o4 + 3, md));
    ((ushort4*)(out + (size_t)row * cD))[t] = o;
}

// ------- causal softmax, 4 rows/block, 1 wave per row, barrier-free, full writes ------
__global__ __launch_bounds__(256)
void softmax4_k(u16* __restrict__ p)
{
    const int row = blockIdx.x * 4 + (threadIdx.x >> 6);
    const int q = row & (cS - 1);
    u16* pr = p + (size_t)row * cS;
    const int lane = threadIdx.x & 63;

    ushort4 v[4];
    float xs[16];
    float mx = -3.4e38f;
    #pragma unroll
    for (int c = 0; c < 4; ++c) {
        const int j0 = (lane + c * 64) * 4;
        v[c] = make_ushort4(0, 0, 0, 0);
        if (j0 <= q) v[c] = ((const ushort4*)pr)[lane + c * 64];
        xs[c * 4 + 0] = (j0 + 0 <= q) ? b2f(v[c].x) : -100000.f;
        xs[c * 4 + 1] = (j0 + 1 <= q) ? b2f(v[c].y) : -100000.f;
        xs[c * 4 + 2] = (j0 + 2 <= q) ? b2f(v[c].z) : -100000.f;
        xs[c * 4 + 3] = (j0 + 3 <= q) ? b2f(v[c].w) : -100000.f;
        mx = fmaxf(mx, fmaxf(fmaxf(xs[c * 4], xs[c * 4 + 1]), fmaxf(xs[c * 4 + 2], xs[c * 4 + 3])));
    }
    mx = wave_max(mx);
    float sum = 0.f;
    #pragma unroll
    for (int j = 0; j < 16; ++j) {
        xs[j] = expf(xs[j] - mx);
        sum += xs[j];
    }
    sum = wave_sum(sum);
    const float inv = 1.f / sum;
    #pragma unroll
    for (int c = 0; c < 4; ++c) {
        ushort4 o;
        o.x = f2b(xs[c * 4 + 0] * inv);
        o.y = f2b(xs[c * 4 + 1] * inv);
        o.z = f2b(xs[c * 4 + 2] * inv);
        o.w = f2b(xs[c * 4 + 3] * inv);
        ((ushort4*)pr)[lane + c * 64] = o;
    }
}

// =====================================================================================
extern "C" void kernel_launch(void* const* d_in, const int* in_sizes, int n_in,
                              void* d_out, int out_size, void* d_ws, size_t ws_size,
                              hipStream_t stream)
{
    (void)in_sizes; (void)n_in; (void)out_size;
    const int*  x     = (const int*)d_in[0];
    const void* E_w   = d_in[1];
    const void* P_w   = d_in[2];
    const void* ln1_w = d_in[3];
    const void* ln1_b = d_in[4];
    const void* Q_w   = d_in[5];
    const void* Q_b   = d_in[6];
    const void* K_w   = d_in[7];
    const void* K_b   = d_in[8];
    const void* V_w   = d_in[9];
    const void* V_b   = d_in[10];
    const void* O_w   = d_in[11];
    const void* O_b   = d_in[12];
    const void* ln2_w = d_in[13];
    const void* ln2_b = d_in[14];
    const void* In_w  = d_in[15];
    const void* In_b  = d_in[16];
    const void* Out_w = d_in[17];
    const void* Out_b = d_in[18];
    const void* lnf_w = d_in[19];
    const void* lnf_b = d_in[20];
    const void* U_w   = d_in[21];
    const void* U_b   = d_in[22];

    // ---- workspace carve with aliasing (~99 MB) ----
    char* wp = (char*)d_ws;
    auto carve = [&](size_t bytes) { char* r = wp; wp += (bytes + 255) & ~(size_t)255; return r; };
    int*   modeflag = (int*)carve(256);
    float* biasQKV  = (float*)carve((size_t)cL * cQKV * 4);
    float* res   = (float*)carve((size_t)cT * cD * 4);
    float* resat = (float*)carve((size_t)cT * cD * 4);
    u16* h     = (u16*)carve((size_t)cT * cD * 2);
    u16* attnb = (u16*)carve((size_t)cT * cD * 2);
    u16* vt    = (u16*)carve((size_t)cT * cD * 2);
    u16* qkv   = (u16*)carve((size_t)cT * cM * 2);       // aliased by mlpb
    u16* mlpb  = qkv;
    u16* WqkvT = (u16*)carve((size_t)cQKV * cD * 2);
    u16* WoT   = (u16*)carve((size_t)cD * cD * 2);
    u16* WinT  = (u16*)carve((size_t)cD * cM * 2);
    u16* WoutT = (u16*)carve((size_t)cD * cM * 2);
    u16* pbuf  = (u16*)carve((size_t)cBH * cS * cS * 2);
    u16* WuT   = pbuf;                                   // alias (pbuf dead after layers)

    if (ws_size && (size_t)(wp - (char*)d_ws) > ws_size) return;  // tripwire

    detect_k<<<1, 64, 0, stream>>>((const uint*)E_w, modeflag);
    packbias_k<<<(cL * cQKV) / 256, 256, 0, stream>>>(Q_b, K_b, V_b, biasQKV, modeflag);
    embed_k<<<cT, 192, 0, stream>>>(x, E_w, P_w, res, modeflag);

    for (int l = 0; l < cL; ++l) {
        // fused weight transposes + LN1 (one launch)
        transln_k<<<6912 + cT, 256, 0, stream>>>(
            Q_w, K_w, V_w, O_w, In_w, Out_w, WqkvT, WoT, WinT, WoutT,
            res, ln1_w, ln1_b, (ll)l * cD, h, l, modeflag);

        // fused QKV projection: 64x128 tiles -> 576 blocks
        gemm_bt<64, 128, 1, 4, 1, false, true, false, false, 2>
            <<<dim3(cT / 64, cQKV / 128, 1), 256, 0, stream>>>(
            h, cD, 0, 0, WqkvT, cD, 0, 0, qkv, cQKV, 0, 0, 1, cD,
            biasQKV, (ll)l * cQKV, 1.f, nullptr, nullptr, modeflag);

        // V slice -> vt [B,H,DH,S]
        transpose_b_k<<<dim3(2, cS / 32, cBH), 256, 0, stream>>>(
            qkv + 2 * cD, vt, cS, cDH, cQKV, cS,
            (ll)cS * cQKV, cDH, (ll)cH * cDH * cS, (ll)cDH * cS, cH);

        // logits = Q K^T * 1/8, 64^2 compact triangular grid (136 tiles x 24)
        gemm_bt<64, 64, 2, 2, 1, false, false, true, false, 0>
            <<<dim3(136, 1, cBH), 256, 0, stream>>>(
            qkv, cQKV, (ll)cS * cQKV, cDH,
            qkv + cD, cQKV, (ll)cS * cQKV, cDH,
            pbuf, cS, (ll)cH * cS * cS, (ll)cS * cS,
            cH, cDH, nullptr, 0, 0.125f, nullptr, nullptr, modeflag);

        // causal softmax: 4 rows/block, barrier-free
        softmax4_k<<<cBH * cS / 4, 256, 0, stream>>>(pbuf);

        // attn = P V, batched, causal K-limit; 64x64 tiles -> 384 blocks
        gemm_bt<64, 64, 2, 2, 1, false, false, false, true, 0>
            <<<dim3(1, 16, cBH), 256, 0, stream>>>(
            pbuf, cS, (ll)cH * cS * cS, (ll)cS * cS,
            vt, cS, (ll)cH * cDH * cS, (ll)cDH * cS,
            attnb, cD, (ll)cS * cD, cDH,
            cH, cS, nullptr, 0, 1.f, nullptr, nullptr, modeflag);

        // O projection + residual -> resat (f32): 64x64 -> 384 blocks
        gemm_bt<64, 64, 2, 2, 0, false, true, false, false, 1>
            <<<dim3(cT / 64, cD / 64, 1), 256, 0, stream>>>(
            attnb, cD, 0, 0, WoT, cD, 0, 0, resat, cD, 0, 0, 1, cD,
            O_b, (ll)l * cD, 1.f, res, nullptr, modeflag);

        // LN2
        ln_k<<<cT, 192, 0, stream>>>(resat, ln2_w, ln2_b, (ll)l * cD, h, modeflag);

        // MLP in: 64x128 tiles -> 768 blocks: gelu(h @ Win + bIn)
        gemm_bt<64, 128, 1, 4, 1, true, true, false, false, 1>
            <<<dim3(cT / 64, cM / 128, 1), 256, 0, stream>>>(
            h, cD, 0, 0, WinT, cD, 0, 0, mlpb, cM, 0, 0, 1, cD,
            In_b, (ll)l * cM, 1.f, nullptr, nullptr, modeflag);

        // MLP out + double residual (64^2 tiles -> 384 blocks)
        gemm_bt<64, 64, 2, 2, 0, false, true, false, false, 1>
            <<<dim3(cT / 64, cD / 64, 1), 256, 0, stream>>>(
            mlpb, cM, 0, 0, WoutT, cM, 0, 0, res, cD, 0, 0, 1, cM,
            Out_b, (ll)l * cD, 1.f, res, resat, modeflag);
    }

    // unembed: r16 config + COALST epilogue (LDS-staged f32x4 NT stores: full 128B
    // lines instead of 4x64B scalar segments). 64x128 tiles, 8000 blocks, T2 + XCD.
    transpose_k<<<dim3(cV / 32, cD / 32, 1), 256, 0, stream>>>(
        U_w, WuT, cD, cV, cV, cD, 0, 0, 0, modeflag);
    ln_k<<<cT, 192, 0, stream>>>(res, lnf_w, lnf_b, 0, h, modeflag);
    gemm_bt<64, 128, 1, 4, 2, false, true, false, false, 1, true, true, true>
        <<<dim3(cT / 64, cV / 128, 1), 256, 0, stream>>>(
        h, cD, 0, 0, WuT, cD, 0, 0, d_out, cV, 0, 0, 1, cD,
        U_b, 0, 1.f, nullptr, nullptr, modeflag);
}

// Round 19
// 860.592 us; speedup vs baseline: 1.4482x; 1.0088x over previous
//
#include <hip/hip_runtime.h>

using uint = unsigned int;
using u16  = unsigned short;
using ll   = long long;

constexpr int cL = 4, cH = 12, cDH = 64, cD = 768, cM = 3072, cV = 32000, cS = 1024, cB = 2;
constexpr int cT  = cB * cS;   // 2048 tokens
constexpr int cBH = cB * cH;   // 24
constexpr int cQKV = 3 * cD;   // 2304

using bf16x8 = __bf16 __attribute__((ext_vector_type(8)));
using f32x4  = float  __attribute__((ext_vector_type(4)));
using u16x8v = u16    __attribute__((ext_vector_type(8)));

__device__ __forceinline__ float b2f(u16 u) {
    union { uint i; float f; } v; v.i = ((uint)u) << 16; return v.f;
}
__device__ __forceinline__ u16 f2b(float f) {
    union { float f; uint i; } v; v.f = f;
    uint u = v.i;
    return (u16)((u + 0x7fffu + ((u >> 16) & 1u)) >> 16);   // RNE
}
// read input element `idx` as float, per mode (1 = bf16, 0 = f32)
__device__ __forceinline__ float inp(const void* p, ll idx, int md) {
    return md ? b2f(((const u16*)p)[idx]) : ((const float*)p)[idx];
}
__device__ __forceinline__ float wave_sum(float v) {
    #pragma unroll
    for (int m = 32; m; m >>= 1) v += __shfl_xor(v, m);
    return v;
}
__device__ __forceinline__ float wave_max(float v) {
    #pragma unroll
    for (int m = 32; m; m >>= 1) v = fmaxf(v, __shfl_xor(v, m));
    return v;
}
__device__ __forceinline__ void gload16(const u16* g, u16* l) {
    __builtin_amdgcn_global_load_lds(
        (const __attribute__((address_space(1))) uint*)g,
        (__attribute__((address_space(3))) uint*)l,
        16, 0, 0);
}

// ---------------- dtype detector ------------------------------------------------------
__global__ void detect_k(const uint* __restrict__ e, int* __restrict__ flag)
{
    const int l = threadIdx.x;
    int hits = 0;
    #pragma unroll
    for (int i = 0; i < 4; ++i) {
        uint w  = e[l * 4 + i];
        uint ex = (w >> 7) & 0xffu;
        hits += (ex >= 100u && ex <= 126u) ? 1 : 0;
    }
    float s = wave_sum((float)hits);
    if (l == 0) *flag = (s >= 128.f) ? 1 : 0;   // 1 = bf16 inputs, 0 = f32 inputs
}

// ---------------- pack QKV biases -> f32 [L][2304] ------------------------------------
__global__ __launch_bounds__(256)
void packbias_k(const void* __restrict__ Qb, const void* __restrict__ Kb,
                const void* __restrict__ Vb, float* __restrict__ out,
                const int* __restrict__ modeflag)
{
    const int md = *modeflag;
    const int i = blockIdx.x * 256 + threadIdx.x;   // i < L*2304
    const int l = i / cQKV, c = i % cQKV;
    float v;
    if (c < cD)           v = inp(Qb, (ll)l * cD + c, md);
    else if (c < 2 * cD)  v = inp(Kb, (ll)l * cD + c - cD, md);
    else                  v = inp(Vb, (ll)l * cD + c - 2 * cD, md);
    out[i] = v;
}

// ---------------- GEMM (m97-style, 4 waves) + T2 both-sides LDS swizzle ----------------
// LDS slot (row, gslot) holds global 16B-group (gslot ^ (row&7)); staging pre-swizzles
// the per-lane global source (linear LDS dest per gload_lds rule); reads XOR the group.
// CSKIP: causal QK^T compact triangular grid. XCDS: bijective XCD swizzle on 2D grid.
// NTST: non-temporal C stores (never-re-read outputs; kills the RFO read stream).
// COALST: LDS-staged coalesced epilogue (requires BM=64,BN=128,WGM=1); f32 NT x4 stores
//         for f32 outputs, cached u16x8 stores for bf16 outputs. GELU supported.
template<int BM, int BN, int WGM, int WGN, int OUTK, bool GELU,
         bool COLMAJ, bool CSKIP, bool CK, int BIASK, bool XCDS = false,
         bool NTST = false, bool COALST = false>
__global__ __launch_bounds__(256)
void gemm_bt(const u16* __restrict__ A, int lda, ll offAo, ll offAi,
             const u16* __restrict__ Bt, int ldb, ll offBo, ll offBi,
             void* __restrict__ Cv, int ldc, ll offCo, ll offCi,
             int HB, int K,
             const void* __restrict__ bias, ll bias_off, float scale,
             const float* __restrict__ r1, const float* __restrict__ r2,
             const int* __restrict__ modeflag)
{
    constexpr int MF = BM / WGM / 16;
    constexpr int NF = BN / WGN / 16;
    static_assert(BM % (WGM * 16) == 0 && BN % (WGN * 16) == 0, "tile/wave mismatch");
    static_assert(WGM * WGN == 4, "4 waves");
    __shared__ __align__(16) u16 smem[BM * 64 + BN * 64];
    u16* sA = smem;
    u16* sB = smem + BM * 64;

    int rowTile, colTile;
    if constexpr (CSKIP) {
        const int bi = blockIdx.x;
        int r = (int)((sqrtf(8.f * bi + 1.f) - 1.f) * 0.5f);
        while ((r + 1) * (r + 2) / 2 <= bi) ++r;
        while (r * (r + 1) / 2 > bi) --r;
        rowTile = r * BM;
        colTile = (bi - r * (r + 1) / 2) * BN;
    } else if constexpr (XCDS) {
        const int nwg = gridDim.x * gridDim.y;
        const int lin = blockIdx.y * gridDim.x + blockIdx.x;
        const int q8 = nwg >> 3, r8 = nwg & 7;
        const int xcd = lin & 7, idx = lin >> 3;
        const int n_  = (xcd < r8 ? xcd * (q8 + 1) : r8 * (q8 + 1) + (xcd - r8) * q8) + idx;
        rowTile = (n_ % gridDim.x) * BM;
        colTile = (n_ / gridDim.x) * BN;
    } else {
        rowTile = (COLMAJ ? blockIdx.x : blockIdx.y) * BM;
        colTile = (COLMAJ ? blockIdx.y : blockIdx.x) * BN;
    }

    const int md = *modeflag;
    const int z = blockIdx.z;
    const ll zo = z / HB, zi = z % HB;
    const u16* Ab = A + zo * offAo + zi * offAi;
    const u16* Bb = Bt + zo * offBo + zi * offBi;

    const int tid  = threadIdx.x;
    const int lane = tid & 63, wid = tid >> 6;
    const int wr = wid / WGN, wc = wid % WGN;
    const int lr = lane >> 3;                       // row-in-chunk (== row & 7)
    const int lc8s = (((lane & 7) ^ lr) << 3);      // pre-swizzled global 16B-group

    f32x4 zero = {0.f, 0.f, 0.f, 0.f};
    f32x4 acc[MF][NF];
    #pragma unroll
    for (int m = 0; m < MF; ++m)
        #pragma unroll
        for (int n = 0; n < NF; ++n) acc[m][n] = zero;

    const int nkt = CK ? ((rowTile + BM) >> 6) : (K >> 6);
    for (int kt = 0; kt < nkt; ++kt) {
        const int k0 = kt << 6;
        #pragma unroll
        for (int i = 0; i < BM / 32; ++i) {
            int c = i * 4 + wid;
            gload16(Ab + (size_t)(rowTile + c * 8 + lr) * lda + k0 + lc8s, &sA[c * 512]);
        }
        #pragma unroll
        for (int i = 0; i < BN / 32; ++i) {
            int c = i * 4 + wid;
            gload16(Bb + (size_t)(colTile + c * 8 + lr) * ldb + k0 + lc8s, &sB[c * 512]);
        }
        asm volatile("s_waitcnt vmcnt(0)" ::: "memory");
        __syncthreads();
        #pragma unroll
        for (int kk = 0; kk < 2; ++kk) {
            const int g = kk * 4 + (lane >> 4);     // 16B-group index (0..7)
            bf16x8 af[MF], bfv[NF];
            #pragma unroll
            for (int m = 0; m < MF; ++m) {
                const int row = wr * (BM / WGM) + m * 16 + (lane & 15);
                af[m] = *(const bf16x8*)&sA[row * 64 + ((g ^ (row & 7)) << 3)];
            }
            #pragma unroll
            for (int n = 0; n < NF; ++n) {
                const int row = wc * (BN / WGN) + n * 16 + (lane & 15);
                bfv[n] = *(const bf16x8*)&sB[row * 64 + ((g ^ (row & 7)) << 3)];
            }
            #pragma unroll
            for (int m = 0; m < MF; ++m)
                #pragma unroll
                for (int n = 0; n < NF; ++n)
                    acc[m][n] = __builtin_amdgcn_mfma_f32_16x16x32_bf16(af[m], bfv[n], acc[m][n], 0, 0, 0);
        }
        __syncthreads();
    }

    const ll offC = zo * offCo + zi * offCi;

    if constexpr (COALST) {
        // LDS-staged coalesced epilogue: two 32-row passes through a padded f32 buffer.
        static_assert(BM == 64 && BN == 128 && WGM == 1 && WGN == 4, "coalst shape");
        float* sf = (float*)smem;                    // [32][132] padded (16.9KB <= 24KB)
        #pragma unroll
        for (int half = 0; half < 2; ++half) {
            if (half) __syncthreads();               // prior pass reads done
            #pragma unroll
            for (int mm = 0; mm < 2; ++mm) {
                const int m = half * 2 + mm;
                #pragma unroll
                for (int n = 0; n < NF; ++n) {
                    const int col = wc * 32 + n * 16 + (lane & 15);
                    float bvv = 0.f;
                    if constexpr (BIASK == 1) bvv = inp(bias, bias_off + colTile + col, md);
                    if constexpr (BIASK == 2) bvv = ((const float*)bias)[bias_off + colTile + col];
                    #pragma unroll
                    for (int r = 0; r < 4; ++r) {
                        const int row = mm * 16 + ((lane >> 4) << 2) + r;
                        float xv = acc[m][n][r] * scale + bvv;
                        if constexpr (GELU) xv = 0.5f * xv * (1.f + erff(xv * 0.70710678118654752f));
                        sf[row * 132 + col] = xv;
                    }
                }
            }
            __syncthreads();
            if constexpr (OUTK == 1) {
                // bf16 out (re-read later): cached u16x8 (16B) stores; 512 slots, 2 iters
                #pragma unroll
                for (int it = 0; it < 2; ++it) {
                    const int slot = it * 256 + tid;   // 32 rows x 16 u16x8 slots
                    const int row = slot >> 4;
                    const int c8 = (slot & 15) << 3;
                    u16x8v o;
                    #pragma unroll
                    for (int j = 0; j < 8; ++j) o[j] = f2b(sf[row * 132 + c8 + j]);
                    const size_t gidx = (size_t)(rowTile + half * 32 + row) * ldc + colTile + c8;
                    *(u16x8v*)&((u16*)Cv)[offC + gidx] = o;
                }
            } else {
                // dynamic (unembed): f32 NT f32x4, or bf16 scalar if md==1; 1024 slots
                #pragma unroll
                for (int it = 0; it < 4; ++it) {
                    const int slot = it * 256 + tid;   // 32 rows x 32 f32x4 slots
                    const int row = slot >> 5;
                    const int c4 = (slot & 31) << 2;
                    const f32x4 v = *(const f32x4*)&sf[row * 132 + c4];
                    const size_t gidx = (size_t)(rowTile + half * 32 + row) * ldc + colTile + c4;
                    if (md) {
                        u16* dst = (u16*)Cv + offC + gidx;
                        dst[0] = f2b(v[0]); dst[1] = f2b(v[1]); dst[2] = f2b(v[2]); dst[3] = f2b(v[3]);
                    } else {
                        __builtin_nontemporal_store(v, (f32x4*)&((float*)Cv)[offC + gidx]);
                    }
                }
            }
        }
        return;
    }

    #pragma unroll
    for (int m = 0; m < MF; ++m) {
        #pragma unroll
        for (int n = 0; n < NF; ++n) {
            const int col = colTile + wc * (BN / WGN) + n * 16 + (lane & 15);
            float bvv = 0.f;
            if constexpr (BIASK == 1) bvv = inp(bias, bias_off + col, md);
            if constexpr (BIASK == 2) bvv = ((const float*)bias)[bias_off + col];
            #pragma unroll
            for (int r = 0; r < 4; ++r) {
                const int row = rowTile + wr * (BM / WGM) + m * 16 + ((lane >> 4) << 2) + r;
                float xv = acc[m][n][r] * scale + bvv;
                if constexpr (GELU) xv = 0.5f * xv * (1.f + erff(xv * 0.70710678118654752f));
                const size_t idx = (size_t)row * ldc + col;
                if (r1) xv += r1[idx];
                if (r2) xv += r2[idx];
                if constexpr (OUTK == 1) {
                    if constexpr (NTST) __builtin_nontemporal_store(f2b(xv), &((u16*)Cv)[offC + idx]);
                    else                ((u16*)Cv)[offC + idx] = f2b(xv);
                } else if constexpr (OUTK == 0) {
                    if constexpr (NTST) __builtin_nontemporal_store(xv, &((float*)Cv)[offC + idx]);
                    else                ((float*)Cv)[offC + idx] = xv;
                } else {
                    if (md) {
                        if constexpr (NTST) __builtin_nontemporal_store(f2b(xv), &((u16*)Cv)[offC + idx]);
                        else                ((u16*)Cv)[offC + idx] = f2b(xv);
                    } else {
                        if constexpr (NTST) __builtin_nontemporal_store(xv, &((float*)Cv)[offC + idx]);
                        else                ((float*)Cv)[offC + idx] = xv;
                    }
                }
            }
        }
    }
}

// ------- transpose input weight (bf16 OR f32) -> bf16 ---------------------------------
__global__ __launch_bounds__(256)
void transpose_k(const void* __restrict__ in, u16* __restrict__ out,
                 int R, int C, int ins, int outs,
                 ll base, ll iStride, ll oStride,
                 const int* __restrict__ modeflag)
{
    __shared__ u16 tile[32][33];
    const int md = *modeflag;
    const int z = blockIdx.z;
    const ll ioff = base + (ll)z * iStride;
    u16* op = out + (ll)z * oStride;
    const int tx = threadIdx.x & 31, ty = threadIdx.x >> 5;
    const int c0 = blockIdx.x * 32, r0 = blockIdx.y * 32;
    #pragma unroll
    for (int i = 0; i < 32; i += 8) {
        int r = r0 + ty + i, c = c0 + tx;
        if (r < R && c < C) tile[ty + i][tx] = f2b(inp(in, ioff + (ll)r * ins + c, md));
    }
    __syncthreads();
    #pragma unroll
    for (int i = 0; i < 32; i += 8) {
        int c = c0 + ty + i, r = r0 + tx;
        if (c < C && r < R) op[(size_t)c * outs + r] = tile[tx][ty + i];
    }
}

// ------- fused: per-layer weight transposes (blocks 0..6911) + LN1 (6912..8959) -------
__global__ __launch_bounds__(256)
void transln_k(const void* __restrict__ Qw, const void* __restrict__ Kw,
               const void* __restrict__ Vw, const void* __restrict__ Ow,
               const void* __restrict__ Inw, const void* __restrict__ Outw,
               u16* __restrict__ WqkvT, u16* __restrict__ WoT,
               u16* __restrict__ WinT, u16* __restrict__ WoutT,
               const float* __restrict__ res, const void* __restrict__ lnw,
               const void* __restrict__ lnb, ll wb_off, u16* __restrict__ hout,
               int l, const int* __restrict__ modeflag)
{
    __shared__ u16 tile[32][33];
    __shared__ float sm[8];
    const int md = *modeflag;
    const int b = blockIdx.x;

    if (b >= 6912) {
        // ---- LN1 path: one row per block, 192 active threads of 256 ----
        const int row = b - 6912, t = threadIdx.x;
        float4 x = {0.f, 0.f, 0.f, 0.f};
        if (t < 192) x = ((const float4*)(res + (size_t)row * cD))[t];
        float s = wave_sum(x.x + x.y + x.z + x.w);
        const int lane = t & 63, wv = t >> 6;
        if (!lane) sm[wv] = s;
        __syncthreads();
        const float mu = (sm[0] + sm[1] + sm[2]) * (1.f / (float)cD);
        const float dx = x.x - mu, dy = x.y - mu, dz = x.z - mu, dw = x.w - mu;
        float ss = wave_sum(dx * dx + dy * dy + dz * dz + dw * dw);
        if (!lane) sm[4 + wv] = ss;
        __syncthreads();
        const float var = (sm[4] + sm[5] + sm[6]) * (1.f / (float)(cD - 1));
        const float rs  = 1.f / sqrtf(var);
        if (t < 192) {
            const ll o4 = wb_off + (ll)t * 4;
            ushort4 o;
            o.x = f2b(inp(lnw, o4 + 0, md) * (dx * rs) + inp(lnb, o4 + 0, md));
            o.y = f2b(inp(lnw, o4 + 1, md) * (dy * rs) + inp(lnb, o4 + 1, md));
            o.z = f2b(inp(lnw, o4 + 2, md) * (dz * rs) + inp(lnb, o4 + 2, md));
            o.w = f2b(inp(lnw, o4 + 3, md) * (dw * rs) + inp(lnb, o4 + 3, md));
            ((ushort4*)(hout + (size_t)row * cD))[t] = o;
        }
        return;
    }

    // ---- weight transpose path ----
    const void* in; u16* out; int ins, outs, tx_, ty_; ll ibase;
    if (b < 1728) {
        const int seg = b / 576, rem = b % 576, hd = rem / 48, tt = rem % 48;
        in = seg == 0 ? Qw : (seg == 1 ? Kw : Vw);
        ibase = (ll)l * cH * cD * cDH + (ll)hd * cD * cDH;
        out = WqkvT + (ll)seg * cD * cD + (ll)hd * cDH * cD;
        ins = cDH; outs = cD; tx_ = tt % 2; ty_ = tt / 2;
    } else if (b < 2304) {
        const int tt = b - 1728;
        in = Ow; ibase = (ll)l * cD * cD; out = WoT;
        ins = cD; outs = cD; tx_ = tt % 24; ty_ = tt / 24;
    } else if (b < 4608) {
        const int tt = b - 2304;
        in = Inw; ibase = (ll)l * cD * cM; out = WinT;
        ins = cM; outs = cD; tx_ = tt % 96; ty_ = tt / 96;
    } else {
        const int tt = b - 4608;
        in = Outw; ibase = (ll)l * cM * cD; out = WoutT;
        ins = cD; outs = cM; tx_ = tt % 24; ty_ = tt / 24;
    }
    const int tx = threadIdx.x & 31, ty = threadIdx.x >> 5;
    const int c0 = tx_ * 32, r0 = ty_ * 32;
    #pragma unroll
    for (int i = 0; i < 32; i += 8)
        tile[ty + i][tx] = f2b(inp(in, ibase + (ll)(r0 + ty + i) * ins + c0 + tx, md));
    __syncthreads();
    #pragma unroll
    for (int i = 0; i < 32; i += 8)
        out[(size_t)(c0 + ty + i) * outs + (r0 + tx)] = tile[tx][ty + i];
}

// ---- bf16 transpose for internal V slice (qkv cols) ----------------------------------
__global__ __launch_bounds__(256)
void transpose_b_k(const u16* __restrict__ in, u16* __restrict__ out,
                   int R, int C, int ins, int outs,
                   ll iOo, ll iOi, ll oOo, ll oOi, int HB)
{
    __shared__ u16 tile[32][33];
    const int z = blockIdx.z;
    const u16* ip = in  + (ll)(z / HB) * iOo + (ll)(z % HB) * iOi;
    u16*       op = out + (ll)(z / HB) * oOo + (ll)(z % HB) * oOi;
    const int tx = threadIdx.x & 31, ty = threadIdx.x >> 5;
    const int c0 = blockIdx.x * 32, r0 = blockIdx.y * 32;
    #pragma unroll
    for (int i = 0; i < 32; i += 8) {
        int r = r0 + ty + i, c = c0 + tx;
        if (r < R && c < C) tile[ty + i][tx] = ip[(size_t)r * ins + c];
    }
    __syncthreads();
    #pragma unroll
    for (int i = 0; i < 32; i += 8) {
        int c = c0 + ty + i, r = r0 + tx;
        if (c < C && r < R) op[(size_t)c * outs + r] = tile[tx][ty + i];
    }
}

// ---------------- embedding: res = E[x] + P (f32 out) ---------------------------------
__global__ __launch_bounds__(192)
void embed_k(const int* __restrict__ x, const void* __restrict__ E,
             const void* __restrict__ P, float* __restrict__ res,
             const int* __restrict__ modeflag)
{
    const int md = *modeflag;
    const int tok = blockIdx.x, t = threadIdx.x;
    const int s = tok & (cS - 1);
    const ll  eb = (ll)x[tok] * cD, pb = (ll)s * cD;
    float4 o;
    o.x = inp(E, eb + t * 4 + 0, md) + inp(P, pb + t * 4 + 0, md);
    o.y = inp(E, eb + t * 4 + 1, md) + inp(P, pb + t * 4 + 1, md);
    o.z = inp(E, eb + t * 4 + 2, md) + inp(P, pb + t * 4 + 2, md);
    o.w = inp(E, eb + t * 4 + 3, md) + inp(P, pb + t * 4 + 3, md);
    ((float4*)(res + (size_t)tok * cD))[t] = o;
}

// ---------------- layernorm (unbiased std, ddof=1), f32 in, bf16 out ------------------
__global__ __launch_bounds__(192)
void ln_k(const float* __restrict__ in, const void* __restrict__ w,
          const void* __restrict__ b, ll wb_off, u16* __restrict__ out,
          const int* __restrict__ modeflag)
{
    __shared__ float sm[8];
    const int md = *modeflag;
    const int row = blockIdx.x, t = threadIdx.x;
    const float4 x = ((const float4*)(in + (size_t)row * cD))[t];
    float s = wave_sum(x.x + x.y + x.z + x.w);
    const int lane = t & 63, wv = t >> 6;
    if (!lane) sm[wv] = s;
    __syncthreads();
    const float mu = (sm[0] + sm[1] + sm[2]) * (1.f / (float)cD);
    const float dx = x.x - mu, dy = x.y - mu, dz = x.z - mu, dw = x.w - mu;
    float ss = wave_sum(dx * dx + dy * dy + dz * dz + dw * dw);
    if (!lane) sm[4 + wv] = ss;
    __syncthreads();
    const float var = (sm[4] + sm[5] + sm[6]) * (1.f / (float)(cD - 1));
    const float rs  = 1.f / sqrtf(var);
    const ll o4 = wb_off + (ll)t * 4;
    ushort4 o;
    o.x = f2b(inp(w, o4 + 0, md) * (dx * rs) + inp(b, o4 + 0, md));
    o.y = f2b(inp(w, o4 + 1, md) * (dy * rs) + inp(b, o4 + 1, md));
    o.z = f2b(inp(w, o4 + 2, md) * (dz * rs) + inp(b, o4 + 2, md));
    o.w = f2b(inp(w, o4 + 3, md) * (dw * rs) + inp(b, o4 + 3, md));
    ((ushort4*)(out + (size_t)row * cD))[t] = o;
}

// ------- causal softmax, 4 rows/block, 1 wave per row, barrier-free, full writes ------
__global__ __launch_bounds__(256)
void softmax4_k(u16* __restrict__ p)
{
    const int row = blockIdx.x * 4 + (threadIdx.x >> 6);
    const int q = row & (cS - 1);
    u16* pr = p + (size_t)row * cS;
    const int lane = threadIdx.x & 63;

    ushort4 v[4];
    float xs[16];
    float mx = -3.4e38f;
    #pragma unroll
    for (int c = 0; c < 4; ++c) {
        const int j0 = (lane + c * 64) * 4;
        v[c] = make_ushort4(0, 0, 0, 0);
        if (j0 <= q) v[c] = ((const ushort4*)pr)[lane + c * 64];
        xs[c * 4 + 0] = (j0 + 0 <= q) ? b2f(v[c].x) : -100000.f;
        xs[c * 4 + 1] = (j0 + 1 <= q) ? b2f(v[c].y) : -100000.f;
        xs[c * 4 + 2] = (j0 + 2 <= q) ? b2f(v[c].z) : -100000.f;
        xs[c * 4 + 3] = (j0 + 3 <= q) ? b2f(v[c].w) : -100000.f;
        mx = fmaxf(mx, fmaxf(fmaxf(xs[c * 4], xs[c * 4 + 1]), fmaxf(xs[c * 4 + 2], xs[c * 4 + 3])));
    }
    mx = wave_max(mx);
    float sum = 0.f;
    #pragma unroll
    for (int j = 0; j < 16; ++j) {
        xs[j] = expf(xs[j] - mx);
        sum += xs[j];
    }
    sum = wave_sum(sum);
    const float inv = 1.f / sum;
    #pragma unroll
    for (int c = 0; c < 4; ++c) {
        ushort4 o;
        o.x = f2b(xs[c * 4 + 0] * inv);
        o.y = f2b(xs[c * 4 + 1] * inv);
        o.z = f2b(xs[c * 4 + 2] * inv);
        o.w = f2b(xs[c * 4 + 3] * inv);
        ((ushort4*)pr)[lane + c * 64] = o;
    }
}

// =====================================================================================
extern "C" void kernel_launch(void* const* d_in, const int* in_sizes, int n_in,
                              void* d_out, int out_size, void* d_ws, size_t ws_size,
                              hipStream_t stream)
{
    (void)in_sizes; (void)n_in; (void)out_size;
    const int*  x     = (const int*)d_in[0];
    const void* E_w   = d_in[1];
    const void* P_w   = d_in[2];
    const void* ln1_w = d_in[3];
    const void* ln1_b = d_in[4];
    const void* Q_w   = d_in[5];
    const void* Q_b   = d_in[6];
    const void* K_w   = d_in[7];
    const void* K_b   = d_in[8];
    const void* V_w   = d_in[9];
    const void* V_b   = d_in[10];
    const void* O_w   = d_in[11];
    const void* O_b   = d_in[12];
    const void* ln2_w = d_in[13];
    const void* ln2_b = d_in[14];
    const void* In_w  = d_in[15];
    const void* In_b  = d_in[16];
    const void* Out_w = d_in[17];
    const void* Out_b = d_in[18];
    const void* lnf_w = d_in[19];
    const void* lnf_b = d_in[20];
    const void* U_w   = d_in[21];
    const void* U_b   = d_in[22];

    // ---- workspace carve with aliasing (~99 MB) ----
    char* wp = (char*)d_ws;
    auto carve = [&](size_t bytes) { char* r = wp; wp += (bytes + 255) & ~(size_t)255; return r; };
    int*   modeflag = (int*)carve(256);
    float* biasQKV  = (float*)carve((size_t)cL * cQKV * 4);
    float* res   = (float*)carve((size_t)cT * cD * 4);
    float* resat = (float*)carve((size_t)cT * cD * 4);
    u16* h     = (u16*)carve((size_t)cT * cD * 2);
    u16* attnb = (u16*)carve((size_t)cT * cD * 2);
    u16* vt    = (u16*)carve((size_t)cT * cD * 2);
    u16* qkv   = (u16*)carve((size_t)cT * cM * 2);       // aliased by mlpb
    u16* mlpb  = qkv;
    u16* WqkvT = (u16*)carve((size_t)cQKV * cD * 2);
    u16* WoT   = (u16*)carve((size_t)cD * cD * 2);
    u16* WinT  = (u16*)carve((size_t)cD * cM * 2);
    u16* WoutT = (u16*)carve((size_t)cD * cM * 2);
    u16* pbuf  = (u16*)carve((size_t)cBH * cS * cS * 2);
    u16* WuT   = pbuf;                                   // alias (pbuf dead after layers)

    if (ws_size && (size_t)(wp - (char*)d_ws) > ws_size) return;  // tripwire

    detect_k<<<1, 64, 0, stream>>>((const uint*)E_w, modeflag);
    packbias_k<<<(cL * cQKV) / 256, 256, 0, stream>>>(Q_b, K_b, V_b, biasQKV, modeflag);
    embed_k<<<cT, 192, 0, stream>>>(x, E_w, P_w, res, modeflag);

    for (int l = 0; l < cL; ++l) {
        // fused weight transposes + LN1 (one launch)
        transln_k<<<6912 + cT, 256, 0, stream>>>(
            Q_w, K_w, V_w, O_w, In_w, Out_w, WqkvT, WoT, WinT, WoutT,
            res, ln1_w, ln1_b, (ll)l * cD, h, l, modeflag);

        // fused QKV projection: 64x128 tiles -> 576 blocks, COALST u16x8 epilogue
        gemm_bt<64, 128, 1, 4, 1, false, true, false, false, 2, false, false, true>
            <<<dim3(cT / 64, cQKV / 128, 1), 256, 0, stream>>>(
            h, cD, 0, 0, WqkvT, cD, 0, 0, qkv, cQKV, 0, 0, 1, cD,
            biasQKV, (ll)l * cQKV, 1.f, nullptr, nullptr, modeflag);

        // V slice -> vt [B,H,DH,S]
        transpose_b_k<<<dim3(2, cS / 32, cBH), 256, 0, stream>>>(
            qkv + 2 * cD, vt, cS, cDH, cQKV, cS,
            (ll)cS * cQKV, cDH, (ll)cH * cDH * cS, (ll)cDH * cS, cH);

        // logits = Q K^T * 1/8, 64^2 compact triangular grid (136 tiles x 24)
        gemm_bt<64, 64, 2, 2, 1, false, false, true, false, 0>
            <<<dim3(136, 1, cBH), 256, 0, stream>>>(
            qkv, cQKV, (ll)cS * cQKV, cDH,
            qkv + cD, cQKV, (ll)cS * cQKV, cDH,
            pbuf, cS, (ll)cH * cS * cS, (ll)cS * cS,
            cH, cDH, nullptr, 0, 0.125f, nullptr, nullptr, modeflag);

        // causal softmax: 4 rows/block, barrier-free
        softmax4_k<<<cBH * cS / 4, 256, 0, stream>>>(pbuf);

        // attn = P V, batched, causal K-limit; 64x64 tiles -> 384 blocks
        gemm_bt<64, 64, 2, 2, 1, false, false, false, true, 0>
            <<<dim3(1, 16, cBH), 256, 0, stream>>>(
            pbuf, cS, (ll)cH * cS * cS, (ll)cS * cS,
            vt, cS, (ll)cH * cDH * cS, (ll)cDH * cS,
            attnb, cD, (ll)cS * cD, cDH,
            cH, cS, nullptr, 0, 1.f, nullptr, nullptr, modeflag);

        // O projection + residual -> resat (f32): 64x64 -> 384 blocks
        gemm_bt<64, 64, 2, 2, 0, false, true, false, false, 1>
            <<<dim3(cT / 64, cD / 64, 1), 256, 0, stream>>>(
            attnb, cD, 0, 0, WoT, cD, 0, 0, resat, cD, 0, 0, 1, cD,
            O_b, (ll)l * cD, 1.f, res, nullptr, modeflag);

        // LN2
        ln_k<<<cT, 192, 0, stream>>>(resat, ln2_w, ln2_b, (ll)l * cD, h, modeflag);

        // MLP in: 64x128 tiles -> 768 blocks, COALST u16x8 epilogue: gelu(h@Win+bIn)
        gemm_bt<64, 128, 1, 4, 1, true, true, false, false, 1, false, false, true>
            <<<dim3(cT / 64, cM / 128, 1), 256, 0, stream>>>(
            h, cD, 0, 0, WinT, cD, 0, 0, mlpb, cM, 0, 0, 1, cD,
            In_b, (ll)l * cM, 1.f, nullptr, nullptr, modeflag);

        // MLP out + double residual (64^2 tiles -> 384 blocks)
        gemm_bt<64, 64, 2, 2, 0, false, true, false, false, 1>
            <<<dim3(cT / 64, cD / 64, 1), 256, 0, stream>>>(
            mlpb, cM, 0, 0, WoutT, cM, 0, 0, res, cD, 0, 0, 1, cM,
            Out_b, (ll)l * cD, 1.f, res, resat, modeflag);
    }

    // unembed: COALST f32x4 NT epilogue, 64x128 tiles, 8000 blocks, T2 + XCD swizzle.
    transpose_k<<<dim3(cV / 32, cD / 32, 1), 256, 0, stream>>>(
        U_w, WuT, cD, cV, cV, cD, 0, 0, 0, modeflag);
    ln_k<<<cT, 192, 0, stream>>>(res, lnf_w, lnf_b, 0, h, modeflag);
    gemm_bt<64, 128, 1, 4, 2, false, true, false, false, 1, true, true, true>
        <<<dim3(cT / 64, cV / 128, 1), 256, 0, stream>>>(
        h, cD, 0, 0, WuT, cD, 0, 0, d_out, cV, 0, 0, 1, cD,
        U_b, 0, 1.f, nullptr, nullptr, modeflag);
}